// Round 1
// baseline (965.521 us; speedup 1.0000x reference)
//
#include <hip/hip_runtime.h>
#include <math.h>

#define B_   2
#define S_   4096
#define HID_ 768
#define H_   12
#define D_   64
#define M_   64
#define CK_  33
#define BH_  (B_*H_)   // 24
#define KD_  768

// =============================================================
// GEMM: C = A @ W^T (+bias).  A [8192, 768] row-major, W [N, 768] row-major.
// 128x128 tile, BK=8, 256 threads, 8x8 micro-tile per thread.
// MODE 0: N=2304, epilogue scatters into Q/K/V [B,H,S,D] buffers.
// MODE 1: N=768,  epilogue writes row-major C (d_out).
// =============================================================
template<int MODE>
__global__ __launch_bounds__(256) void gemm_fp32(
    const float* __restrict__ A, const float* __restrict__ W,
    const float* __restrict__ bias, float* __restrict__ o0,
    float* __restrict__ o1, float* __restrict__ o2)
{
  __shared__ float As[8][128];
  __shared__ float Bs[8][128];
  const int tid = threadIdx.x;
  const int m0 = blockIdx.y * 128;
  const int n0 = blockIdx.x * 128;
  const int lrow = tid >> 1;          // 0..127
  const int lk   = (tid & 1) * 4;     // 0 or 4
  const float* Ap = A + (size_t)(m0 + lrow) * KD_ + lk;
  const float* Wp = W + (size_t)(n0 + lrow) * KD_ + lk;
  const int tr = tid >> 4;            // 0..15 -> rows tr*8 .. +7
  const int tc = tid & 15;            // 0..15 -> cols tc*4..+3 and 64+tc*4..+3

  float acc[8][8];
#pragma unroll
  for (int i = 0; i < 8; ++i)
#pragma unroll
    for (int j = 0; j < 8; ++j) acc[i][j] = 0.f;

  float4 an = *(const float4*)Ap;
  float4 bn = *(const float4*)Wp;

  for (int kt = 0; kt < KD_ / 8; ++kt) {
    __syncthreads();
    As[lk + 0][lrow] = an.x; As[lk + 1][lrow] = an.y;
    As[lk + 2][lrow] = an.z; As[lk + 3][lrow] = an.w;
    Bs[lk + 0][lrow] = bn.x; Bs[lk + 1][lrow] = bn.y;
    Bs[lk + 2][lrow] = bn.z; Bs[lk + 3][lrow] = bn.w;
    __syncthreads();
    if (kt + 1 < KD_ / 8) {
      an = *(const float4*)(Ap + (size_t)(kt + 1) * 8);
      bn = *(const float4*)(Wp + (size_t)(kt + 1) * 8);
    }
#pragma unroll
    for (int k = 0; k < 8; ++k) {
      const float4 a0 = *(const float4*)&As[k][tr * 8];
      const float4 a1 = *(const float4*)&As[k][tr * 8 + 4];
      const float4 b0 = *(const float4*)&Bs[k][tc * 4];
      const float4 b1 = *(const float4*)&Bs[k][tc * 4 + 64];
      const float av[8] = {a0.x, a0.y, a0.z, a0.w, a1.x, a1.y, a1.z, a1.w};
      const float bv[8] = {b0.x, b0.y, b0.z, b0.w, b1.x, b1.y, b1.z, b1.w};
#pragma unroll
      for (int i = 0; i < 8; ++i)
#pragma unroll
        for (int j = 0; j < 8; ++j) acc[i][j] += av[i] * bv[j];
    }
  }

  if (MODE == 0) {
    // scatter into Q/K/V [B,H,S,D]; a 128-col tile never crosses a 768 boundary
    const int part = n0 / HID_;
    const int h0 = (n0 - part * HID_) >> 6;   // column block -> head
    const int d0 = tc * 4;
    float* base = (part == 0) ? o0 : ((part == 1) ? o1 : o2);
    const float4 bl = *(const float4*)&bias[n0 + tc * 4];
    const float4 bh2 = *(const float4*)&bias[n0 + 64 + tc * 4];
#pragma unroll
    for (int i = 0; i < 8; ++i) {
      const int row = m0 + tr * 8 + i;
      const int b = row >> 12;
      const int s = row & (S_ - 1);
      float4 lo = make_float4(acc[i][0] + bl.x, acc[i][1] + bl.y,
                              acc[i][2] + bl.z, acc[i][3] + bl.w);
      float4 hi = make_float4(acc[i][4] + bh2.x, acc[i][5] + bh2.y,
                              acc[i][6] + bh2.z, acc[i][7] + bh2.w);
      *(float4*)&base[(((size_t)(b * H_ + h0) * S_ + s) << 6) + d0] = lo;
      *(float4*)&base[(((size_t)(b * H_ + h0 + 1) * S_ + s) << 6) + d0] = hi;
    }
  } else {
    const float4 bl = *(const float4*)&bias[n0 + tc * 4];
    const float4 bh2 = *(const float4*)&bias[n0 + 64 + tc * 4];
#pragma unroll
    for (int i = 0; i < 8; ++i) {
      const int row = m0 + tr * 8 + i;
      float4 lo = make_float4(acc[i][0] + bl.x, acc[i][1] + bl.y,
                              acc[i][2] + bl.z, acc[i][3] + bl.w);
      float4 hi = make_float4(acc[i][4] + bh2.x, acc[i][5] + bh2.y,
                              acc[i][6] + bh2.z, acc[i][7] + bh2.w);
      *(float4*)&o0[(size_t)row * HID_ + n0 + tc * 4] = lo;
      *(float4*)&o0[(size_t)row * HID_ + n0 + 64 + tc * 4] = hi;
    }
  }
}

// =============================================================
// Landmark means: Ql/Kl [BH, 64, 64] = segment means of Q/K over seg=64
// grid: BH*64 blocks, 64 threads (one per d)
// =============================================================
__global__ void landmarks_kernel(const float* __restrict__ Q,
                                 const float* __restrict__ K,
                                 float* __restrict__ Ql, float* __restrict__ Kl)
{
  const int blk = blockIdx.x;
  const int bh = blk >> 6, m = blk & 63;
  const int d = threadIdx.x;
  const float* qp = Q + ((size_t)bh * S_ + m * 64) * 64 + d;
  const float* kp = K + ((size_t)bh * S_ + m * 64) * 64 + d;
  float sq = 0.f, sk = 0.f;
  for (int j = 0; j < 64; ++j) { sq += qp[(size_t)j * 64]; sk += kp[(size_t)j * 64]; }
  Ql[((size_t)bh * M_ + m) * 64 + d] = sq * (1.f / 64.f);
  Kl[((size_t)bh * M_ + m) * 64 + d] = sk * (1.f / 64.f);
}

// =============================================================
// kernel_2 = softmax(Ql @ Kl^T / 8) [BH,64,64]; also per-(b,h) max col-sum
// and max row-sum (for the global Newton-Schulz scale).
// =============================================================
__global__ __launch_bounds__(256) void kernel2_softmax(
    const float* __restrict__ Ql, const float* __restrict__ Kl,
    float* __restrict__ K2, float* __restrict__ colmax, float* __restrict__ rowmax)
{
  __shared__ float Qs[64][68], Ks[64][68], S2[64][68];
  __shared__ float red1[64], red2[64];
  const int bh = blockIdx.x, tid = threadIdx.x;
  for (int idx = tid; idx < 4096; idx += 256) {
    const int r = idx >> 6, c = idx & 63;
    Qs[r][c] = Ql[(size_t)bh * 4096 + idx];
    Ks[r][c] = Kl[(size_t)bh * 4096 + idx];
  }
  __syncthreads();
  for (int idx = tid; idx < 4096; idx += 256) {
    const int r = idx >> 6, c = idx & 63;
    float dot = 0.f;
#pragma unroll
    for (int k = 0; k < 64; k += 4) {
      const float4 a = *(const float4*)&Qs[r][k];
      const float4 b = *(const float4*)&Ks[c][k];
      dot += a.x * b.x + a.y * b.y + a.z * b.z + a.w * b.w;
    }
    S2[r][c] = dot * 0.125f;
  }
  __syncthreads();
  if (tid < 64) {
    const int r = tid;
    float mx = -1e30f;
    for (int c = 0; c < 64; ++c) mx = fmaxf(mx, S2[r][c]);
    float sum = 0.f;
    for (int c = 0; c < 64; ++c) { const float e = expf(S2[r][c] - mx); S2[r][c] = e; sum += e; }
    const float inv = 1.f / sum;
    for (int c = 0; c < 64; ++c) S2[r][c] *= inv;
  }
  __syncthreads();
  for (int idx = tid; idx < 4096; idx += 256)
    K2[(size_t)bh * 4096 + idx] = S2[idx >> 6][idx & 63];
  if (tid < 64) {
    float cs = 0.f, rs = 0.f;
    for (int m = 0; m < 64; ++m) { cs += S2[m][tid]; rs += S2[tid][m]; }
    red1[tid] = cs; red2[tid] = rs;
  }
  __syncthreads();
  if (tid == 0) {
    float mc = 0.f, mr = 0.f;
    for (int i = 0; i < 64; ++i) { mc = fmaxf(mc, red1[i]); mr = fmaxf(mr, red2[i]); }
    colmax[bh] = mc; rowmax[bh] = mr;
  }
}

// 64x64x64 matmul in LDS: C = A @ B. 256 threads, 4x4 per thread.
__device__ inline void mm64(float (*C)[64], float (*A)[64], float (*B)[64], int tid)
{
  const int ry = tid >> 4, cx = tid & 15;
  const int r0 = ry * 4, c0 = cx * 4;
  float acc[4][4];
#pragma unroll
  for (int i = 0; i < 4; ++i)
#pragma unroll
    for (int j = 0; j < 4; ++j) acc[i][j] = 0.f;
  for (int k = 0; k < 64; k += 4) {
    float4 a[4], b[4];
#pragma unroll
    for (int i = 0; i < 4; ++i) a[i] = *(const float4*)&A[r0 + i][k];
#pragma unroll
    for (int j = 0; j < 4; ++j) b[j] = *(const float4*)&B[k + j][c0];
    const float bb[4][4] = {{b[0].x, b[0].y, b[0].z, b[0].w},
                            {b[1].x, b[1].y, b[1].z, b[1].w},
                            {b[2].x, b[2].y, b[2].z, b[2].w},
                            {b[3].x, b[3].y, b[3].z, b[3].w}};
    const float aa[4][4] = {{a[0].x, a[0].y, a[0].z, a[0].w},
                            {a[1].x, a[1].y, a[1].z, a[1].w},
                            {a[2].x, a[2].y, a[2].z, a[2].w},
                            {a[3].x, a[3].y, a[3].z, a[3].w}};
#pragma unroll
    for (int i = 0; i < 4; ++i)
#pragma unroll
      for (int j = 0; j < 4; ++j)
#pragma unroll
        for (int kk = 0; kk < 4; ++kk) acc[i][j] += aa[i][kk] * bb[kk][j];
  }
#pragma unroll
  for (int i = 0; i < 4; ++i)
    *(float4*)&C[r0 + i][c0] = make_float4(acc[i][0], acc[i][1], acc[i][2], acc[i][3]);
}

// =============================================================
// Newton-Schulz pseudo-inverse of kernel_2, 6 iterations, global scale.
// One block per (b,h). 80 KB LDS.
// =============================================================
__global__ __launch_bounds__(256) void newton_inv(
    const float* __restrict__ K2, const float* __restrict__ colmax,
    const float* __restrict__ rowmax, float* __restrict__ Vinv)
{
  __shared__ float A_[64][64], V_[64][64], KV_[64][64], T_[64][64], U_[64][64];
  __shared__ float scale_s;
  const int bh = blockIdx.x, tid = threadIdx.x;
  if (tid == 0) {
    float mc = 0.f, mr = 0.f;
    for (int i = 0; i < BH_; ++i) { mc = fmaxf(mc, colmax[i]); mr = fmaxf(mr, rowmax[i]); }
    scale_s = 1.f / (mc * mr);
  }
  for (int idx = tid; idx < 4096; idx += 256)
    A_[idx >> 6][idx & 63] = K2[(size_t)bh * 4096 + idx];
  __syncthreads();
  const float scale = scale_s;
  for (int idx = tid; idx < 4096; idx += 256) {
    const int r = idx >> 6, c = idx & 63;
    V_[r][c] = scale * A_[c][r];           // V0 = scale * K2^T
  }
  __syncthreads();
  for (int it = 0; it < 6; ++it) {
    mm64(KV_, A_, V_, tid); __syncthreads();
    for (int idx = tid; idx < 4096; idx += 256) {
      const int r = idx >> 6, c = idx & 63;
      T_[r][c] = (r == c ? 7.f : 0.f) - KV_[r][c];
    }
    __syncthreads();
    mm64(U_, KV_, T_, tid); __syncthreads();
    for (int idx = tid; idx < 4096; idx += 256) {
      const int r = idx >> 6, c = idx & 63;
      T_[r][c] = (r == c ? 15.f : 0.f) - U_[r][c];
    }
    __syncthreads();
    mm64(U_, KV_, T_, tid); __syncthreads();
    for (int idx = tid; idx < 4096; idx += 256) {
      const int r = idx >> 6, c = idx & 63;
      T_[r][c] = (r == c ? 13.f : 0.f) - U_[r][c];
    }
    __syncthreads();
    mm64(U_, V_, T_, tid); __syncthreads();
    for (int idx = tid; idx < 4096; idx += 256) {
      const int r = idx >> 6, c = idx & 63;
      V_[r][c] = 0.25f * U_[r][c];
    }
    __syncthreads();
  }
  for (int idx = tid; idx < 4096; idx += 256)
    Vinv[(size_t)bh * 4096 + idx] = V_[idx >> 6][idx & 63];
}

// =============================================================
// W1 = softmax(Ql @ K^T / 8, axis=S) @ V   -> [BH, 64, 64]
// One block per (b,h,m): whole 4096-score row lives in LDS.
// =============================================================
__global__ __launch_bounds__(256) void k3v_fused(
    const float* __restrict__ Ql, const float* __restrict__ K,
    const float* __restrict__ V, float* __restrict__ W1)
{
  __shared__ float sc[4096];
  __shared__ float qs[64];
  __shared__ float red[256];
  __shared__ float part[16][64];
  const int blk = blockIdx.x;
  const int bh = blk >> 6, m = blk & 63;
  const int tid = threadIdx.x;
  if (tid < 64) qs[tid] = Ql[((size_t)bh * 64 + m) * 64 + tid];
  __syncthreads();
  const float* Kb = K + (size_t)bh * S_ * 64;
  const float* Vb = V + (size_t)bh * S_ * 64;
  float lmax = -1e30f;
  for (int s = tid; s < S_; s += 256) {
    float dot = 0.f;
#pragma unroll
    for (int k = 0; k < 64; k += 4) {
      const float4 kv = *(const float4*)&Kb[(size_t)s * 64 + k];
      const float4 qv = *(const float4*)&qs[k];
      dot += kv.x * qv.x + kv.y * qv.y + kv.z * qv.z + kv.w * qv.w;
    }
    dot *= 0.125f;
    sc[s] = dot;
    lmax = fmaxf(lmax, dot);
  }
  red[tid] = lmax; __syncthreads();
  for (int off = 128; off > 0; off >>= 1) {
    if (tid < off) red[tid] = fmaxf(red[tid], red[tid + off]);
    __syncthreads();
  }
  const float gmax = red[0];
  __syncthreads();
  float lsum = 0.f;
  for (int s = tid; s < S_; s += 256) { const float e = expf(sc[s] - gmax); sc[s] = e; lsum += e; }
  red[tid] = lsum; __syncthreads();
  for (int off = 128; off > 0; off >>= 1) {
    if (tid < off) red[tid] += red[tid + off];
    __syncthreads();
  }
  const float inv = 1.f / red[0];
  __syncthreads();
  // PV: 16 s-groups x 16 d-quads
  const int g = tid >> 4, d4 = (tid & 15) * 4;
  float4 acc = make_float4(0.f, 0.f, 0.f, 0.f);
  for (int s = g; s < S_; s += 16) {
    const float p = sc[s];
    const float4 v = *(const float4*)&Vb[(size_t)s * 64 + d4];
    acc.x += p * v.x; acc.y += p * v.y; acc.z += p * v.z; acc.w += p * v.w;
  }
  *(float4*)&part[g][d4] = acc;
  __syncthreads();
  if (tid < 64) {
    float r2 = 0.f;
    for (int gg = 0; gg < 16; ++gg) r2 += part[gg][tid];
    W1[((size_t)bh * 64 + m) * 64 + tid] = r2 * inv;
  }
}

// W2 = Vinv @ W1, one block per (b,h)
__global__ __launch_bounds__(256) void w2_small(
    const float* __restrict__ Vinv, const float* __restrict__ W1, float* __restrict__ W2)
{
  __shared__ float A_[64][64], B2[64][64], C_[64][64];
  const int bh = blockIdx.x, tid = threadIdx.x;
  for (int idx = tid; idx < 4096; idx += 256) {
    A_[idx >> 6][idx & 63] = Vinv[(size_t)bh * 4096 + idx];
    B2[idx >> 6][idx & 63] = W1[(size_t)bh * 4096 + idx];
  }
  __syncthreads();
  mm64(C_, A_, B2, tid);
  __syncthreads();
  for (int idx = tid; idx < 4096; idx += 256)
    W2[(size_t)bh * 4096 + idx] = C_[idx >> 6][idx & 63];
}

// =============================================================
// X = softmax(Q @ Kl^T / 8, axis=M) @ W2, written transposed into Xc [B,S,HID]
// thread-per-row; Kl and W2 tiles broadcast from LDS.
// =============================================================
__global__ __launch_bounds__(256) void attn_core(
    const float* __restrict__ Q, const float* __restrict__ Kl,
    const float* __restrict__ W2, float* __restrict__ Xc)
{
  __shared__ float Kls[64][64];
  __shared__ float W2s[64][64];
  const int blk = blockIdx.x;          // bh*16 + chunk
  const int bh = blk >> 4, chunk = blk & 15;
  const int tid = threadIdx.x;
  const int b = bh / H_, h = bh % H_;
  for (int idx = tid; idx < 4096; idx += 256) {
    Kls[idx >> 6][idx & 63] = Kl[(size_t)bh * 4096 + idx];
    W2s[idx >> 6][idx & 63] = W2[(size_t)bh * 4096 + idx];
  }
  __syncthreads();
  const int s = chunk * 256 + tid;
  const float* qp = Q + ((size_t)bh * S_ + s) * 64;
  float4 q4[16];
#pragma unroll
  for (int k = 0; k < 16; ++k) q4[k] = *(const float4*)&qp[k * 4];
  float p[64];
#pragma unroll
  for (int m = 0; m < 64; ++m) {
    float dot = 0.f;
#pragma unroll
    for (int k = 0; k < 16; ++k) {
      const float4 kv = *(const float4*)&Kls[m][k * 4];
      dot += q4[k].x * kv.x + q4[k].y * kv.y + q4[k].z * kv.z + q4[k].w * kv.w;
    }
    p[m] = dot * 0.125f;
  }
  float mx = -1e30f;
#pragma unroll
  for (int m = 0; m < 64; ++m) mx = fmaxf(mx, p[m]);
  float sum = 0.f;
#pragma unroll
  for (int m = 0; m < 64; ++m) { p[m] = expf(p[m] - mx); sum += p[m]; }
  const float inv = 1.f / sum;
#pragma unroll
  for (int m = 0; m < 64; ++m) p[m] *= inv;
  float4 o4[16];
#pragma unroll
  for (int k = 0; k < 16; ++k) o4[k] = make_float4(0.f, 0.f, 0.f, 0.f);
#pragma unroll
  for (int m = 0; m < 64; ++m) {
    const float pm = p[m];
#pragma unroll
    for (int k = 0; k < 16; ++k) {
      const float4 wv = *(const float4*)&W2s[m][k * 4];
      o4[k].x += pm * wv.x; o4[k].y += pm * wv.y;
      o4[k].z += pm * wv.z; o4[k].w += pm * wv.w;
    }
  }
  float* xp = Xc + ((size_t)(b * S_ + s)) * HID_ + h * 64;
#pragma unroll
  for (int k = 0; k < 16; ++k) *(float4*)&xp[k * 4] = o4[k];
}

// =============================================================
// Depthwise conv over S (33 taps, zero pad 16), accumulated into Xc.
// One block per (b,h, 128-row chunk); V chunk + halo in LDS.
// =============================================================
__global__ __launch_bounds__(256) void conv_add(
    const float* __restrict__ V, const float* __restrict__ cw,
    float* __restrict__ Xc)
{
  __shared__ float Vs[160][64];
  __shared__ float cws[33];
  const int blk = blockIdx.x;          // bh*32 + chunk
  const int bh = blk >> 5, chunk = blk & 31;
  const int tid = threadIdx.x;
  const int b = bh / H_, h = bh % H_;
  const int s0 = chunk * 128;
  if (tid < 33) cws[tid] = cw[h * 33 + tid];
  const float* Vb = V + (size_t)bh * S_ * 64;
  for (int idx = tid; idx < 160 * 64; idx += 256) {
    const int r = idx >> 6, c = idx & 63;
    const int sv = s0 - 16 + r;
    Vs[r][c] = (sv >= 0 && sv < S_) ? Vb[(size_t)sv * 64 + c] : 0.f;
  }
  __syncthreads();
  const int d = tid & 63, rg = tid >> 6;   // rg 0..3 each owns 32 rows
  for (int rr = 0; rr < 32; ++rr) {
    const int r = rg * 32 + rr;
    float acc = 0.f;
#pragma unroll
    for (int t = 0; t < 33; ++t) acc += Vs[r + t][d] * cws[t];
    float* xp = Xc + ((size_t)(b * S_ + s0 + r)) * HID_ + h * 64 + d;
    *xp += acc;
  }
}

// =============================================================
extern "C" void kernel_launch(void* const* d_in, const int* in_sizes, int n_in,
                              void* d_out, int out_size, void* d_ws, size_t ws_size,
                              hipStream_t stream)
{
  (void)in_sizes; (void)n_in; (void)out_size; (void)ws_size;
  const float* x      = (const float*)d_in[0];
  const float* qkv_w  = (const float*)d_in[1];
  const float* qkv_b  = (const float*)d_in[2];
  const float* conv_w = (const float*)d_in[3];
  const float* out_w  = (const float*)d_in[4];
  const float* out_b  = (const float*)d_in[5];
  float* out = (float*)d_out;

  // workspace layout (floats). total ~74.3 MiB; Xc aliases dead K buffer.
  float* ws   = (float*)d_ws;
  float* Q    = ws;                       // [BH,S,D]  6291456
  float* K    = ws + 6291456;             // [BH,S,D]
  float* V    = ws + 12582912;            // [BH,S,D]
  float* Ql   = ws + 18874368;            // [BH,M,D]  98304
  float* Kl   = Ql + 98304;
  float* K2   = Kl + 98304;               // [BH,M,M]
  float* Vinv = K2 + 98304;
  float* W1   = Vinv + 98304;
  float* W2   = W1 + 98304;
  float* colmax = W2 + 98304;             // [BH]
  float* rowmax = colmax + BH_;
  float* Xc   = K;                        // alias: K dead after k3v_fused

  gemm_fp32<0><<<dim3(18, 64), 256, 0, stream>>>(x, qkv_w, qkv_b, Q, K, V);
  landmarks_kernel<<<BH_ * 64, 64, 0, stream>>>(Q, K, Ql, Kl);
  kernel2_softmax<<<BH_, 256, 0, stream>>>(Ql, Kl, K2, colmax, rowmax);
  newton_inv<<<BH_, 256, 0, stream>>>(K2, colmax, rowmax, Vinv);
  k3v_fused<<<BH_ * 64, 256, 0, stream>>>(Ql, K, V, W1);
  w2_small<<<BH_, 256, 0, stream>>>(Vinv, W1, W2);
  attn_core<<<BH_ * 16, 256, 0, stream>>>(Q, Kl, W2, Xc);
  conv_add<<<BH_ * 32, 256, 0, stream>>>(V, conv_w, Xc);
  gemm_fp32<1><<<dim3(6, 64), 256, 0, stream>>>(Xc, out_w, out_b, out, nullptr, nullptr);
}

// Round 2
// 643.460 us; speedup vs baseline: 1.5005x; 1.5005x over previous
//
#include <hip/hip_runtime.h>
#include <math.h>

#define B_   2
#define S_   4096
#define HID_ 768
#define H_   12
#define D_   64
#define M_   64
#define CK_  33
#define BH_  (B_*H_)   // 24
#define KD_  768

typedef float  f32x4  __attribute__((ext_vector_type(4)));
typedef short  bf16x8 __attribute__((ext_vector_type(8)));
typedef unsigned short u16;

__device__ __forceinline__ u16 f2bf(float f) {
  unsigned int u = __float_as_uint(f);
  u += 0x7FFFu + ((u >> 16) & 1u);   // round-to-nearest-even
  return (u16)(u >> 16);
}
__device__ __forceinline__ float bf2f(u16 s) {
  return __uint_as_float(((unsigned int)s) << 16);
}

__device__ __forceinline__ void gld16(const void* g, void* l) {
  __builtin_amdgcn_global_load_lds(
      (const __attribute__((address_space(1))) void*)g,
      (__attribute__((address_space(3))) void*)l, 16, 0, 0);
}

// =============================================================
// split fp32 -> (hi, lo) bf16 pair. 8 elements / thread.
// =============================================================
__global__ __launch_bounds__(256) void split_pair(
    const float* __restrict__ src, u16* __restrict__ h, u16* __restrict__ l, int n8)
{
  const int i = blockIdx.x * 256 + threadIdx.x;
  if (i >= n8) return;
  const float4* s4 = (const float4*)src;
  const float4 a = s4[2 * i], b = s4[2 * i + 1];
  const float v[8] = {a.x, a.y, a.z, a.w, b.x, b.y, b.z, b.w};
  union { u16 u[8]; uint4 q; } hv, lv;
#pragma unroll
  for (int e = 0; e < 8; ++e) {
    const u16 hh = f2bf(v[e]);
    hv.u[e] = hh;
    lv.u[e] = f2bf(v[e] - bf2f(hh));
  }
  ((uint4*)h)[i] = hv.q;
  ((uint4*)l)[i] = lv.q;
}

// =============================================================
// Split-bf16 3-product MFMA GEMM: C = A @ W^T (+bias)
// A [M,768] as (Ah,Al) bf16 row-major; W [N,768] as (Bh,Bl) bf16 row-major.
// 128x128 tile, BK=32, 256 thr (4 waves, 2x2), 4x4 frags of 16x16x32.
// MODE 0: N=2304, scatter into Q/K/V [B,H,S,D].  MODE 1: N=768 row-major.
// =============================================================
template<int MODE>
__global__ __launch_bounds__(256) void gemm3_mfma(
    const u16* __restrict__ Ahg, const u16* __restrict__ Alg,
    const u16* __restrict__ Bhg, const u16* __restrict__ Blg,
    const float* __restrict__ bias,
    float* __restrict__ o0, float* __restrict__ o1, float* __restrict__ o2)
{
  __shared__ __align__(16) u16 Ah_s[128 * 32];
  __shared__ __align__(16) u16 Al_s[128 * 32];
  __shared__ __align__(16) u16 Bh_s[128 * 32];
  __shared__ __align__(16) u16 Bl_s[128 * 32];

  const int tid = threadIdx.x;
  const int m0 = blockIdx.y * 128;
  const int n0 = blockIdx.x * 128;
  const int wave = tid >> 6, lane = tid & 63;
  const int wm = wave >> 1, wn = wave & 1;
  const int lr = lane & 15, kg = lane >> 4;
  const int srow = tid >> 2;            // staging row 0..63
  const int sk = (tid & 3) * 8;         // staging k-offset (elems)

  const u16* pAh = Ahg + (size_t)(m0 + srow) * KD_ + sk;
  const u16* pAl = Alg + (size_t)(m0 + srow) * KD_ + sk;
  const u16* pBh = Bhg + (size_t)(n0 + srow) * KD_ + sk;
  const u16* pBl = Blg + (size_t)(n0 + srow) * KD_ + sk;

  f32x4 acc[4][4];
#pragma unroll
  for (int i = 0; i < 4; ++i)
#pragma unroll
    for (int j = 0; j < 4; ++j) acc[i][j] = (f32x4){0.f, 0.f, 0.f, 0.f};

  const int abase = (wm * 64 + lr) * 32 + kg * 8;
  const int bbase = (wn * 64 + lr) * 32 + kg * 8;

  for (int kt = 0; kt < KD_ / 32; ++kt) {
    __syncthreads();
    const size_t go = (size_t)kt * 32;
    gld16(pAh + go,                 Ah_s + tid * 8);
    gld16(pAh + go + 64 * KD_,      Ah_s + 2048 + tid * 8);
    gld16(pAl + go,                 Al_s + tid * 8);
    gld16(pAl + go + 64 * KD_,      Al_s + 2048 + tid * 8);
    gld16(pBh + go,                 Bh_s + tid * 8);
    gld16(pBh + go + 64 * KD_,      Bh_s + 2048 + tid * 8);
    gld16(pBl + go,                 Bl_s + tid * 8);
    gld16(pBl + go + 64 * KD_,      Bl_s + 2048 + tid * 8);
    __syncthreads();

    bf16x8 ah[4], al[4], bh[4], bl[4];
#pragma unroll
    for (int f = 0; f < 4; ++f) {
      ah[f] = *(const bf16x8*)&Ah_s[abase + f * 512];
      al[f] = *(const bf16x8*)&Al_s[abase + f * 512];
      bh[f] = *(const bf16x8*)&Bh_s[bbase + f * 512];
      bl[f] = *(const bf16x8*)&Bl_s[bbase + f * 512];
    }
#pragma unroll
    for (int i = 0; i < 4; ++i)
#pragma unroll
      for (int j = 0; j < 4; ++j) {
        acc[i][j] = __builtin_amdgcn_mfma_f32_16x16x32_bf16(ah[i], bh[j], acc[i][j], 0, 0, 0);
        acc[i][j] = __builtin_amdgcn_mfma_f32_16x16x32_bf16(ah[i], bl[j], acc[i][j], 0, 0, 0);
        acc[i][j] = __builtin_amdgcn_mfma_f32_16x16x32_bf16(al[i], bh[j], acc[i][j], 0, 0, 0);
      }
  }

  // epilogue: C/D layout col = lane&15, row = (lane>>4)*4 + r  [m89-verified]
#pragma unroll
  for (int i = 0; i < 4; ++i) {
    const int mbase = m0 + wm * 64 + i * 16 + kg * 4;
#pragma unroll
    for (int j = 0; j < 4; ++j) {
      const int ncol = n0 + wn * 64 + j * 16 + lr;
      const float bv = bias[ncol];
      if (MODE == 0) {
        const int part = (ncol >= 1536) ? 2 : (ncol >= 768 ? 1 : 0);
        const int within = ncol - part * 768;
        const int h0 = within >> 6, d = within & 63;
        float* base = (part == 0) ? o0 : ((part == 1) ? o1 : o2);
#pragma unroll
        for (int r = 0; r < 4; ++r) {
          const int row = mbase + r;
          const int b = row >> 12, s = row & (S_ - 1);
          base[(((size_t)(b * H_ + h0) * S_ + s) << 6) + d] = acc[i][j][r] + bv;
        }
      } else {
#pragma unroll
        for (int r = 0; r < 4; ++r) {
          const int row = mbase + r;
          o0[(size_t)row * HID_ + ncol] = acc[i][j][r] + bv;
        }
      }
    }
  }
}

// =============================================================
// Landmark means
// =============================================================
__global__ void landmarks_kernel(const float* __restrict__ Q,
                                 const float* __restrict__ K,
                                 float* __restrict__ Ql, float* __restrict__ Kl)
{
  const int blk = blockIdx.x;
  const int bh = blk >> 6, m = blk & 63;
  const int d = threadIdx.x;
  const float* qp = Q + ((size_t)bh * S_ + m * 64) * 64 + d;
  const float* kp = K + ((size_t)bh * S_ + m * 64) * 64 + d;
  float sq = 0.f, sk = 0.f;
  for (int j = 0; j < 64; ++j) { sq += qp[(size_t)j * 64]; sk += kp[(size_t)j * 64]; }
  Ql[((size_t)bh * M_ + m) * 64 + d] = sq * (1.f / 64.f);
  Kl[((size_t)bh * M_ + m) * 64 + d] = sk * (1.f / 64.f);
}

// =============================================================
// kernel_2 softmax + per-(b,h) max col/row sums
// =============================================================
__global__ __launch_bounds__(256) void kernel2_softmax(
    const float* __restrict__ Ql, const float* __restrict__ Kl,
    float* __restrict__ K2, float* __restrict__ colmax, float* __restrict__ rowmax)
{
  __shared__ float Qs[64][68], Ks[64][68], S2[64][68];
  __shared__ float red1[64], red2[64];
  const int bh = blockIdx.x, tid = threadIdx.x;
  for (int idx = tid; idx < 4096; idx += 256) {
    const int r = idx >> 6, c = idx & 63;
    Qs[r][c] = Ql[(size_t)bh * 4096 + idx];
    Ks[r][c] = Kl[(size_t)bh * 4096 + idx];
  }
  __syncthreads();
  for (int idx = tid; idx < 4096; idx += 256) {
    const int r = idx >> 6, c = idx & 63;
    float dot = 0.f;
#pragma unroll
    for (int k = 0; k < 64; k += 4) {
      const float4 a = *(const float4*)&Qs[r][k];
      const float4 b = *(const float4*)&Ks[c][k];
      dot += a.x * b.x + a.y * b.y + a.z * b.z + a.w * b.w;
    }
    S2[r][c] = dot * 0.125f;
  }
  __syncthreads();
  if (tid < 64) {
    const int r = tid;
    float mx = -1e30f;
    for (int c = 0; c < 64; ++c) mx = fmaxf(mx, S2[r][c]);
    float sum = 0.f;
    for (int c = 0; c < 64; ++c) { const float e = expf(S2[r][c] - mx); S2[r][c] = e; sum += e; }
    const float inv = 1.f / sum;
    for (int c = 0; c < 64; ++c) S2[r][c] *= inv;
  }
  __syncthreads();
  for (int idx = tid; idx < 4096; idx += 256)
    K2[(size_t)bh * 4096 + idx] = S2[idx >> 6][idx & 63];
  if (tid < 64) {
    float cs = 0.f, rs = 0.f;
    for (int m = 0; m < 64; ++m) { cs += S2[m][tid]; rs += S2[tid][m]; }
    red1[tid] = cs; red2[tid] = rs;
  }
  __syncthreads();
  if (tid == 0) {
    float mc = 0.f, mr = 0.f;
    for (int i = 0; i < 64; ++i) { mc = fmaxf(mc, red1[i]); mr = fmaxf(mr, red2[i]); }
    colmax[bh] = mc; rowmax[bh] = mr;
  }
}

// 64x64x64 matmul in LDS
__device__ inline void mm64(float (*C)[64], float (*A)[64], float (*B)[64], int tid)
{
  const int ry = tid >> 4, cx = tid & 15;
  const int r0 = ry * 4, c0 = cx * 4;
  float acc[4][4];
#pragma unroll
  for (int i = 0; i < 4; ++i)
#pragma unroll
    for (int j = 0; j < 4; ++j) acc[i][j] = 0.f;
  for (int k = 0; k < 64; k += 4) {
    float4 a[4], b[4];
#pragma unroll
    for (int i = 0; i < 4; ++i) a[i] = *(const float4*)&A[r0 + i][k];
#pragma unroll
    for (int j = 0; j < 4; ++j) b[j] = *(const float4*)&B[k + j][c0];
    const float bb[4][4] = {{b[0].x, b[0].y, b[0].z, b[0].w},
                            {b[1].x, b[1].y, b[1].z, b[1].w},
                            {b[2].x, b[2].y, b[2].z, b[2].w},
                            {b[3].x, b[3].y, b[3].z, b[3].w}};
    const float aa[4][4] = {{a[0].x, a[0].y, a[0].z, a[0].w},
                            {a[1].x, a[1].y, a[1].z, a[1].w},
                            {a[2].x, a[2].y, a[2].z, a[2].w},
                            {a[3].x, a[3].y, a[3].z, a[3].w}};
#pragma unroll
    for (int i = 0; i < 4; ++i)
#pragma unroll
      for (int j = 0; j < 4; ++j)
#pragma unroll
        for (int kk = 0; kk < 4; ++kk) acc[i][j] += aa[i][kk] * bb[kk][j];
  }
#pragma unroll
  for (int i = 0; i < 4; ++i)
    *(float4*)&C[r0 + i][c0] = make_float4(acc[i][0], acc[i][1], acc[i][2], acc[i][3]);
}

// =============================================================
// Newton-Schulz pseudo-inverse (6 iters, global scale)
// =============================================================
__global__ __launch_bounds__(256) void newton_inv(
    const float* __restrict__ K2, const float* __restrict__ colmax,
    const float* __restrict__ rowmax, float* __restrict__ Vinv)
{
  __shared__ float A_[64][64], V_[64][64], KV_[64][64], T_[64][64], U_[64][64];
  __shared__ float scale_s;
  const int bh = blockIdx.x, tid = threadIdx.x;
  if (tid == 0) {
    float mc = 0.f, mr = 0.f;
    for (int i = 0; i < BH_; ++i) { mc = fmaxf(mc, colmax[i]); mr = fmaxf(mr, rowmax[i]); }
    scale_s = 1.f / (mc * mr);
  }
  for (int idx = tid; idx < 4096; idx += 256)
    A_[idx >> 6][idx & 63] = K2[(size_t)bh * 4096 + idx];
  __syncthreads();
  const float scale = scale_s;
  for (int idx = tid; idx < 4096; idx += 256) {
    const int r = idx >> 6, c = idx & 63;
    V_[r][c] = scale * A_[c][r];
  }
  __syncthreads();
  for (int it = 0; it < 6; ++it) {
    mm64(KV_, A_, V_, tid); __syncthreads();
    for (int idx = tid; idx < 4096; idx += 256) {
      const int r = idx >> 6, c = idx & 63;
      T_[r][c] = (r == c ? 7.f : 0.f) - KV_[r][c];
    }
    __syncthreads();
    mm64(U_, KV_, T_, tid); __syncthreads();
    for (int idx = tid; idx < 4096; idx += 256) {
      const int r = idx >> 6, c = idx & 63;
      T_[r][c] = (r == c ? 15.f : 0.f) - U_[r][c];
    }
    __syncthreads();
    mm64(U_, KV_, T_, tid); __syncthreads();
    for (int idx = tid; idx < 4096; idx += 256) {
      const int r = idx >> 6, c = idx & 63;
      T_[r][c] = (r == c ? 13.f : 0.f) - U_[r][c];
    }
    __syncthreads();
    mm64(U_, V_, T_, tid); __syncthreads();
    for (int idx = tid; idx < 4096; idx += 256) {
      const int r = idx >> 6, c = idx & 63;
      V_[r][c] = 0.25f * U_[r][c];
    }
    __syncthreads();
  }
  for (int idx = tid; idx < 4096; idx += 256)
    Vinv[(size_t)bh * 4096 + idx] = V_[idx >> 6][idx & 63];
}

// =============================================================
// W1 = softmax(Ql @ K^T / 8, axis=S) @ V
// =============================================================
__global__ __launch_bounds__(256) void k3v_fused(
    const float* __restrict__ Ql, const float* __restrict__ K,
    const float* __restrict__ V, float* __restrict__ W1)
{
  __shared__ float sc[4096];
  __shared__ float qs[64];
  __shared__ float red[256];
  __shared__ float part[16][64];
  const int blk = blockIdx.x;
  const int bh = blk >> 6, m = blk & 63;
  const int tid = threadIdx.x;
  if (tid < 64) qs[tid] = Ql[((size_t)bh * 64 + m) * 64 + tid];
  __syncthreads();
  const float* Kb = K + (size_t)bh * S_ * 64;
  const float* Vb = V + (size_t)bh * S_ * 64;
  float lmax = -1e30f;
  for (int s = tid; s < S_; s += 256) {
    float dot = 0.f;
#pragma unroll
    for (int k = 0; k < 64; k += 4) {
      const float4 kv = *(const float4*)&Kb[(size_t)s * 64 + k];
      const float4 qv = *(const float4*)&qs[k];
      dot += kv.x * qv.x + kv.y * qv.y + kv.z * qv.z + kv.w * qv.w;
    }
    dot *= 0.125f;
    sc[s] = dot;
    lmax = fmaxf(lmax, dot);
  }
  red[tid] = lmax; __syncthreads();
  for (int off = 128; off > 0; off >>= 1) {
    if (tid < off) red[tid] = fmaxf(red[tid], red[tid + off]);
    __syncthreads();
  }
  const float gmax = red[0];
  __syncthreads();
  float lsum = 0.f;
  for (int s = tid; s < S_; s += 256) { const float e = expf(sc[s] - gmax); sc[s] = e; lsum += e; }
  red[tid] = lsum; __syncthreads();
  for (int off = 128; off > 0; off >>= 1) {
    if (tid < off) red[tid] += red[tid + off];
    __syncthreads();
  }
  const float inv = 1.f / red[0];
  __syncthreads();
  const int g = tid >> 4, d4 = (tid & 15) * 4;
  float4 acc = make_float4(0.f, 0.f, 0.f, 0.f);
  for (int s = g; s < S_; s += 16) {
    const float p = sc[s];
    const float4 v = *(const float4*)&Vb[(size_t)s * 64 + d4];
    acc.x += p * v.x; acc.y += p * v.y; acc.z += p * v.z; acc.w += p * v.w;
  }
  *(float4*)&part[g][d4] = acc;
  __syncthreads();
  if (tid < 64) {
    float r2 = 0.f;
    for (int gg = 0; gg < 16; ++gg) r2 += part[gg][tid];
    W1[((size_t)bh * 64 + m) * 64 + tid] = r2 * inv;
  }
}

// W2 = Vinv @ W1
__global__ __launch_bounds__(256) void w2_small(
    const float* __restrict__ Vinv, const float* __restrict__ W1, float* __restrict__ W2)
{
  __shared__ float A_[64][64], B2[64][64], C_[64][64];
  const int bh = blockIdx.x, tid = threadIdx.x;
  for (int idx = tid; idx < 4096; idx += 256) {
    A_[idx >> 6][idx & 63] = Vinv[(size_t)bh * 4096 + idx];
    B2[idx >> 6][idx & 63] = W1[(size_t)bh * 4096 + idx];
  }
  __syncthreads();
  mm64(C_, A_, B2, tid);
  __syncthreads();
  for (int idx = tid; idx < 4096; idx += 256)
    W2[(size_t)bh * 4096 + idx] = C_[idx >> 6][idx & 63];
}

// =============================================================
// X = softmax(Q @ Kl^T / 8) @ W2  -> Xc [B,S,HID] fp32
// =============================================================
__global__ __launch_bounds__(256) void attn_core(
    const float* __restrict__ Q, const float* __restrict__ Kl,
    const float* __restrict__ W2, float* __restrict__ Xc)
{
  __shared__ float Kls[64][64];
  __shared__ float W2s[64][64];
  const int blk = blockIdx.x;
  const int bh = blk >> 4, chunk = blk & 15;
  const int tid = threadIdx.x;
  const int b = bh / H_, h = bh % H_;
  for (int idx = tid; idx < 4096; idx += 256) {
    Kls[idx >> 6][idx & 63] = Kl[(size_t)bh * 4096 + idx];
    W2s[idx >> 6][idx & 63] = W2[(size_t)bh * 4096 + idx];
  }
  __syncthreads();
  const int s = chunk * 256 + tid;
  const float* qp = Q + ((size_t)bh * S_ + s) * 64;
  float4 q4[16];
#pragma unroll
  for (int k = 0; k < 16; ++k) q4[k] = *(const float4*)&qp[k * 4];
  float p[64];
#pragma unroll
  for (int m = 0; m < 64; ++m) {
    float dot = 0.f;
#pragma unroll
    for (int k = 0; k < 16; ++k) {
      const float4 kv = *(const float4*)&Kls[m][k * 4];
      dot += q4[k].x * kv.x + q4[k].y * kv.y + q4[k].z * kv.z + q4[k].w * kv.w;
    }
    p[m] = dot * 0.125f;
  }
  float mx = -1e30f;
#pragma unroll
  for (int m = 0; m < 64; ++m) mx = fmaxf(mx, p[m]);
  float sum = 0.f;
#pragma unroll
  for (int m = 0; m < 64; ++m) { p[m] = expf(p[m] - mx); sum += p[m]; }
  const float inv = 1.f / sum;
#pragma unroll
  for (int m = 0; m < 64; ++m) p[m] *= inv;
  float4 o4[16];
#pragma unroll
  for (int k = 0; k < 16; ++k) o4[k] = make_float4(0.f, 0.f, 0.f, 0.f);
#pragma unroll
  for (int m = 0; m < 64; ++m) {
    const float pm = p[m];
#pragma unroll
    for (int k = 0; k < 16; ++k) {
      const float4 wv = *(const float4*)&W2s[m][k * 4];
      o4[k].x += pm * wv.x; o4[k].y += pm * wv.y;
      o4[k].z += pm * wv.z; o4[k].w += pm * wv.w;
    }
  }
  float* xp = Xc + ((size_t)(b * S_ + s)) * HID_ + h * 64;
#pragma unroll
  for (int k = 0; k < 16; ++k) *(float4*)&xp[k * 4] = o4[k];
}

// =============================================================
// Depthwise conv + add attn, write split-bf16 (input of out-GEMM)
// =============================================================
__global__ __launch_bounds__(256) void conv_add_split(
    const float* __restrict__ V, const float* __restrict__ cw,
    const float* __restrict__ Xc, u16* __restrict__ Xch, u16* __restrict__ Xcl)
{
  __shared__ float Vs[160][64];
  __shared__ float cws[33];
  const int blk = blockIdx.x;
  const int bh = blk >> 5, chunk = blk & 31;
  const int tid = threadIdx.x;
  const int b = bh / H_, h = bh % H_;
  const int s0 = chunk * 128;
  if (tid < 33) cws[tid] = cw[h * 33 + tid];
  const float* Vb = V + (size_t)bh * S_ * 64;
  for (int idx = tid; idx < 160 * 64; idx += 256) {
    const int r = idx >> 6, c = idx & 63;
    const int sv = s0 - 16 + r;
    Vs[r][c] = (sv >= 0 && sv < S_) ? Vb[(size_t)sv * 64 + c] : 0.f;
  }
  __syncthreads();
  const int d = tid & 63, rg = tid >> 6;
  for (int rr = 0; rr < 32; ++rr) {
    const int r = rg * 32 + rr;
    float acc = 0.f;
#pragma unroll
    for (int t = 0; t < 33; ++t) acc += Vs[r + t][d] * cws[t];
    const size_t idx = ((size_t)(b * S_ + s0 + r)) * HID_ + h * 64 + d;
    const float o = Xc[idx] + acc;
    const u16 hh = f2bf(o);
    Xch[idx] = hh;
    Xcl[idx] = f2bf(o - bf2f(hh));
  }
}

// =============================================================
extern "C" void kernel_launch(void* const* d_in, const int* in_sizes, int n_in,
                              void* d_out, int out_size, void* d_ws, size_t ws_size,
                              hipStream_t stream)
{
  (void)in_sizes; (void)n_in; (void)out_size; (void)ws_size;
  const float* x      = (const float*)d_in[0];
  const float* qkv_w  = (const float*)d_in[1];
  const float* qkv_b  = (const float*)d_in[2];
  const float* conv_w = (const float*)d_in[3];
  const float* out_w  = (const float*)d_in[4];
  const float* out_b  = (const float*)d_in[5];
  float* out = (float*)d_out;

  // fp32 region
  float* ws   = (float*)d_ws;
  float* Q    = ws;                       // [BH,S,D] 6291456
  float* K    = Q + 6291456;
  float* V    = K + 6291456;
  float* Ql   = V + 6291456;              // 98304 each below
  float* Kl   = Ql + 98304;
  float* K2   = Kl + 98304;
  float* Vinv = K2 + 98304;
  float* W1   = Vinv + 98304;
  float* W2   = W1 + 98304;
  float* colmax = W2 + 98304;
  float* rowmax = colmax + 32;
  // bf16 (u16) region
  u16* ub  = (u16*)(rowmax + 32);
  u16* Xh  = ub;                          // 6291456
  u16* Xl  = Xh + 6291456;
  u16* Wqh = Xl + 6291456;                // 1769472
  u16* Wql = Wqh + 1769472;
  u16* Woh = Wql + 1769472;               // 589824
  u16* Wol = Woh + 589824;
  // aliases
  u16* Xch = Xh;                          // Xh/Xl dead after QKV GEMM
  u16* Xcl = Xl;
  float* Xc = K;                          // K dead after k3v_fused

  split_pair<<<786432 / 256, 256, 0, stream>>>(x, Xh, Xl, 786432);
  split_pair<<<221184 / 256, 256, 0, stream>>>(qkv_w, Wqh, Wql, 221184);
  split_pair<<<73728 / 256, 256, 0, stream>>>(out_w, Woh, Wol, 73728);

  gemm3_mfma<0><<<dim3(18, 64), 256, 0, stream>>>(Xh, Xl, Wqh, Wql, qkv_b, Q, K, V);

  landmarks_kernel<<<BH_ * 64, 64, 0, stream>>>(Q, K, Ql, Kl);
  kernel2_softmax<<<BH_, 256, 0, stream>>>(Ql, Kl, K2, colmax, rowmax);
  newton_inv<<<BH_, 256, 0, stream>>>(K2, colmax, rowmax, Vinv);
  k3v_fused<<<BH_ * 64, 256, 0, stream>>>(Ql, K, V, W1);
  w2_small<<<BH_, 256, 0, stream>>>(Vinv, W1, W2);
  attn_core<<<BH_ * 16, 256, 0, stream>>>(Q, Kl, W2, Xc);
  conv_add_split<<<BH_ * 32, 256, 0, stream>>>(V, conv_w, Xc, Xch, Xcl);

  gemm3_mfma<1><<<dim3(6, 64), 256, 0, stream>>>(Xch, Xcl, Woh, Wol, out_b, out, nullptr, nullptr);
}

// Round 3
// 407.621 us; speedup vs baseline: 2.3687x; 1.5786x over previous
//
#include <hip/hip_runtime.h>
#include <math.h>

#define B_   2
#define S_   4096
#define HID_ 768
#define H_   12
#define D_   64
#define M_   64
#define CK_  33
#define BH_  (B_*H_)   // 24
#define KD_  768
#define NCH_ 32        // k3v S-chunks
#define SC_  128       // keys per chunk

typedef float  f32x4  __attribute__((ext_vector_type(4)));
typedef short  bf16x8 __attribute__((ext_vector_type(8)));
typedef unsigned short u16;

__device__ __forceinline__ u16 f2bf(float f) {
  unsigned int u = __float_as_uint(f);
  u += 0x7FFFu + ((u >> 16) & 1u);   // round-to-nearest-even
  return (u16)(u >> 16);
}
__device__ __forceinline__ float bf2f(u16 s) {
  return __uint_as_float(((unsigned int)s) << 16);
}
// two float4 -> bf16x8 (hi) + bf16x8 (lo residual)
__device__ __forceinline__ void cvt8(const float4 a, const float4 b,
                                     bf16x8* hi, bf16x8* lo) {
  const float v[8] = {a.x, a.y, a.z, a.w, b.x, b.y, b.z, b.w};
  union { u16 u[8]; bf16x8 v; } H, L;
#pragma unroll
  for (int e = 0; e < 8; ++e) {
    const u16 hh = f2bf(v[e]);
    H.u[e] = hh;
    L.u[e] = f2bf(v[e] - bf2f(hh));
  }
  *hi = H.v; *lo = L.v;
}

__device__ __forceinline__ void gld16(const void* g, void* l) {
  __builtin_amdgcn_global_load_lds(
      (const __attribute__((address_space(1))) void*)g,
      (__attribute__((address_space(3))) void*)l, 16, 0, 0);
}

// =============================================================
// split fp32 -> (hi, lo) bf16 pair. 8 elements / thread.
// =============================================================
__global__ __launch_bounds__(256) void split_pair(
    const float* __restrict__ src, u16* __restrict__ h, u16* __restrict__ l, int n8)
{
  const int i = blockIdx.x * 256 + threadIdx.x;
  if (i >= n8) return;
  const float4* s4 = (const float4*)src;
  const float4 a = s4[2 * i], b = s4[2 * i + 1];
  const float v[8] = {a.x, a.y, a.z, a.w, b.x, b.y, b.z, b.w};
  union { u16 u[8]; uint4 q; } hv, lv;
#pragma unroll
  for (int e = 0; e < 8; ++e) {
    const u16 hh = f2bf(v[e]);
    hv.u[e] = hh;
    lv.u[e] = f2bf(v[e] - bf2f(hh));
  }
  ((uint4*)h)[i] = hv.q;
  ((uint4*)l)[i] = lv.q;
}

// =============================================================
// Split-bf16 3-product MFMA GEMM: C = A @ W^T (+bias)
// =============================================================
template<int MODE>
__global__ __launch_bounds__(256) void gemm3_mfma(
    const u16* __restrict__ Ahg, const u16* __restrict__ Alg,
    const u16* __restrict__ Bhg, const u16* __restrict__ Blg,
    const float* __restrict__ bias,
    float* __restrict__ o0, float* __restrict__ o1, float* __restrict__ o2)
{
  __shared__ __align__(16) u16 Ah_s[128 * 32];
  __shared__ __align__(16) u16 Al_s[128 * 32];
  __shared__ __align__(16) u16 Bh_s[128 * 32];
  __shared__ __align__(16) u16 Bl_s[128 * 32];

  const int tid = threadIdx.x;
  const int m0 = blockIdx.y * 128;
  const int n0 = blockIdx.x * 128;
  const int wave = tid >> 6, lane = tid & 63;
  const int wm = wave >> 1, wn = wave & 1;
  const int lr = lane & 15, kg = lane >> 4;

  const int srow = tid >> 2;
  const int sk = (tid & 3) * 8;

  const u16* pAh = Ahg + (size_t)(m0 + srow) * KD_ + sk;
  const u16* pAl = Alg + (size_t)(m0 + srow) * KD_ + sk;
  const u16* pBh = Bhg + (size_t)(n0 + srow) * KD_ + sk;
  const u16* pBl = Blg + (size_t)(n0 + srow) * KD_ + sk;

  f32x4 acc[4][4];
#pragma unroll
  for (int i = 0; i < 4; ++i)
#pragma unroll
    for (int j = 0; j < 4; ++j) acc[i][j] = (f32x4){0.f, 0.f, 0.f, 0.f};

  const int abase = (wm * 64 + lr) * 32 + kg * 8;
  const int bbase = (wn * 64 + lr) * 32 + kg * 8;

  for (int kt = 0; kt < KD_ / 32; ++kt) {
    __syncthreads();
    const size_t go = (size_t)kt * 32;
    gld16(pAh + go,                 Ah_s + tid * 8);
    gld16(pAh + go + 64 * KD_,      Ah_s + 2048 + tid * 8);
    gld16(pAl + go,                 Al_s + tid * 8);
    gld16(pAl + go + 64 * KD_,      Al_s + 2048 + tid * 8);
    gld16(pBh + go,                 Bh_s + tid * 8);
    gld16(pBh + go + 64 * KD_,      Bh_s + 2048 + tid * 8);
    gld16(pBl + go,                 Bl_s + tid * 8);
    gld16(pBl + go + 64 * KD_,      Bl_s + 2048 + tid * 8);
    __syncthreads();

    bf16x8 ah[4], al[4], bh[4], bl[4];
#pragma unroll
    for (int f = 0; f < 4; ++f) {
      ah[f] = *(const bf16x8*)&Ah_s[abase + f * 512];
      al[f] = *(const bf16x8*)&Al_s[abase + f * 512];
      bh[f] = *(const bf16x8*)&Bh_s[bbase + f * 512];
      bl[f] = *(const bf16x8*)&Bl_s[bbase + f * 512];
    }
#pragma unroll
    for (int i = 0; i < 4; ++i)
#pragma unroll
      for (int j = 0; j < 4; ++j) {
        acc[i][j] = __builtin_amdgcn_mfma_f32_16x16x32_bf16(ah[i], bh[j], acc[i][j], 0, 0, 0);
        acc[i][j] = __builtin_amdgcn_mfma_f32_16x16x32_bf16(ah[i], bl[j], acc[i][j], 0, 0, 0);
        acc[i][j] = __builtin_amdgcn_mfma_f32_16x16x32_bf16(al[i], bh[j], acc[i][j], 0, 0, 0);
      }
  }

#pragma unroll
  for (int i = 0; i < 4; ++i) {
    const int mbase = m0 + wm * 64 + i * 16 + kg * 4;
#pragma unroll
    for (int j = 0; j < 4; ++j) {
      const int ncol = n0 + wn * 64 + j * 16 + lr;
      const float bv = bias[ncol];
      if (MODE == 0) {
        const int part = (ncol >= 1536) ? 2 : (ncol >= 768 ? 1 : 0);
        const int within = ncol - part * 768;
        const int h0 = within >> 6, d = within & 63;
        float* base = (part == 0) ? o0 : ((part == 1) ? o1 : o2);
#pragma unroll
        for (int r = 0; r < 4; ++r) {
          const int row = mbase + r;
          const int b = row >> 12, s = row & (S_ - 1);
          base[(((size_t)(b * H_ + h0) * S_ + s) << 6) + d] = acc[i][j][r] + bv;
        }
      } else {
#pragma unroll
        for (int r = 0; r < 4; ++r) {
          const int row = mbase + r;
          o0[(size_t)row * HID_ + ncol] = acc[i][j][r] + bv;
        }
      }
    }
  }
}

// =============================================================
// Landmark means
// =============================================================
__global__ void landmarks_kernel(const float* __restrict__ Q,
                                 const float* __restrict__ K,
                                 float* __restrict__ Ql, float* __restrict__ Kl)
{
  const int blk = blockIdx.x;
  const int bh = blk >> 6, m = blk & 63;
  const int d = threadIdx.x;
  const float* qp = Q + ((size_t)bh * S_ + m * 64) * 64 + d;
  const float* kp = K + ((size_t)bh * S_ + m * 64) * 64 + d;
  float sq = 0.f, sk = 0.f;
  for (int j = 0; j < 64; ++j) { sq += qp[(size_t)j * 64]; sk += kp[(size_t)j * 64]; }
  Ql[((size_t)bh * M_ + m) * 64 + d] = sq * (1.f / 64.f);
  Kl[((size_t)bh * M_ + m) * 64 + d] = sk * (1.f / 64.f);
}

// =============================================================
// kernel_2 softmax + per-(b,h) max col/row sums
// =============================================================
__global__ __launch_bounds__(256) void kernel2_softmax(
    const float* __restrict__ Ql, const float* __restrict__ Kl,
    float* __restrict__ K2, float* __restrict__ colmax, float* __restrict__ rowmax)
{
  __shared__ float Qs[64][68], Ks[64][68], S2[64][68];
  __shared__ float red1[64], red2[64];
  const int bh = blockIdx.x, tid = threadIdx.x;
  for (int idx = tid; idx < 4096; idx += 256) {
    const int r = idx >> 6, c = idx & 63;
    Qs[r][c] = Ql[(size_t)bh * 4096 + idx];
    Ks[r][c] = Kl[(size_t)bh * 4096 + idx];
  }
  __syncthreads();
  for (int idx = tid; idx < 4096; idx += 256) {
    const int r = idx >> 6, c = idx & 63;
    float dot = 0.f;
#pragma unroll
    for (int k = 0; k < 64; k += 4) {
      const float4 a = *(const float4*)&Qs[r][k];
      const float4 b = *(const float4*)&Ks[c][k];
      dot += a.x * b.x + a.y * b.y + a.z * b.z + a.w * b.w;
    }
    S2[r][c] = dot * 0.125f;
  }
  __syncthreads();
  if (tid < 64) {
    const int r = tid;
    float mx = -1e30f;
    for (int c = 0; c < 64; ++c) mx = fmaxf(mx, S2[r][c]);
    float sum = 0.f;
    for (int c = 0; c < 64; ++c) { const float e = expf(S2[r][c] - mx); S2[r][c] = e; sum += e; }
    const float inv = 1.f / sum;
    for (int c = 0; c < 64; ++c) S2[r][c] *= inv;
  }
  __syncthreads();
  for (int idx = tid; idx < 4096; idx += 256)
    K2[(size_t)bh * 4096 + idx] = S2[idx >> 6][idx & 63];
  if (tid < 64) {
    float cs = 0.f, rs = 0.f;
    for (int m = 0; m < 64; ++m) { cs += S2[m][tid]; rs += S2[tid][m]; }
    red1[tid] = cs; red2[tid] = rs;
  }
  __syncthreads();
  if (tid == 0) {
    float mc = 0.f, mr = 0.f;
    for (int i = 0; i < 64; ++i) { mc = fmaxf(mc, red1[i]); mr = fmaxf(mr, red2[i]); }
    colmax[bh] = mc; rowmax[bh] = mr;
  }
}

// 64x64x64 matmul in LDS
__device__ inline void mm64(float (*C)[64], float (*A)[64], float (*B)[64], int tid)
{
  const int ry = tid >> 4, cx = tid & 15;
  const int r0 = ry * 4, c0 = cx * 4;
  float acc[4][4];
#pragma unroll
  for (int i = 0; i < 4; ++i)
#pragma unroll
    for (int j = 0; j < 4; ++j) acc[i][j] = 0.f;
  for (int k = 0; k < 64; k += 4) {
    float4 a[4], b[4];
#pragma unroll
    for (int i = 0; i < 4; ++i) a[i] = *(const float4*)&A[r0 + i][k];
#pragma unroll
    for (int j = 0; j < 4; ++j) b[j] = *(const float4*)&B[k + j][c0];
    const float bb[4][4] = {{b[0].x, b[0].y, b[0].z, b[0].w},
                            {b[1].x, b[1].y, b[1].z, b[1].w},
                            {b[2].x, b[2].y, b[2].z, b[2].w},
                            {b[3].x, b[3].y, b[3].z, b[3].w}};
    const float aa[4][4] = {{a[0].x, a[0].y, a[0].z, a[0].w},
                            {a[1].x, a[1].y, a[1].z, a[1].w},
                            {a[2].x, a[2].y, a[2].z, a[2].w},
                            {a[3].x, a[3].y, a[3].z, a[3].w}};
#pragma unroll
    for (int i = 0; i < 4; ++i)
#pragma unroll
      for (int j = 0; j < 4; ++j)
#pragma unroll
        for (int kk = 0; kk < 4; ++kk) acc[i][j] += aa[i][kk] * bb[kk][j];
  }
#pragma unroll
  for (int i = 0; i < 4; ++i)
    *(float4*)&C[r0 + i][c0] = make_float4(acc[i][0], acc[i][1], acc[i][2], acc[i][3]);
}

// =============================================================
// Newton-Schulz pseudo-inverse (6 iters, global scale)
// =============================================================
__global__ __launch_bounds__(256) void newton_inv(
    const float* __restrict__ K2, const float* __restrict__ colmax,
    const float* __restrict__ rowmax, float* __restrict__ Vinv)
{
  __shared__ float A_[64][64], V_[64][64], KV_[64][64], T_[64][64], U_[64][64];
  __shared__ float scale_s;
  const int bh = blockIdx.x, tid = threadIdx.x;
  if (tid == 0) {
    float mc = 0.f, mr = 0.f;
    for (int i = 0; i < BH_; ++i) { mc = fmaxf(mc, colmax[i]); mr = fmaxf(mr, rowmax[i]); }
    scale_s = 1.f / (mc * mr);
  }
  for (int idx = tid; idx < 4096; idx += 256)
    A_[idx >> 6][idx & 63] = K2[(size_t)bh * 4096 + idx];
  __syncthreads();
  const float scale = scale_s;
  for (int idx = tid; idx < 4096; idx += 256) {
    const int r = idx >> 6, c = idx & 63;
    V_[r][c] = scale * A_[c][r];
  }
  __syncthreads();
  for (int it = 0; it < 6; ++it) {
    mm64(KV_, A_, V_, tid); __syncthreads();
    for (int idx = tid; idx < 4096; idx += 256) {
      const int r = idx >> 6, c = idx & 63;
      T_[r][c] = (r == c ? 7.f : 0.f) - KV_[r][c];
    }
    __syncthreads();
    mm64(U_, KV_, T_, tid); __syncthreads();
    for (int idx = tid; idx < 4096; idx += 256) {
      const int r = idx >> 6, c = idx & 63;
      T_[r][c] = (r == c ? 15.f : 0.f) - U_[r][c];
    }
    __syncthreads();
    mm64(U_, KV_, T_, tid); __syncthreads();
    for (int idx = tid; idx < 4096; idx += 256) {
      const int r = idx >> 6, c = idx & 63;
      T_[r][c] = (r == c ? 13.f : 0.f) - U_[r][c];
    }
    __syncthreads();
    mm64(U_, V_, T_, tid); __syncthreads();
    for (int idx = tid; idx < 4096; idx += 256) {
      const int r = idx >> 6, c = idx & 63;
      V_[r][c] = 0.25f * U_[r][c];
    }
    __syncthreads();
  }
  for (int idx = tid; idx < 4096; idx += 256)
    Vinv[(size_t)bh * 4096 + idx] = V_[idx >> 6][idx & 63];
}

// =============================================================
// k3v pass 1: per (bh, chunk of 128 keys):
//   S = Ql @ K_chunk^T / 8   (MFMA, split-bf16, on-the-fly cvt)
//   per-chunk row max m_j, l_j = sum exp(S - m_j)
//   O_j = exp(S - m_j) @ V_chunk   (fp32 VALU)
// =============================================================
__global__ __launch_bounds__(256) void k3v_pass1(
    const float* __restrict__ Ql, const float* __restrict__ K,
    const float* __restrict__ V, float* __restrict__ Opart,
    float* __restrict__ mpart, float* __restrict__ lpart)
{
  __shared__ float P[64][132];
  __shared__ float red1[64][4], red2[64][4];

  const int ch = blockIdx.x;     // 0..31
  const int bh = blockIdx.y;     // 0..23
  const int tid = threadIdx.x;
  const int wave = tid >> 6, lane = tid & 63;
  const int lr = lane & 15, kg = lane >> 4;

  const float* Qlb = Ql + (size_t)bh * 4096;
  const float* Kb  = K + (size_t)bh * S_ * 64;
  const float* Vb  = V + (size_t)bh * S_ * 64;

  // --- Ql fragments in registers: [mt 0..3][kk 0..1] hi/lo ---
  bf16x8 ah[4][2], al[4][2];
#pragma unroll
  for (int mt = 0; mt < 4; ++mt)
#pragma unroll
    for (int kk = 0; kk < 2; ++kk) {
      const float* qr = Qlb + (size_t)(mt * 16 + lr) * 64 + kk * 32 + kg * 8;
      cvt8(*(const float4*)qr, *(const float4*)(qr + 4), &ah[mt][kk], &al[mt][kk]);
    }

  // --- scores: each wave does 2 s-tiles of 16 ---
#pragma unroll
  for (int t = 0; t < 2; ++t) {
    const int s0 = (wave * 2 + t) * 16;
    const int srow = ch * SC_ + s0 + lr;
    f32x4 acc[4];
#pragma unroll
    for (int mt = 0; mt < 4; ++mt) acc[mt] = (f32x4){0.f, 0.f, 0.f, 0.f};
#pragma unroll
    for (int kk = 0; kk < 2; ++kk) {
      const float* kr = Kb + (size_t)srow * 64 + kk * 32 + kg * 8;
      bf16x8 bhf, blf;
      cvt8(*(const float4*)kr, *(const float4*)(kr + 4), &bhf, &blf);
#pragma unroll
      for (int mt = 0; mt < 4; ++mt) {
        acc[mt] = __builtin_amdgcn_mfma_f32_16x16x32_bf16(ah[mt][kk], bhf, acc[mt], 0, 0, 0);
        acc[mt] = __builtin_amdgcn_mfma_f32_16x16x32_bf16(ah[mt][kk], blf, acc[mt], 0, 0, 0);
        acc[mt] = __builtin_amdgcn_mfma_f32_16x16x32_bf16(al[mt][kk], bhf, acc[mt], 0, 0, 0);
      }
    }
    // write to P: row m = mt*16 + kg*4 + r, col s = s0 + lr
#pragma unroll
    for (int mt = 0; mt < 4; ++mt)
#pragma unroll
      for (int r = 0; r < 4; ++r)
        P[mt * 16 + kg * 4 + r][s0 + lr] = acc[mt][r] * 0.125f;
  }
  __syncthreads();

  // --- softmax partials: 4 threads per row ---
  const int r = tid >> 2, q = tid & 3;
  {
    float mx = -1e30f;
#pragma unroll
    for (int s = 0; s < 32; ++s) mx = fmaxf(mx, P[r][q * 32 + s]);
    red1[r][q] = mx;
  }
  __syncthreads();
  const float rowmax = fmaxf(fmaxf(red1[r][0], red1[r][1]),
                             fmaxf(red1[r][2], red1[r][3]));
  {
    float sum = 0.f;
#pragma unroll
    for (int s = 0; s < 32; ++s) {
      const float e = expf(P[r][q * 32 + s] - rowmax);
      P[r][q * 32 + s] = e;
      sum += e;
    }
    red2[r][q] = sum;
  }
  __syncthreads();
  if (q == 0) {
    const float rowsum = red2[r][0] + red2[r][1] + red2[r][2] + red2[r][3];
    mpart[((size_t)bh * NCH_ + ch) * 64 + r] = rowmax;
    lpart[((size_t)bh * NCH_ + ch) * 64 + r] = rowsum;
  }

  // --- O_j = P @ V_chunk (fp32) ---
  const int mg = tid >> 4, dq = (tid & 15) * 4;
  float4 oacc[4];
#pragma unroll
  for (int i = 0; i < 4; ++i) oacc[i] = make_float4(0.f, 0.f, 0.f, 0.f);
  for (int s = 0; s < SC_; ++s) {
    const float4 v = *(const float4*)&Vb[(size_t)(ch * SC_ + s) * 64 + dq];
#pragma unroll
    for (int i = 0; i < 4; ++i) {
      const float p = P[mg * 4 + i][s];
      oacc[i].x += p * v.x; oacc[i].y += p * v.y;
      oacc[i].z += p * v.z; oacc[i].w += p * v.w;
    }
  }
#pragma unroll
  for (int i = 0; i < 4; ++i) {
    const size_t o = (((size_t)bh * NCH_ + ch) * 64 + mg * 4 + i) * 64 + dq;
    *(float4*)&Opart[o] = oacc[i];
  }
}

// =============================================================
// k3v pass 2: combine chunks -> W1 [bh,64,64]
// =============================================================
__global__ __launch_bounds__(256) void k3v_combine(
    const float* __restrict__ Opart, const float* __restrict__ mpart,
    const float* __restrict__ lpart, float* __restrict__ W1)
{
  __shared__ float w[64][33];
  const int bh = blockIdx.x, tid = threadIdx.x;
  if (tid < 64) {
    const int m = tid;
    float M = -1e30f;
    for (int j = 0; j < NCH_; ++j)
      M = fmaxf(M, mpart[((size_t)bh * NCH_ + j) * 64 + m]);
    float denom = 0.f;
    for (int j = 0; j < NCH_; ++j)
      denom += expf(mpart[((size_t)bh * NCH_ + j) * 64 + m] - M) *
               lpart[((size_t)bh * NCH_ + j) * 64 + m];
    const float inv = 1.f / denom;
    for (int j = 0; j < NCH_; ++j)
      w[m][j] = expf(mpart[((size_t)bh * NCH_ + j) * 64 + m] - M) * inv;
  }
  __syncthreads();
  const int mg = tid >> 4, dq = (tid & 15) * 4;
#pragma unroll
  for (int i = 0; i < 4; ++i) {
    const int m = mg * 4 + i;
    float4 acc = make_float4(0.f, 0.f, 0.f, 0.f);
    for (int j = 0; j < NCH_; ++j) {
      const float ww = w[m][j];
      const float4 o = *(const float4*)&Opart[(((size_t)bh * NCH_ + j) * 64 + m) * 64 + dq];
      acc.x += ww * o.x; acc.y += ww * o.y; acc.z += ww * o.z; acc.w += ww * o.w;
    }
    *(float4*)&W1[((size_t)bh * 64 + m) * 64 + dq] = acc;
  }
}

// W2 = Vinv @ W1
__global__ __launch_bounds__(256) void w2_small(
    const float* __restrict__ Vinv, const float* __restrict__ W1, float* __restrict__ W2)
{
  __shared__ float A_[64][64], B2[64][64], C_[64][64];
  const int bh = blockIdx.x, tid = threadIdx.x;
  for (int idx = tid; idx < 4096; idx += 256) {
    A_[idx >> 6][idx & 63] = Vinv[(size_t)bh * 4096 + idx];
    B2[idx >> 6][idx & 63] = W1[(size_t)bh * 4096 + idx];
  }
  __syncthreads();
  mm64(C_, A_, B2, tid);
  __syncthreads();
  for (int idx = tid; idx < 4096; idx += 256)
    W2[(size_t)bh * 4096 + idx] = C_[idx >> 6][idx & 63];
}

// =============================================================
// X = softmax(Q @ Kl^T / 8) @ W2  -> Xc [B,S,HID] fp32
// =============================================================
__global__ __launch_bounds__(256) void attn_core(
    const float* __restrict__ Q, const float* __restrict__ Kl,
    const float* __restrict__ W2, float* __restrict__ Xc)
{
  __shared__ float Kls[64][64];
  __shared__ float W2s[64][64];
  const int blk = blockIdx.x;
  const int bh = blk >> 4, chunk = blk & 15;
  const int tid = threadIdx.x;
  const int b = bh / H_, h = bh % H_;
  for (int idx = tid; idx < 4096; idx += 256) {
    Kls[idx >> 6][idx & 63] = Kl[(size_t)bh * 4096 + idx];
    W2s[idx >> 6][idx & 63] = W2[(size_t)bh * 4096 + idx];
  }
  __syncthreads();
  const int s = chunk * 256 + tid;
  const float* qp = Q + ((size_t)bh * S_ + s) * 64;
  float4 q4[16];
#pragma unroll
  for (int k = 0; k < 16; ++k) q4[k] = *(const float4*)&qp[k * 4];
  float p[64];
#pragma unroll
  for (int m = 0; m < 64; ++m) {
    float dot = 0.f;
#pragma unroll
    for (int k = 0; k < 16; ++k) {
      const float4 kv = *(const float4*)&Kls[m][k * 4];
      dot += q4[k].x * kv.x + q4[k].y * kv.y + q4[k].z * kv.z + q4[k].w * kv.w;
    }
    p[m] = dot * 0.125f;
  }
  float mx = -1e30f;
#pragma unroll
  for (int m = 0; m < 64; ++m) mx = fmaxf(mx, p[m]);
  float sum = 0.f;
#pragma unroll
  for (int m = 0; m < 64; ++m) { p[m] = expf(p[m] - mx); sum += p[m]; }
  const float inv = 1.f / sum;
#pragma unroll
  for (int m = 0; m < 64; ++m) p[m] *= inv;
  float4 o4[16];
#pragma unroll
  for (int k = 0; k < 16; ++k) o4[k] = make_float4(0.f, 0.f, 0.f, 0.f);
#pragma unroll
  for (int m = 0; m < 64; ++m) {
    const float pm = p[m];
#pragma unroll
    for (int k = 0; k < 16; ++k) {
      const float4 wv = *(const float4*)&W2s[m][k * 4];
      o4[k].x += pm * wv.x; o4[k].y += pm * wv.y;
      o4[k].z += pm * wv.z; o4[k].w += pm * wv.w;
    }
  }
  float* xp = Xc + ((size_t)(b * S_ + s)) * HID_ + h * 64;
#pragma unroll
  for (int k = 0; k < 16; ++k) *(float4*)&xp[k * 4] = o4[k];
}

// =============================================================
// Depthwise conv + add attn, write split-bf16 (input of out-GEMM)
// =============================================================
__global__ __launch_bounds__(256) void conv_add_split(
    const float* __restrict__ V, const float* __restrict__ cw,
    const float* __restrict__ Xc, u16* __restrict__ Xch, u16* __restrict__ Xcl)
{
  __shared__ float Vs[160][64];
  __shared__ float cws[33];
  const int blk = blockIdx.x;
  const int bh = blk >> 5, chunk = blk & 31;
  const int tid = threadIdx.x;
  const int b = bh / H_, h = bh % H_;
  const int s0 = chunk * 128;
  if (tid < 33) cws[tid] = cw[h * 33 + tid];
  const float* Vb = V + (size_t)bh * S_ * 64;
  for (int idx = tid; idx < 160 * 64; idx += 256) {
    const int r = idx >> 6, c = idx & 63;
    const int sv = s0 - 16 + r;
    Vs[r][c] = (sv >= 0 && sv < S_) ? Vb[(size_t)sv * 64 + c] : 0.f;
  }
  __syncthreads();
  const int d = tid & 63, rg = tid >> 6;
  for (int rr = 0; rr < 32; ++rr) {
    const int r = rg * 32 + rr;
    float acc = 0.f;
#pragma unroll
    for (int t = 0; t < 33; ++t) acc += Vs[r + t][d] * cws[t];
    const size_t idx = ((size_t)(b * S_ + s0 + r)) * HID_ + h * 64 + d;
    const float o = Xc[idx] + acc;
    const u16 hh = f2bf(o);
    Xch[idx] = hh;
    Xcl[idx] = f2bf(o - bf2f(hh));
  }
}

// =============================================================
extern "C" void kernel_launch(void* const* d_in, const int* in_sizes, int n_in,
                              void* d_out, int out_size, void* d_ws, size_t ws_size,
                              hipStream_t stream)
{
  (void)in_sizes; (void)n_in; (void)out_size; (void)ws_size;
  const float* x      = (const float*)d_in[0];
  const float* qkv_w  = (const float*)d_in[1];
  const float* qkv_b  = (const float*)d_in[2];
  const float* conv_w = (const float*)d_in[3];
  const float* out_w  = (const float*)d_in[4];
  const float* out_b  = (const float*)d_in[5];
  float* out = (float*)d_out;

  // fp32 region
  float* ws   = (float*)d_ws;
  float* Q    = ws;                       // [BH,S,D] 6291456
  float* K    = Q + 6291456;
  float* V    = K + 6291456;
  float* Ql   = V + 6291456;              // 98304 each below
  float* Kl   = Ql + 98304;
  float* K2   = Kl + 98304;
  float* Vinv = K2 + 98304;
  float* W1   = Vinv + 98304;
  float* W2   = W1 + 98304;
  float* colmax = W2 + 98304;
  float* rowmax = colmax + 32;
  // bf16 (u16) region
  u16* ub  = (u16*)(rowmax + 32);
  u16* Xh  = ub;                          // 6291456 u16
  u16* Xl  = Xh + 6291456;
  u16* Wqh = Xl + 6291456;                // 1769472
  u16* Wql = Wqh + 1769472;
  u16* Woh = Wql + 1769472;               // 589824
  u16* Wol = Woh + 589824;
  // aliases
  u16* Xch = Xh;                          // Xh/Xl dead between QKV GEMM and conv
  u16* Xcl = Xl;
  float* Xc = K;                          // K dead after k3v_pass1
  float* Opart = (float*)Xh;              // 3145728 floats (exact fit)
  float* mpart = (float*)Xl;              // 49152
  float* lpart = mpart + BH_ * NCH_ * 64; // 49152
  float* W1buf = W1;

  split_pair<<<786432 / 256, 256, 0, stream>>>(x, Xh, Xl, 786432);
  split_pair<<<221184 / 256, 256, 0, stream>>>(qkv_w, Wqh, Wql, 221184);
  split_pair<<<73728 / 256, 256, 0, stream>>>(out_w, Woh, Wol, 73728);

  gemm3_mfma<0><<<dim3(18, 64), 256, 0, stream>>>(Xh, Xl, Wqh, Wql, qkv_b, Q, K, V);

  landmarks_kernel<<<BH_ * 64, 64, 0, stream>>>(Q, K, Ql, Kl);
  kernel2_softmax<<<BH_, 256, 0, stream>>>(Ql, Kl, K2, colmax, rowmax);
  newton_inv<<<BH_, 256, 0, stream>>>(K2, colmax, rowmax, Vinv);

  k3v_pass1<<<dim3(NCH_, BH_), 256, 0, stream>>>(Ql, K, V, Opart, mpart, lpart);
  k3v_combine<<<BH_, 256, 0, stream>>>(Opart, mpart, lpart, W1buf);

  w2_small<<<BH_, 256, 0, stream>>>(Vinv, W1buf, W2);
  attn_core<<<BH_ * 16, 256, 0, stream>>>(Q, Kl, W2, Xc);
  conv_add_split<<<BH_ * 32, 256, 0, stream>>>(V, conv_w, Xc, Xch, Xcl);

  gemm3_mfma<1><<<dim3(6, 64), 256, 0, stream>>>(Xch, Xcl, Woh, Wol, out_b, out, nullptr, nullptr);
}

// Round 4
// 391.720 us; speedup vs baseline: 2.4648x; 1.0406x over previous
//
#include <hip/hip_runtime.h>
#include <math.h>

#define B_   2
#define S_   4096
#define HID_ 768
#define H_   12
#define D_   64
#define M_   64
#define CK_  33
#define BH_  (B_*H_)   // 24
#define KD_  768
#define NCH_ 32        // k3v S-chunks
#define SC_  128       // keys per chunk

typedef float  f32x4  __attribute__((ext_vector_type(4)));
typedef short  bf16x8 __attribute__((ext_vector_type(8)));
typedef unsigned short u16;

__device__ __forceinline__ u16 f2bf(float f) {
  unsigned int u = __float_as_uint(f);
  u += 0x7FFFu + ((u >> 16) & 1u);   // round-to-nearest-even
  return (u16)(u >> 16);
}
__device__ __forceinline__ float bf2f(u16 s) {
  return __uint_as_float(((unsigned int)s) << 16);
}
// two float4 -> bf16x8 (hi) + bf16x8 (lo residual)
__device__ __forceinline__ void cvt8(const float4 a, const float4 b,
                                     bf16x8* hi, bf16x8* lo) {
  const float v[8] = {a.x, a.y, a.z, a.w, b.x, b.y, b.z, b.w};
  union { u16 u[8]; bf16x8 v; } H, L;
#pragma unroll
  for (int e = 0; e < 8; ++e) {
    const u16 hh = f2bf(v[e]);
    H.u[e] = hh;
    L.u[e] = f2bf(v[e] - bf2f(hh));
  }
  *hi = H.v; *lo = L.v;
}

__device__ __forceinline__ void gld16(const void* g, void* l) {
  __builtin_amdgcn_global_load_lds(
      (const __attribute__((address_space(1))) void*)g,
      (__attribute__((address_space(3))) void*)l, 16, 0, 0);
}

// =============================================================
// split fp32 -> (hi, lo) bf16 pair. 8 elements / thread.
// =============================================================
__global__ __launch_bounds__(256) void split_pair(
    const float* __restrict__ src, u16* __restrict__ h, u16* __restrict__ l, int n8)
{
  const int i = blockIdx.x * 256 + threadIdx.x;
  if (i >= n8) return;
  const float4* s4 = (const float4*)src;
  const float4 a = s4[2 * i], b = s4[2 * i + 1];
  const float v[8] = {a.x, a.y, a.z, a.w, b.x, b.y, b.z, b.w};
  union { u16 u[8]; uint4 q; } hv, lv;
#pragma unroll
  for (int e = 0; e < 8; ++e) {
    const u16 hh = f2bf(v[e]);
    hv.u[e] = hh;
    lv.u[e] = f2bf(v[e] - bf2f(hh));
  }
  ((uint4*)h)[i] = hv.q;
  ((uint4*)l)[i] = lv.q;
}

// =============================================================
// Split-bf16 3-product MFMA GEMM: C = A @ W^T (+bias)
// 128x128 tile, BK=32, 4 waves. LDS XOR-swizzle (T2, both-sides):
//   phys 16B-block q' = q ^ ((row>>1)&3)  -- linear gld_lds dest,
//   inverse-swizzled global source, swizzled ds_read.
// XCD-bijective block swizzle (nwg % 8 == 0 in both modes).
// =============================================================
template<int MODE>
__global__ __launch_bounds__(256) void gemm3_mfma(
    const u16* __restrict__ Ahg, const u16* __restrict__ Alg,
    const u16* __restrict__ Bhg, const u16* __restrict__ Blg,
    const float* __restrict__ bias,
    float* __restrict__ o0, float* __restrict__ o1, float* __restrict__ o2)
{
  __shared__ __align__(16) u16 Ah_s[128 * 32];
  __shared__ __align__(16) u16 Al_s[128 * 32];
  __shared__ __align__(16) u16 Bh_s[128 * 32];
  __shared__ __align__(16) u16 Bl_s[128 * 32];

  constexpr int NBX = (MODE == 0) ? 18 : 6;
  constexpr int CPX = (NBX * 64) / 8;

  const int tid = threadIdx.x;
  const int lin = blockIdx.y * NBX + blockIdx.x;
  const int swb = (lin & 7) * CPX + (lin >> 3);    // XCD-contiguous chunks
  const int m0 = (swb / NBX) * 128;
  const int n0 = (swb % NBX) * 128;

  const int wave = tid >> 6, lane = tid & 63;
  const int wm = wave >> 1, wn = wave & 1;
  const int lr = lane & 15, kg = lane >> 4;

  // staging: phys row = tid>>2, phys q = tid&3; source holds logical q^swz
  const int srow = tid >> 2;
  const int swz_s = (tid >> 3) & 3;                // (row>>1)&3
  const int sk = ((tid & 3) ^ swz_s) * 8;

  const u16* pAh = Ahg + (size_t)(m0 + srow) * KD_ + sk;
  const u16* pAl = Alg + (size_t)(m0 + srow) * KD_ + sk;
  const u16* pBh = Bhg + (size_t)(n0 + srow) * KD_ + sk;
  const u16* pBl = Blg + (size_t)(n0 + srow) * KD_ + sk;

  f32x4 acc[4][4];
#pragma unroll
  for (int i = 0; i < 4; ++i)
#pragma unroll
    for (int j = 0; j < 4; ++j) acc[i][j] = (f32x4){0.f, 0.f, 0.f, 0.f};

  // fragment read: logical (row, kg) lives at phys q = kg ^ ((row>>1)&3)
  const int rsw = (lr >> 1) & 3;
  const int kq = (kg ^ rsw) * 8;
  const int abase = (wm * 64 + lr) * 32 + kq;
  const int bbase = (wn * 64 + lr) * 32 + kq;

  for (int kt = 0; kt < KD_ / 32; ++kt) {
    __syncthreads();
    const size_t go = (size_t)kt * 32;
    gld16(pAh + go,                 Ah_s + tid * 8);
    gld16(pAh + go + 64 * KD_,      Ah_s + 2048 + tid * 8);
    gld16(pAl + go,                 Al_s + tid * 8);
    gld16(pAl + go + 64 * KD_,      Al_s + 2048 + tid * 8);
    gld16(pBh + go,                 Bh_s + tid * 8);
    gld16(pBh + go + 64 * KD_,      Bh_s + 2048 + tid * 8);
    gld16(pBl + go,                 Bl_s + tid * 8);
    gld16(pBl + go + 64 * KD_,      Bl_s + 2048 + tid * 8);
    __syncthreads();

    bf16x8 ah[4], al[4], bh[4], bl[4];
#pragma unroll
    for (int f = 0; f < 4; ++f) {
      ah[f] = *(const bf16x8*)&Ah_s[abase + f * 512];
      al[f] = *(const bf16x8*)&Al_s[abase + f * 512];
      bh[f] = *(const bf16x8*)&Bh_s[bbase + f * 512];
      bl[f] = *(const bf16x8*)&Bl_s[bbase + f * 512];
    }
#pragma unroll
    for (int i = 0; i < 4; ++i)
#pragma unroll
      for (int j = 0; j < 4; ++j) {
        acc[i][j] = __builtin_amdgcn_mfma_f32_16x16x32_bf16(ah[i], bh[j], acc[i][j], 0, 0, 0);
        acc[i][j] = __builtin_amdgcn_mfma_f32_16x16x32_bf16(ah[i], bl[j], acc[i][j], 0, 0, 0);
        acc[i][j] = __builtin_amdgcn_mfma_f32_16x16x32_bf16(al[i], bh[j], acc[i][j], 0, 0, 0);
      }
  }

#pragma unroll
  for (int i = 0; i < 4; ++i) {
    const int mbase = m0 + wm * 64 + i * 16 + kg * 4;
#pragma unroll
    for (int j = 0; j < 4; ++j) {
      const int ncol = n0 + wn * 64 + j * 16 + lr;
      const float bv = bias[ncol];
      if (MODE == 0) {
        const int part = (ncol >= 1536) ? 2 : (ncol >= 768 ? 1 : 0);
        const int within = ncol - part * 768;
        const int h0 = within >> 6, d = within & 63;
        float* base = (part == 0) ? o0 : ((part == 1) ? o1 : o2);
#pragma unroll
        for (int r = 0; r < 4; ++r) {
          const int row = mbase + r;
          const int b = row >> 12, s = row & (S_ - 1);
          base[(((size_t)(b * H_ + h0) * S_ + s) << 6) + d] = acc[i][j][r] + bv;
        }
      } else {
#pragma unroll
        for (int r = 0; r < 4; ++r) {
          const int row = mbase + r;
          o0[(size_t)row * HID_ + ncol] = acc[i][j][r] + bv;
        }
      }
    }
  }
}

// =============================================================
// Landmark means
// =============================================================
__global__ void landmarks_kernel(const float* __restrict__ Q,
                                 const float* __restrict__ K,
                                 float* __restrict__ Ql, float* __restrict__ Kl)
{
  const int blk = blockIdx.x;
  const int bh = blk >> 6, m = blk & 63;
  const int d = threadIdx.x;
  const float* qp = Q + ((size_t)bh * S_ + m * 64) * 64 + d;
  const float* kp = K + ((size_t)bh * S_ + m * 64) * 64 + d;
  float sq = 0.f, sk = 0.f;
  for (int j = 0; j < 64; ++j) { sq += qp[(size_t)j * 64]; sk += kp[(size_t)j * 64]; }
  Ql[((size_t)bh * M_ + m) * 64 + d] = sq * (1.f / 64.f);
  Kl[((size_t)bh * M_ + m) * 64 + d] = sk * (1.f / 64.f);
}

// =============================================================
// kernel_2 softmax + per-(b,h) max col/row sums
// =============================================================
__global__ __launch_bounds__(256) void kernel2_softmax(
    const float* __restrict__ Ql, const float* __restrict__ Kl,
    float* __restrict__ K2, float* __restrict__ colmax, float* __restrict__ rowmax)
{
  __shared__ float Qs[64][68], Ks[64][68], S2[64][68];
  __shared__ float red1[64], red2[64];
  const int bh = blockIdx.x, tid = threadIdx.x;
  for (int idx = tid; idx < 4096; idx += 256) {
    const int r = idx >> 6, c = idx & 63;
    Qs[r][c] = Ql[(size_t)bh * 4096 + idx];
    Ks[r][c] = Kl[(size_t)bh * 4096 + idx];
  }
  __syncthreads();
  for (int idx = tid; idx < 4096; idx += 256) {
    const int r = idx >> 6, c = idx & 63;
    float dot = 0.f;
#pragma unroll
    for (int k = 0; k < 64; k += 4) {
      const float4 a = *(const float4*)&Qs[r][k];
      const float4 b = *(const float4*)&Ks[c][k];
      dot += a.x * b.x + a.y * b.y + a.z * b.z + a.w * b.w;
    }
    S2[r][c] = dot * 0.125f;
  }
  __syncthreads();
  if (tid < 64) {
    const int r = tid;
    float mx = -1e30f;
    for (int c = 0; c < 64; ++c) mx = fmaxf(mx, S2[r][c]);
    float sum = 0.f;
    for (int c = 0; c < 64; ++c) { const float e = expf(S2[r][c] - mx); S2[r][c] = e; sum += e; }
    const float inv = 1.f / sum;
    for (int c = 0; c < 64; ++c) S2[r][c] *= inv;
  }
  __syncthreads();
  for (int idx = tid; idx < 4096; idx += 256)
    K2[(size_t)bh * 4096 + idx] = S2[idx >> 6][idx & 63];
  if (tid < 64) {
    float cs = 0.f, rs = 0.f;
    for (int m = 0; m < 64; ++m) { cs += S2[m][tid]; rs += S2[tid][m]; }
    red1[tid] = cs; red2[tid] = rs;
  }
  __syncthreads();
  if (tid == 0) {
    float mc = 0.f, mr = 0.f;
    for (int i = 0; i < 64; ++i) { mc = fmaxf(mc, red1[i]); mr = fmaxf(mr, red2[i]); }
    colmax[bh] = mc; rowmax[bh] = mr;
  }
}

// 64x64x64 matmul in LDS (stride-68 padded: A-row reads 2-way, B 2-way)
__device__ inline void mm64(float (*C)[68], float (*A)[68], float (*B)[68], int tid)
{
  const int ry = tid >> 4, cx = tid & 15;
  const int r0 = ry * 4, c0 = cx * 4;
  float acc[4][4];
#pragma unroll
  for (int i = 0; i < 4; ++i)
#pragma unroll
    for (int j = 0; j < 4; ++j) acc[i][j] = 0.f;
  for (int k = 0; k < 64; k += 4) {
    float4 a[4], b[4];
#pragma unroll
    for (int i = 0; i < 4; ++i) a[i] = *(const float4*)&A[r0 + i][k];
#pragma unroll
    for (int j = 0; j < 4; ++j) b[j] = *(const float4*)&B[k + j][c0];
    const float bb[4][4] = {{b[0].x, b[0].y, b[0].z, b[0].w},
                            {b[1].x, b[1].y, b[1].z, b[1].w},
                            {b[2].x, b[2].y, b[2].z, b[2].w},
                            {b[3].x, b[3].y, b[3].z, b[3].w}};
    const float aa[4][4] = {{a[0].x, a[0].y, a[0].z, a[0].w},
                            {a[1].x, a[1].y, a[1].z, a[1].w},
                            {a[2].x, a[2].y, a[2].z, a[2].w},
                            {a[3].x, a[3].y, a[3].z, a[3].w}};
#pragma unroll
    for (int i = 0; i < 4; ++i)
#pragma unroll
      for (int j = 0; j < 4; ++j)
#pragma unroll
        for (int kk = 0; kk < 4; ++kk) acc[i][j] += aa[i][kk] * bb[kk][j];
  }
#pragma unroll
  for (int i = 0; i < 4; ++i)
    *(float4*)&C[r0 + i][c0] = make_float4(acc[i][0], acc[i][1], acc[i][2], acc[i][3]);
}

// =============================================================
// Newton-Schulz pseudo-inverse (6 iters, global scale)
// =============================================================
__global__ __launch_bounds__(256) void newton_inv(
    const float* __restrict__ K2, const float* __restrict__ colmax,
    const float* __restrict__ rowmax, float* __restrict__ Vinv)
{
  __shared__ float A_[64][68], V_[64][68], KV_[64][68], T_[64][68], U_[64][68];
  __shared__ float scale_s;
  const int bh = blockIdx.x, tid = threadIdx.x;
  if (tid == 0) {
    float mc = 0.f, mr = 0.f;
    for (int i = 0; i < BH_; ++i) { mc = fmaxf(mc, colmax[i]); mr = fmaxf(mr, rowmax[i]); }
    scale_s = 1.f / (mc * mr);
  }
  for (int idx = tid; idx < 4096; idx += 256)
    A_[idx >> 6][idx & 63] = K2[(size_t)bh * 4096 + idx];
  __syncthreads();
  const float scale = scale_s;
  for (int idx = tid; idx < 4096; idx += 256) {
    const int r = idx >> 6, c = idx & 63;
    V_[r][c] = scale * A_[c][r];
  }
  __syncthreads();
  for (int it = 0; it < 6; ++it) {
    mm64(KV_, A_, V_, tid); __syncthreads();
    for (int idx = tid; idx < 4096; idx += 256) {
      const int r = idx >> 6, c = idx & 63;
      T_[r][c] = (r == c ? 7.f : 0.f) - KV_[r][c];
    }
    __syncthreads();
    mm64(U_, KV_, T_, tid); __syncthreads();
    for (int idx = tid; idx < 4096; idx += 256) {
      const int r = idx >> 6, c = idx & 63;
      T_[r][c] = (r == c ? 15.f : 0.f) - U_[r][c];
    }
    __syncthreads();
    mm64(U_, KV_, T_, tid); __syncthreads();
    for (int idx = tid; idx < 4096; idx += 256) {
      const int r = idx >> 6, c = idx & 63;
      T_[r][c] = (r == c ? 13.f : 0.f) - U_[r][c];
    }
    __syncthreads();
    mm64(U_, V_, T_, tid); __syncthreads();
    for (int idx = tid; idx < 4096; idx += 256) {
      const int r = idx >> 6, c = idx & 63;
      V_[r][c] = 0.25f * U_[r][c];
    }
    __syncthreads();
  }
  for (int idx = tid; idx < 4096; idx += 256)
    Vinv[(size_t)bh * 4096 + idx] = V_[idx >> 6][idx & 63];
}

// =============================================================
// k3v pass 1: S = Ql @ K_chunk^T / 8 (MFMA), partial softmax + O_j
// P stride 129: PV read bank = (row+s)%32 -> 2-way (was 8-way at 132)
// =============================================================
__global__ __launch_bounds__(256) void k3v_pass1(
    const float* __restrict__ Ql, const float* __restrict__ K,
    const float* __restrict__ V, float* __restrict__ Opart,
    float* __restrict__ mpart, float* __restrict__ lpart)
{
  __shared__ float P[64][129];
  __shared__ float red1[64][4], red2[64][4];

  const int ch = blockIdx.x;     // 0..31
  const int bh = blockIdx.y;     // 0..23
  const int tid = threadIdx.x;
  const int wave = tid >> 6, lane = tid & 63;
  const int lr = lane & 15, kg = lane >> 4;

  const float* Qlb = Ql + (size_t)bh * 4096;
  const float* Kb  = K + (size_t)bh * S_ * 64;
  const float* Vb  = V + (size_t)bh * S_ * 64;

  bf16x8 ah[4][2], al[4][2];
#pragma unroll
  for (int mt = 0; mt < 4; ++mt)
#pragma unroll
    for (int kk = 0; kk < 2; ++kk) {
      const float* qr = Qlb + (size_t)(mt * 16 + lr) * 64 + kk * 32 + kg * 8;
      cvt8(*(const float4*)qr, *(const float4*)(qr + 4), &ah[mt][kk], &al[mt][kk]);
    }

#pragma unroll
  for (int t = 0; t < 2; ++t) {
    const int s0 = (wave * 2 + t) * 16;
    const int srow = ch * SC_ + s0 + lr;
    f32x4 acc[4];
#pragma unroll
    for (int mt = 0; mt < 4; ++mt) acc[mt] = (f32x4){0.f, 0.f, 0.f, 0.f};
#pragma unroll
    for (int kk = 0; kk < 2; ++kk) {
      const float* kr = Kb + (size_t)srow * 64 + kk * 32 + kg * 8;
      bf16x8 bhf, blf;
      cvt8(*(const float4*)kr, *(const float4*)(kr + 4), &bhf, &blf);
#pragma unroll
      for (int mt = 0; mt < 4; ++mt) {
        acc[mt] = __builtin_amdgcn_mfma_f32_16x16x32_bf16(ah[mt][kk], bhf, acc[mt], 0, 0, 0);
        acc[mt] = __builtin_amdgcn_mfma_f32_16x16x32_bf16(ah[mt][kk], blf, acc[mt], 0, 0, 0);
        acc[mt] = __builtin_amdgcn_mfma_f32_16x16x32_bf16(al[mt][kk], bhf, acc[mt], 0, 0, 0);
      }
    }
#pragma unroll
    for (int mt = 0; mt < 4; ++mt)
#pragma unroll
      for (int r = 0; r < 4; ++r)
        P[mt * 16 + kg * 4 + r][s0 + lr] = acc[mt][r] * 0.125f;
  }
  __syncthreads();

  const int r = tid >> 2, q = tid & 3;
  {
    float mx = -1e30f;
#pragma unroll
    for (int s = 0; s < 32; ++s) mx = fmaxf(mx, P[r][q * 32 + s]);
    red1[r][q] = mx;
  }
  __syncthreads();
  const float rowmax = fmaxf(fmaxf(red1[r][0], red1[r][1]),
                             fmaxf(red1[r][2], red1[r][3]));
  {
    float sum = 0.f;
#pragma unroll
    for (int s = 0; s < 32; ++s) {
      const float e = expf(P[r][q * 32 + s] - rowmax);
      P[r][q * 32 + s] = e;
      sum += e;
    }
    red2[r][q] = sum;
  }
  __syncthreads();
  if (q == 0) {
    const float rowsum = red2[r][0] + red2[r][1] + red2[r][2] + red2[r][3];
    mpart[((size_t)bh * NCH_ + ch) * 64 + r] = rowmax;
    lpart[((size_t)bh * NCH_ + ch) * 64 + r] = rowsum;
  }

  const int mg = tid >> 4, dq = (tid & 15) * 4;
  float4 oacc[4];
#pragma unroll
  for (int i = 0; i < 4; ++i) oacc[i] = make_float4(0.f, 0.f, 0.f, 0.f);
  for (int s = 0; s < SC_; ++s) {
    const float4 v = *(const float4*)&Vb[(size_t)(ch * SC_ + s) * 64 + dq];
#pragma unroll
    for (int i = 0; i < 4; ++i) {
      const float p = P[mg * 4 + i][s];
      oacc[i].x += p * v.x; oacc[i].y += p * v.y;
      oacc[i].z += p * v.z; oacc[i].w += p * v.w;
    }
  }
#pragma unroll
  for (int i = 0; i < 4; ++i) {
    const size_t o = (((size_t)bh * NCH_ + ch) * 64 + mg * 4 + i) * 64 + dq;
    *(float4*)&Opart[o] = oacc[i];
  }
}

// =============================================================
// k3v pass 2 + W2: combine chunks -> W1 (LDS), then W2 = Vinv @ W1
// =============================================================
__global__ __launch_bounds__(256) void k3v_combine_w2(
    const float* __restrict__ Opart, const float* __restrict__ mpart,
    const float* __restrict__ lpart, const float* __restrict__ Vinv,
    float* __restrict__ W2)
{
  __shared__ float w[64][33];
  __shared__ float W1s[64][68], Vs[64][68], C_[64][68];
  const int bh = blockIdx.x, tid = threadIdx.x;
  for (int idx = tid; idx < 4096; idx += 256)
    Vs[idx >> 6][idx & 63] = Vinv[(size_t)bh * 4096 + idx];
  if (tid < 64) {
    const int m = tid;
    float M = -1e30f;
    for (int j = 0; j < NCH_; ++j)
      M = fmaxf(M, mpart[((size_t)bh * NCH_ + j) * 64 + m]);
    float denom = 0.f;
    for (int j = 0; j < NCH_; ++j)
      denom += expf(mpart[((size_t)bh * NCH_ + j) * 64 + m] - M) *
               lpart[((size_t)bh * NCH_ + j) * 64 + m];
    const float inv = 1.f / denom;
    for (int j = 0; j < NCH_; ++j)
      w[m][j] = expf(mpart[((size_t)bh * NCH_ + j) * 64 + m] - M) * inv;
  }
  __syncthreads();
  const int mg = tid >> 4, dq = (tid & 15) * 4;
#pragma unroll
  for (int i = 0; i < 4; ++i) {
    const int m = mg * 4 + i;
    float4 acc = make_float4(0.f, 0.f, 0.f, 0.f);
    for (int j = 0; j < NCH_; ++j) {
      const float ww = w[m][j];
      const float4 o = *(const float4*)&Opart[(((size_t)bh * NCH_ + j) * 64 + m) * 64 + dq];
      acc.x += ww * o.x; acc.y += ww * o.y; acc.z += ww * o.z; acc.w += ww * o.w;
    }
    *(float4*)&W1s[m][dq] = acc;
  }
  __syncthreads();
  mm64(C_, Vs, W1s, tid);
  __syncthreads();
  for (int idx = tid; idx < 4096; idx += 256)
    W2[(size_t)bh * 4096 + idx] = C_[idx >> 6][idx & 63];
}

// =============================================================
// X = softmax(Q @ Kl^T / 8) @ W2  -> Xc [B,S,HID] fp32
// =============================================================
__global__ __launch_bounds__(256) void attn_core(
    const float* __restrict__ Q, const float* __restrict__ Kl,
    const float* __restrict__ W2, float* __restrict__ Xc)
{
  __shared__ float Kls[64][64];
  __shared__ float W2s[64][64];
  const int blk = blockIdx.x;
  const int bh = blk >> 4, chunk = blk & 15;
  const int tid = threadIdx.x;
  const int b = bh / H_, h = bh % H_;
  for (int idx = tid; idx < 4096; idx += 256) {
    Kls[idx >> 6][idx & 63] = Kl[(size_t)bh * 4096 + idx];
    W2s[idx >> 6][idx & 63] = W2[(size_t)bh * 4096 + idx];
  }
  __syncthreads();
  const int s = chunk * 256 + tid;
  const float* qp = Q + ((size_t)bh * S_ + s) * 64;
  float4 q4[16];
#pragma unroll
  for (int k = 0; k < 16; ++k) q4[k] = *(const float4*)&qp[k * 4];
  float p[64];
#pragma unroll
  for (int m = 0; m < 64; ++m) {
    float dot = 0.f;
#pragma unroll
    for (int k = 0; k < 16; ++k) {
      const float4 kv = *(const float4*)&Kls[m][k * 4];
      dot += q4[k].x * kv.x + q4[k].y * kv.y + q4[k].z * kv.z + q4[k].w * kv.w;
    }
    p[m] = dot * 0.125f;
  }
  float mx = -1e30f;
#pragma unroll
  for (int m = 0; m < 64; ++m) mx = fmaxf(mx, p[m]);
  float sum = 0.f;
#pragma unroll
  for (int m = 0; m < 64; ++m) { p[m] = expf(p[m] - mx); sum += p[m]; }
  const float inv = 1.f / sum;
#pragma unroll
  for (int m = 0; m < 64; ++m) p[m] *= inv;
  float4 o4[16];
#pragma unroll
  for (int k = 0; k < 16; ++k) o4[k] = make_float4(0.f, 0.f, 0.f, 0.f);
#pragma unroll
  for (int m = 0; m < 64; ++m) {
    const float pm = p[m];
#pragma unroll
    for (int k = 0; k < 16; ++k) {
      const float4 wv = *(const float4*)&W2s[m][k * 4];
      o4[k].x += pm * wv.x; o4[k].y += pm * wv.y;
      o4[k].z += pm * wv.z; o4[k].w += pm * wv.w;
    }
  }
  float* xp = Xc + ((size_t)(b * S_ + s)) * HID_ + h * 64;
#pragma unroll
  for (int k = 0; k < 16; ++k) *(float4*)&xp[k * 4] = o4[k];
}

// =============================================================
// Depthwise conv + add attn, write split-bf16 (input of out-GEMM)
// =============================================================
__global__ __launch_bounds__(256) void conv_add_split(
    const float* __restrict__ V, const float* __restrict__ cw,
    const float* __restrict__ Xc, u16* __restrict__ Xch, u16* __restrict__ Xcl)
{
  __shared__ float Vs[160][64];
  __shared__ float cws[33];
  const int blk = blockIdx.x;
  const int bh = blk >> 5, chunk = blk & 31;
  const int tid = threadIdx.x;
  const int b = bh / H_, h = bh % H_;
  const int s0 = chunk * 128;
  if (tid < 33) cws[tid] = cw[h * 33 + tid];
  const float* Vb = V + (size_t)bh * S_ * 64;
  for (int idx = tid; idx < 160 * 64; idx += 256) {
    const int r = idx >> 6, c = idx & 63;
    const int sv = s0 - 16 + r;
    Vs[r][c] = (sv >= 0 && sv < S_) ? Vb[(size_t)sv * 64 + c] : 0.f;
  }
  __syncthreads();
  const int d = tid & 63, rg = tid >> 6;
  for (int rr = 0; rr < 32; ++rr) {
    const int r = rg * 32 + rr;
    float acc = 0.f;
#pragma unroll
    for (int t = 0; t < 33; ++t) acc += Vs[r + t][d] * cws[t];
    const size_t idx = ((size_t)(b * S_ + s0 + r)) * HID_ + h * 64 + d;
    const float o = Xc[idx] + acc;
    const u16 hh = f2bf(o);
    Xch[idx] = hh;
    Xcl[idx] = f2bf(o - bf2f(hh));
  }
}

// =============================================================
extern "C" void kernel_launch(void* const* d_in, const int* in_sizes, int n_in,
                              void* d_out, int out_size, void* d_ws, size_t ws_size,
                              hipStream_t stream)
{
  (void)in_sizes; (void)n_in; (void)out_size; (void)ws_size;
  const float* x      = (const float*)d_in[0];
  const float* qkv_w  = (const float*)d_in[1];
  const float* qkv_b  = (const float*)d_in[2];
  const float* conv_w = (const float*)d_in[3];
  const float* out_w  = (const float*)d_in[4];
  const float* out_b  = (const float*)d_in[5];
  float* out = (float*)d_out;

  // fp32 region
  float* ws   = (float*)d_ws;
  float* Q    = ws;                       // [BH,S,D] 6291456
  float* K    = Q + 6291456;
  float* V    = K + 6291456;
  float* Ql   = V + 6291456;              // 98304 each below
  float* Kl   = Ql + 98304;
  float* K2   = Kl + 98304;
  float* Vinv = K2 + 98304;
  float* W1   = Vinv + 98304;
  float* W2   = W1 + 98304;
  float* colmax = W2 + 98304;
  float* rowmax = colmax + 32;
  // bf16 (u16) region
  u16* ub  = (u16*)(rowmax + 32);
  u16* Xh  = ub;                          // 6291456 u16
  u16* Xl  = Xh + 6291456;
  u16* Wqh = Xl + 6291456;                // 1769472
  u16* Wql = Wqh + 1769472;
  u16* Woh = Wql + 1769472;               // 589824
  u16* Wol = Woh + 589824;
  // aliases
  u16* Xch = Xh;                          // Xh/Xl dead between QKV GEMM and conv
  u16* Xcl = Xl;
  float* Xc = K;                          // K dead after k3v_pass1
  float* Opart = (float*)Xh;              // 3145728 floats (exact fit)
  float* mpart = (float*)Xl;              // 49152
  float* lpart = mpart + BH_ * NCH_ * 64; // 49152

  split_pair<<<786432 / 256, 256, 0, stream>>>(x, Xh, Xl, 786432);
  split_pair<<<221184 / 256, 256, 0, stream>>>(qkv_w, Wqh, Wql, 221184);
  split_pair<<<73728 / 256, 256, 0, stream>>>(out_w, Woh, Wol, 73728);

  gemm3_mfma<0><<<dim3(18, 64), 256, 0, stream>>>(Xh, Xl, Wqh, Wql, qkv_b, Q, K, V);

  landmarks_kernel<<<BH_ * 64, 64, 0, stream>>>(Q, K, Ql, Kl);
  kernel2_softmax<<<BH_, 256, 0, stream>>>(Ql, Kl, K2, colmax, rowmax);
  newton_inv<<<BH_, 256, 0, stream>>>(K2, colmax, rowmax, Vinv);

  k3v_pass1<<<dim3(NCH_, BH_), 256, 0, stream>>>(Ql, K, V, Opart, mpart, lpart);
  k3v_combine_w2<<<BH_, 256, 0, stream>>>(Opart, mpart, lpart, Vinv, W2);

  attn_core<<<BH_ * 16, 256, 0, stream>>>(Q, Kl, W2, Xc);
  conv_add_split<<<BH_ * 32, 256, 0, stream>>>(V, conv_w, Xc, Xch, Xcl);

  gemm3_mfma<1><<<dim3(6, 64), 256, 0, stream>>>(Xch, Xcl, Woh, Wol, out_b, out, nullptr, nullptr);
}

// Round 5
// 371.995 us; speedup vs baseline: 2.5955x; 1.0530x over previous
//
#include <hip/hip_runtime.h>
#include <math.h>

#define B_   2
#define S_   4096
#define HID_ 768
#define H_   12
#define D_   64
#define M_   64
#define CK_  33
#define BH_  (B_*H_)   // 24
#define KD_  768
#define NCH_ 32        // k3v S-chunks
#define SC_  128       // keys per chunk

typedef float  f32x4  __attribute__((ext_vector_type(4)));
typedef short  bf16x8 __attribute__((ext_vector_type(8)));
typedef unsigned short u16;

__device__ __forceinline__ u16 f2bf(float f) {
  unsigned int u = __float_as_uint(f);
  u += 0x7FFFu + ((u >> 16) & 1u);   // round-to-nearest-even
  return (u16)(u >> 16);
}
__device__ __forceinline__ float bf2f(u16 s) {
  return __uint_as_float(((unsigned int)s) << 16);
}
// two float4 -> bf16x8 (hi) + bf16x8 (lo residual)
__device__ __forceinline__ void cvt8(const float4 a, const float4 b,
                                     bf16x8* hi, bf16x8* lo) {
  const float v[8] = {a.x, a.y, a.z, a.w, b.x, b.y, b.z, b.w};
  union { u16 u[8]; bf16x8 v; } H, L;
#pragma unroll
  for (int e = 0; e < 8; ++e) {
    const u16 hh = f2bf(v[e]);
    H.u[e] = hh;
    L.u[e] = f2bf(v[e] - bf2f(hh));
  }
  *hi = H.v; *lo = L.v;
}

__device__ __forceinline__ void gld16(const void* g, void* l) {
  __builtin_amdgcn_global_load_lds(
      (const __attribute__((address_space(1))) void*)g,
      (__attribute__((address_space(3))) void*)l, 16, 0, 0);
}

// =============================================================
// split fp32 -> (hi, lo) bf16 pair. 8 elements / thread.
// =============================================================
__global__ __launch_bounds__(256) void split_pair(
    const float* __restrict__ src, u16* __restrict__ h, u16* __restrict__ l, int n8)
{
  const int i = blockIdx.x * 256 + threadIdx.x;
  if (i >= n8) return;
  const float4* s4 = (const float4*)src;
  const float4 a = s4[2 * i], b = s4[2 * i + 1];
  const float v[8] = {a.x, a.y, a.z, a.w, b.x, b.y, b.z, b.w};
  union { u16 u[8]; uint4 q; } hv, lv;
#pragma unroll
  for (int e = 0; e < 8; ++e) {
    const u16 hh = f2bf(v[e]);
    hv.u[e] = hh;
    lv.u[e] = f2bf(v[e] - bf2f(hh));
  }
  ((uint4*)h)[i] = hv.q;
  ((uint4*)l)[i] = lv.q;
}

// =============================================================
// Split-bf16 3-product MFMA GEMM: C = A @ W^T (+bias)
// 128x128 tile, BK=32, 4 waves. LDS XOR-swizzle (T2, both-sides).
// DOUBLE-BUFFERED 2-phase pipeline: STAGE(next) issued before
// compute(cur); single vmcnt(0)-drain barrier per K-step (T3 min-2ph).
// MODE 0 additionally computes landmark segment means (Ql/Kl) in the
// epilogue: each tile holds 2 full segments x 2 full heads.
// =============================================================
template<int MODE>
__global__ __launch_bounds__(256) void gemm3_mfma(
    const u16* __restrict__ Ahg, const u16* __restrict__ Alg,
    const u16* __restrict__ Bhg, const u16* __restrict__ Blg,
    const float* __restrict__ bias,
    float* __restrict__ o0, float* __restrict__ o1, float* __restrict__ o2,
    float* __restrict__ Ql, float* __restrict__ Kl)
{
  __shared__ __align__(16) u16 lds[2][4][4096];   // [buf][Ah,Al,Bh,Bl][128*32]

  constexpr int NBX = (MODE == 0) ? 18 : 6;
  constexpr int CPX = (NBX * 64) / 8;
  constexpr int NT  = KD_ / 32;

  const int tid = threadIdx.x;
  const int lin = blockIdx.y * NBX + blockIdx.x;
  const int swb = (lin & 7) * CPX + (lin >> 3);    // XCD-contiguous chunks
  const int m0 = (swb / NBX) * 128;
  const int n0 = (swb % NBX) * 128;

  const int wave = tid >> 6, lane = tid & 63;
  const int wm = wave >> 1, wn = wave & 1;
  const int lr = lane & 15, kg = lane >> 4;

  // staging: phys row = tid>>2, phys q = tid&3; source holds logical q^swz
  const int srow = tid >> 2;
  const int swz_s = (tid >> 3) & 3;                // (row>>1)&3
  const int sk = ((tid & 3) ^ swz_s) * 8;

  const u16* pAh = Ahg + (size_t)(m0 + srow) * KD_ + sk;
  const u16* pAl = Alg + (size_t)(m0 + srow) * KD_ + sk;
  const u16* pBh = Bhg + (size_t)(n0 + srow) * KD_ + sk;
  const u16* pBl = Blg + (size_t)(n0 + srow) * KD_ + sk;

  f32x4 acc[4][4];
#pragma unroll
  for (int i = 0; i < 4; ++i)
#pragma unroll
    for (int j = 0; j < 4; ++j) acc[i][j] = (f32x4){0.f, 0.f, 0.f, 0.f};

  // fragment read: logical (row, kg) lives at phys q = kg ^ ((row>>1)&3)
  const int rsw = (lr >> 1) & 3;
  const int kq = (kg ^ rsw) * 8;
  const int abase = (wm * 64 + lr) * 32 + kq;
  const int bbase = (wn * 64 + lr) * 32 + kq;

#define STAGE_(buf, kt) do {                                        \
    const size_t go_ = (size_t)(kt) * 32;                           \
    u16* L_ = &lds[buf][0][0];                                      \
    gld16(pAh + go_,            L_ + tid * 8);                      \
    gld16(pAh + go_ + 64 * KD_, L_ + 2048 + tid * 8);               \
    gld16(pAl + go_,            L_ + 4096 + tid * 8);               \
    gld16(pAl + go_ + 64 * KD_, L_ + 6144 + tid * 8);               \
    gld16(pBh + go_,            L_ + 8192 + tid * 8);               \
    gld16(pBh + go_ + 64 * KD_, L_ + 10240 + tid * 8);              \
    gld16(pBl + go_,            L_ + 12288 + tid * 8);              \
    gld16(pBl + go_ + 64 * KD_, L_ + 14336 + tid * 8);              \
  } while (0)

  STAGE_(0, 0);
  __syncthreads();                 // drains vmcnt(0): buf0 ready

  int cur = 0;
  for (int kt = 0; kt < NT; ++kt) {
    if (kt + 1 < NT) STAGE_(cur ^ 1, kt + 1);   // prefetch next tile

    const u16* LAh = &lds[cur][0][0];
    const u16* LAl = &lds[cur][1][0];
    const u16* LBh = &lds[cur][2][0];
    const u16* LBl = &lds[cur][3][0];
    bf16x8 ah[4], al[4], bh[4], bl[4];
#pragma unroll
    for (int f = 0; f < 4; ++f) {
      ah[f] = *(const bf16x8*)&LAh[abase + f * 512];
      al[f] = *(const bf16x8*)&LAl[abase + f * 512];
      bh[f] = *(const bf16x8*)&LBh[bbase + f * 512];
      bl[f] = *(const bf16x8*)&LBl[bbase + f * 512];
    }
#pragma unroll
    for (int i = 0; i < 4; ++i)
#pragma unroll
      for (int j = 0; j < 4; ++j) {
        acc[i][j] = __builtin_amdgcn_mfma_f32_16x16x32_bf16(ah[i], bh[j], acc[i][j], 0, 0, 0);
        acc[i][j] = __builtin_amdgcn_mfma_f32_16x16x32_bf16(ah[i], bl[j], acc[i][j], 0, 0, 0);
        acc[i][j] = __builtin_amdgcn_mfma_f32_16x16x32_bf16(al[i], bh[j], acc[i][j], 0, 0, 0);
      }

    __syncthreads();               // drains vmcnt(0): next buf ready
    cur ^= 1;
  }
#undef STAGE_

  // ---- epilogue: C write (+ fused landmarks for MODE 0, parts 0/1) ----
#pragma unroll
  for (int i = 0; i < 4; ++i) {
    const int mbase = m0 + wm * 64 + i * 16 + kg * 4;
#pragma unroll
    for (int j = 0; j < 4; ++j) {
      const int ncol = n0 + wn * 64 + j * 16 + lr;
      const float bv = bias[ncol];
      if (MODE == 0) {
        const int part = (ncol >= 1536) ? 2 : (ncol >= 768 ? 1 : 0);
        const int within = ncol - part * 768;
        const int h0 = within >> 6, d = within & 63;
        float* base = (part == 0) ? o0 : ((part == 1) ? o1 : o2);
#pragma unroll
        for (int r = 0; r < 4; ++r) {
          const int row = mbase + r;
          const int b = row >> 12, s = row & (S_ - 1);
          base[(((size_t)(b * H_ + h0) * S_ + s) << 6) + d] = acc[i][j][r] + bv;
        }
      } else {
#pragma unroll
        for (int r = 0; r < 4; ++r) {
          const int row = mbase + r;
          o0[(size_t)row * HID_ + ncol] = acc[i][j][r] + bv;
        }
      }
    }
  }

  if (MODE == 0) {
    // landmark means: this wave's 64 rows (m0+wm*64 .. +63) form one full
    // segment of one (b,h); cols j*16+lr are head-dim d for head h0+wn.
    const int part = n0 / 768;
    if (part < 2) {
      const int within0 = n0 - part * 768;
      const int h = (within0 >> 6) + wn;
      const int rowseg = m0 + wm * 64;
      const int b = rowseg >> 12;
      const int seg = (rowseg & (S_ - 1)) >> 6;
      const int bh = b * H_ + h;
      float* dst = (part == 0) ? Ql : Kl;
#pragma unroll
      for (int j = 0; j < 4; ++j) {
        float sj = 0.f;
#pragma unroll
        for (int i = 0; i < 4; ++i)
#pragma unroll
          for (int r = 0; r < 4; ++r) sj += acc[i][j][r];
        sj += __shfl_xor(sj, 16);
        sj += __shfl_xor(sj, 32);
        if (kg == 0) {
          const int d = j * 16 + lr;
          const int ncol = n0 + wn * 64 + j * 16 + lr;
          dst[((size_t)bh * M_ + seg) * 64 + d] = sj * (1.f / 64.f) + bias[ncol];
        }
      }
    }
  }
}

// =============================================================
// kernel_2 softmax + per-(b,h) max col/row sums
// =============================================================
__global__ __launch_bounds__(256) void kernel2_softmax(
    const float* __restrict__ Ql, const float* __restrict__ Kl,
    float* __restrict__ K2, float* __restrict__ colmax, float* __restrict__ rowmax)
{
  __shared__ float Qs[64][68], Ks[64][68], S2[64][68];
  __shared__ float red1[64], red2[64];
  const int bh = blockIdx.x, tid = threadIdx.x;
  for (int idx = tid; idx < 4096; idx += 256) {
    const int r = idx >> 6, c = idx & 63;
    Qs[r][c] = Ql[(size_t)bh * 4096 + idx];
    Ks[r][c] = Kl[(size_t)bh * 4096 + idx];
  }
  __syncthreads();
  for (int idx = tid; idx < 4096; idx += 256) {
    const int r = idx >> 6, c = idx & 63;
    float dot = 0.f;
#pragma unroll
    for (int k = 0; k < 64; k += 4) {
      const float4 a = *(const float4*)&Qs[r][k];
      const float4 b = *(const float4*)&Ks[c][k];
      dot += a.x * b.x + a.y * b.y + a.z * b.z + a.w * b.w;
    }
    S2[r][c] = dot * 0.125f;
  }
  __syncthreads();
  if (tid < 64) {
    const int r = tid;
    float mx = -1e30f;
    for (int c = 0; c < 64; ++c) mx = fmaxf(mx, S2[r][c]);
    float sum = 0.f;
    for (int c = 0; c < 64; ++c) { const float e = expf(S2[r][c] - mx); S2[r][c] = e; sum += e; }
    const float inv = 1.f / sum;
    for (int c = 0; c < 64; ++c) S2[r][c] *= inv;
  }
  __syncthreads();
  for (int idx = tid; idx < 4096; idx += 256)
    K2[(size_t)bh * 4096 + idx] = S2[idx >> 6][idx & 63];
  if (tid < 64) {
    float cs = 0.f, rs = 0.f;
    for (int m = 0; m < 64; ++m) { cs += S2[m][tid]; rs += S2[tid][m]; }
    red1[tid] = cs; red2[tid] = rs;
  }
  __syncthreads();
  if (tid == 0) {
    float mc = 0.f, mr = 0.f;
    for (int i = 0; i < 64; ++i) { mc = fmaxf(mc, red1[i]); mr = fmaxf(mr, red2[i]); }
    colmax[bh] = mc; rowmax[bh] = mr;
  }
}

// 64x64x64 matmul in LDS (stride-68 padded)
__device__ inline void mm64(float (*C)[68], float (*A)[68], float (*B)[68], int tid)
{
  const int ry = tid >> 4, cx = tid & 15;
  const int r0 = ry * 4, c0 = cx * 4;
  float acc[4][4];
#pragma unroll
  for (int i = 0; i < 4; ++i)
#pragma unroll
    for (int j = 0; j < 4; ++j) acc[i][j] = 0.f;
  for (int k = 0; k < 64; k += 4) {
    float4 a[4], b[4];
#pragma unroll
    for (int i = 0; i < 4; ++i) a[i] = *(const float4*)&A[r0 + i][k];
#pragma unroll
    for (int j = 0; j < 4; ++j) b[j] = *(const float4*)&B[k + j][c0];
    const float bb[4][4] = {{b[0].x, b[0].y, b[0].z, b[0].w},
                            {b[1].x, b[1].y, b[1].z, b[1].w},
                            {b[2].x, b[2].y, b[2].z, b[2].w},
                            {b[3].x, b[3].y, b[3].z, b[3].w}};
    const float aa[4][4] = {{a[0].x, a[0].y, a[0].z, a[0].w},
                            {a[1].x, a[1].y, a[1].z, a[1].w},
                            {a[2].x, a[2].y, a[2].z, a[2].w},
                            {a[3].x, a[3].y, a[3].z, a[3].w}};
#pragma unroll
    for (int i = 0; i < 4; ++i)
#pragma unroll
      for (int j = 0; j < 4; ++j)
#pragma unroll
        for (int kk = 0; kk < 4; ++kk) acc[i][j] += aa[i][kk] * bb[kk][j];
  }
#pragma unroll
  for (int i = 0; i < 4; ++i)
    *(float4*)&C[r0 + i][c0] = make_float4(acc[i][0], acc[i][1], acc[i][2], acc[i][3]);
}

// =============================================================
// Newton-Schulz pseudo-inverse (6 iters, global scale)
// =============================================================
__global__ __launch_bounds__(256) void newton_inv(
    const float* __restrict__ K2, const float* __restrict__ colmax,
    const float* __restrict__ rowmax, float* __restrict__ Vinv)
{
  __shared__ float A_[64][68], V_[64][68], KV_[64][68], T_[64][68], U_[64][68];
  __shared__ float scale_s;
  const int bh = blockIdx.x, tid = threadIdx.x;
  if (tid == 0) {
    float mc = 0.f, mr = 0.f;
    for (int i = 0; i < BH_; ++i) { mc = fmaxf(mc, colmax[i]); mr = fmaxf(mr, rowmax[i]); }
    scale_s = 1.f / (mc * mr);
  }
  for (int idx = tid; idx < 4096; idx += 256)
    A_[idx >> 6][idx & 63] = K2[(size_t)bh * 4096 + idx];
  __syncthreads();
  const float scale = scale_s;
  for (int idx = tid; idx < 4096; idx += 256) {
    const int r = idx >> 6, c = idx & 63;
    V_[r][c] = scale * A_[c][r];
  }
  __syncthreads();
  for (int it = 0; it < 6; ++it) {
    mm64(KV_, A_, V_, tid); __syncthreads();
    for (int idx = tid; idx < 4096; idx += 256) {
      const int r = idx >> 6, c = idx & 63;
      T_[r][c] = (r == c ? 7.f : 0.f) - KV_[r][c];
    }
    __syncthreads();
    mm64(U_, KV_, T_, tid); __syncthreads();
    for (int idx = tid; idx < 4096; idx += 256) {
      const int r = idx >> 6, c = idx & 63;
      T_[r][c] = (r == c ? 15.f : 0.f) - U_[r][c];
    }
    __syncthreads();
    mm64(U_, KV_, T_, tid); __syncthreads();
    for (int idx = tid; idx < 4096; idx += 256) {
      const int r = idx >> 6, c = idx & 63;
      T_[r][c] = (r == c ? 13.f : 0.f) - U_[r][c];
    }
    __syncthreads();
    mm64(U_, V_, T_, tid); __syncthreads();
    for (int idx = tid; idx < 4096; idx += 256) {
      const int r = idx >> 6, c = idx & 63;
      V_[r][c] = 0.25f * U_[r][c];
    }
    __syncthreads();
  }
  for (int idx = tid; idx < 4096; idx += 256)
    Vinv[(size_t)bh * 4096 + idx] = V_[idx >> 6][idx & 63];
}

// =============================================================
// k3v pass 1: S = Ql @ K_chunk^T / 8 (MFMA), partial softmax + O_j
// =============================================================
__global__ __launch_bounds__(256) void k3v_pass1(
    const float* __restrict__ Ql, const float* __restrict__ K,
    const float* __restrict__ V, float* __restrict__ Opart,
    float* __restrict__ mpart, float* __restrict__ lpart)
{
  __shared__ float P[64][129];
  __shared__ float red1[64][4], red2[64][4];

  const int ch = blockIdx.x;     // 0..31
  const int bh = blockIdx.y;     // 0..23
  const int tid = threadIdx.x;
  const int wave = tid >> 6, lane = tid & 63;
  const int lr = lane & 15, kg = lane >> 4;

  const float* Qlb = Ql + (size_t)bh * 4096;
  const float* Kb  = K + (size_t)bh * S_ * 64;
  const float* Vb  = V + (size_t)bh * S_ * 64;

  bf16x8 ah[4][2], al[4][2];
#pragma unroll
  for (int mt = 0; mt < 4; ++mt)
#pragma unroll
    for (int kk = 0; kk < 2; ++kk) {
      const float* qr = Qlb + (size_t)(mt * 16 + lr) * 64 + kk * 32 + kg * 8;
      cvt8(*(const float4*)qr, *(const float4*)(qr + 4), &ah[mt][kk], &al[mt][kk]);
    }

#pragma unroll
  for (int t = 0; t < 2; ++t) {
    const int s0 = (wave * 2 + t) * 16;
    const int srow = ch * SC_ + s0 + lr;
    f32x4 acc[4];
#pragma unroll
    for (int mt = 0; mt < 4; ++mt) acc[mt] = (f32x4){0.f, 0.f, 0.f, 0.f};
#pragma unroll
    for (int kk = 0; kk < 2; ++kk) {
      const float* kr = Kb + (size_t)srow * 64 + kk * 32 + kg * 8;
      bf16x8 bhf, blf;
      cvt8(*(const float4*)kr, *(const float4*)(kr + 4), &bhf, &blf);
#pragma unroll
      for (int mt = 0; mt < 4; ++mt) {
        acc[mt] = __builtin_amdgcn_mfma_f32_16x16x32_bf16(ah[mt][kk], bhf, acc[mt], 0, 0, 0);
        acc[mt] = __builtin_amdgcn_mfma_f32_16x16x32_bf16(ah[mt][kk], blf, acc[mt], 0, 0, 0);
        acc[mt] = __builtin_amdgcn_mfma_f32_16x16x32_bf16(al[mt][kk], bhf, acc[mt], 0, 0, 0);
      }
    }
#pragma unroll
    for (int mt = 0; mt < 4; ++mt)
#pragma unroll
      for (int r = 0; r < 4; ++r)
        P[mt * 16 + kg * 4 + r][s0 + lr] = acc[mt][r] * 0.125f;
  }
  __syncthreads();

  const int r = tid >> 2, q = tid & 3;
  {
    float mx = -1e30f;
#pragma unroll
    for (int s = 0; s < 32; ++s) mx = fmaxf(mx, P[r][q * 32 + s]);
    red1[r][q] = mx;
  }
  __syncthreads();
  const float rowmax = fmaxf(fmaxf(red1[r][0], red1[r][1]),
                             fmaxf(red1[r][2], red1[r][3]));
  {
    float sum = 0.f;
#pragma unroll
    for (int s = 0; s < 32; ++s) {
      const float e = expf(P[r][q * 32 + s] - rowmax);
      P[r][q * 32 + s] = e;
      sum += e;
    }
    red2[r][q] = sum;
  }
  __syncthreads();
  if (q == 0) {
    const float rowsum = red2[r][0] + red2[r][1] + red2[r][2] + red2[r][3];
    mpart[((size_t)bh * NCH_ + ch) * 64 + r] = rowmax;
    lpart[((size_t)bh * NCH_ + ch) * 64 + r] = rowsum;
  }

  const int mg = tid >> 4, dq = (tid & 15) * 4;
  float4 oacc[4];
#pragma unroll
  for (int i = 0; i < 4; ++i) oacc[i] = make_float4(0.f, 0.f, 0.f, 0.f);
  for (int s = 0; s < SC_; ++s) {
    const float4 v = *(const float4*)&Vb[(size_t)(ch * SC_ + s) * 64 + dq];
#pragma unroll
    for (int i = 0; i < 4; ++i) {
      const float p = P[mg * 4 + i][s];
      oacc[i].x += p * v.x; oacc[i].y += p * v.y;
      oacc[i].z += p * v.z; oacc[i].w += p * v.w;
    }
  }
#pragma unroll
  for (int i = 0; i < 4; ++i) {
    const size_t o = (((size_t)bh * NCH_ + ch) * 64 + mg * 4 + i) * 64 + dq;
    *(float4*)&Opart[o] = oacc[i];
  }
}

// =============================================================
// k3v pass 2 + W2: combine chunks -> W1 (LDS), then W2 = Vinv @ W1
// =============================================================
__global__ __launch_bounds__(256) void k3v_combine_w2(
    const float* __restrict__ Opart, const float* __restrict__ mpart,
    const float* __restrict__ lpart, const float* __restrict__ Vinv,
    float* __restrict__ W2)
{
  __shared__ float w[64][33];
  __shared__ float W1s[64][68], Vs[64][68], C_[64][68];
  const int bh = blockIdx.x, tid = threadIdx.x;
  for (int idx = tid; idx < 4096; idx += 256)
    Vs[idx >> 6][idx & 63] = Vinv[(size_t)bh * 4096 + idx];
  if (tid < 64) {
    const int m = tid;
    float M = -1e30f;
    for (int j = 0; j < NCH_; ++j)
      M = fmaxf(M, mpart[((size_t)bh * NCH_ + j) * 64 + m]);
    float denom = 0.f;
    for (int j = 0; j < NCH_; ++j)
      denom += expf(mpart[((size_t)bh * NCH_ + j) * 64 + m] - M) *
               lpart[((size_t)bh * NCH_ + j) * 64 + m];
    const float inv = 1.f / denom;
    for (int j = 0; j < NCH_; ++j)
      w[m][j] = expf(mpart[((size_t)bh * NCH_ + j) * 64 + m] - M) * inv;
  }
  __syncthreads();
  const int mg = tid >> 4, dq = (tid & 15) * 4;
#pragma unroll
  for (int i = 0; i < 4; ++i) {
    const int m = mg * 4 + i;
    float4 acc = make_float4(0.f, 0.f, 0.f, 0.f);
    for (int j = 0; j < NCH_; ++j) {
      const float ww = w[m][j];
      const float4 o = *(const float4*)&Opart[(((size_t)bh * NCH_ + j) * 64 + m) * 64 + dq];
      acc.x += ww * o.x; acc.y += ww * o.y; acc.z += ww * o.z; acc.w += ww * o.w;
    }
    *(float4*)&W1s[m][dq] = acc;
  }
  __syncthreads();
  mm64(C_, Vs, W1s, tid);
  __syncthreads();
  for (int idx = tid; idx < 4096; idx += 256)
    W2[(size_t)bh * 4096 + idx] = C_[idx >> 6][idx & 63];
}

// =============================================================
// X = softmax(Q @ Kl^T / 8) @ W2  -> Xc [B,S,HID] fp32
// =============================================================
__global__ __launch_bounds__(256) void attn_core(
    const float* __restrict__ Q, const float* __restrict__ Kl,
    const float* __restrict__ W2, float* __restrict__ Xc)
{
  __shared__ float Kls[64][64];
  __shared__ float W2s[64][64];
  const int blk = blockIdx.x;
  const int bh = blk >> 4, chunk = blk & 15;
  const int tid = threadIdx.x;
  const int b = bh / H_, h = bh % H_;
  for (int idx = tid; idx < 4096; idx += 256) {
    Kls[idx >> 6][idx & 63] = Kl[(size_t)bh * 4096 + idx];
    W2s[idx >> 6][idx & 63] = W2[(size_t)bh * 4096 + idx];
  }
  __syncthreads();
  const int s = chunk * 256 + tid;
  const float* qp = Q + ((size_t)bh * S_ + s) * 64;
  float4 q4[16];
#pragma unroll
  for (int k = 0; k < 16; ++k) q4[k] = *(const float4*)&qp[k * 4];
  float p[64];
#pragma unroll
  for (int m = 0; m < 64; ++m) {
    float dot = 0.f;
#pragma unroll
    for (int k = 0; k < 16; ++k) {
      const float4 kv = *(const float4*)&Kls[m][k * 4];
      dot += q4[k].x * kv.x + q4[k].y * kv.y + q4[k].z * kv.z + q4[k].w * kv.w;
    }
    p[m] = dot * 0.125f;
  }
  float mx = -1e30f;
#pragma unroll
  for (int m = 0; m < 64; ++m) mx = fmaxf(mx, p[m]);
  float sum = 0.f;
#pragma unroll
  for (int m = 0; m < 64; ++m) { p[m] = expf(p[m] - mx); sum += p[m]; }
  const float inv = 1.f / sum;
#pragma unroll
  for (int m = 0; m < 64; ++m) p[m] *= inv;
  float4 o4[16];
#pragma unroll
  for (int k = 0; k < 16; ++k) o4[k] = make_float4(0.f, 0.f, 0.f, 0.f);
#pragma unroll
  for (int m = 0; m < 64; ++m) {
    const float pm = p[m];
#pragma unroll
    for (int k = 0; k < 16; ++k) {
      const float4 wv = *(const float4*)&W2s[m][k * 4];
      o4[k].x += pm * wv.x; o4[k].y += pm * wv.y;
      o4[k].z += pm * wv.z; o4[k].w += pm * wv.w;
    }
  }
  float* xp = Xc + ((size_t)(b * S_ + s)) * HID_ + h * 64;
#pragma unroll
  for (int k = 0; k < 16; ++k) *(float4*)&xp[k * 4] = o4[k];
}

// =============================================================
// Depthwise conv + add attn, write split-bf16 (input of out-GEMM)
// =============================================================
__global__ __launch_bounds__(256) void conv_add_split(
    const float* __restrict__ V, const float* __restrict__ cw,
    const float* __restrict__ Xc, u16* __restrict__ Xch, u16* __restrict__ Xcl)
{
  __shared__ float Vs[160][64];
  __shared__ float cws[33];
  const int blk = blockIdx.x;
  const int bh = blk >> 5, chunk = blk & 31;
  const int tid = threadIdx.x;
  const int b = bh / H_, h = bh % H_;
  const int s0 = chunk * 128;
  if (tid < 33) cws[tid] = cw[h * 33 + tid];
  const float* Vb = V + (size_t)bh * S_ * 64;
  for (int idx = tid; idx < 160 * 64; idx += 256) {
    const int r = idx >> 6, c = idx & 63;
    const int sv = s0 - 16 + r;
    Vs[r][c] = (sv >= 0 && sv < S_) ? Vb[(size_t)sv * 64 + c] : 0.f;
  }
  __syncthreads();
  const int d = tid & 63, rg = tid >> 6;
  for (int rr = 0; rr < 32; ++rr) {
    const int r = rg * 32 + rr;
    float acc = 0.f;
#pragma unroll
    for (int t = 0; t < 33; ++t) acc += Vs[r + t][d] * cws[t];
    const size_t idx = ((size_t)(b * S_ + s0 + r)) * HID_ + h * 64 + d;
    const float o = Xc[idx] + acc;
    const u16 hh = f2bf(o);
    Xch[idx] = hh;
    Xcl[idx] = f2bf(o - bf2f(hh));
  }
}

// =============================================================
extern "C" void kernel_launch(void* const* d_in, const int* in_sizes, int n_in,
                              void* d_out, int out_size, void* d_ws, size_t ws_size,
                              hipStream_t stream)
{
  (void)in_sizes; (void)n_in; (void)out_size; (void)ws_size;
  const float* x      = (const float*)d_in[0];
  const float* qkv_w  = (const float*)d_in[1];
  const float* qkv_b  = (const float*)d_in[2];
  const float* conv_w = (const float*)d_in[3];
  const float* out_w  = (const float*)d_in[4];
  const float* out_b  = (const float*)d_in[5];
  float* out = (float*)d_out;

  // fp32 region
  float* ws   = (float*)d_ws;
  float* Q    = ws;                       // [BH,S,D] 6291456
  float* K    = Q + 6291456;
  float* V    = K + 6291456;
  float* Ql   = V + 6291456;              // 98304 each below
  float* Kl   = Ql + 98304;
  float* K2   = Kl + 98304;
  float* Vinv = K2 + 98304;
  float* W1   = Vinv + 98304;
  float* W2   = W1 + 98304;
  float* colmax = W2 + 98304;
  float* rowmax = colmax + 32;
  // bf16 (u16) region
  u16* ub  = (u16*)(rowmax + 32);
  u16* Xh  = ub;                          // 6291456 u16
  u16* Xl  = Xh + 6291456;
  u16* Wqh = Xl + 6291456;                // 1769472
  u16* Wql = Wqh + 1769472;
  u16* Woh = Wql + 1769472;               // 589824
  u16* Wol = Woh + 589824;
  // aliases
  u16* Xch = Xh;                          // Xh/Xl dead between QKV GEMM and conv
  u16* Xcl = Xl;
  float* Xc = K;                          // K dead after k3v_pass1
  float* Opart = (float*)Xh;              // 3145728 floats (exact fit)
  float* mpart = (float*)Xl;              // 49152
  float* lpart = mpart + BH_ * NCH_ * 64; // 49152

  split_pair<<<786432 / 256, 256, 0, stream>>>(x, Xh, Xl, 786432);
  split_pair<<<221184 / 256, 256, 0, stream>>>(qkv_w, Wqh, Wql, 221184);
  split_pair<<<73728 / 256, 256, 0, stream>>>(out_w, Woh, Wol, 73728);

  gemm3_mfma<0><<<dim3(18, 64), 256, 0, stream>>>(Xh, Xl, Wqh, Wql, qkv_b,
                                                  Q, K, V, Ql, Kl);

  kernel2_softmax<<<BH_, 256, 0, stream>>>(Ql, Kl, K2, colmax, rowmax);
  newton_inv<<<BH_, 256, 0, stream>>>(K2, colmax, rowmax, Vinv);

  k3v_pass1<<<dim3(NCH_, BH_), 256, 0, stream>>>(Ql, K, V, Opart, mpart, lpart);
  k3v_combine_w2<<<BH_, 256, 0, stream>>>(Opart, mpart, lpart, Vinv, W2);

  attn_core<<<BH_ * 16, 256, 0, stream>>>(Q, Kl, W2, Xc);
  conv_add_split<<<BH_ * 32, 256, 0, stream>>>(V, conv_w, Xc, Xch, Xcl);

  gemm3_mfma<1><<<dim3(6, 64), 256, 0, stream>>>(Xch, Xcl, Woh, Wol, out_b,
                                                 out, nullptr, nullptr, nullptr, nullptr);
}

// Round 6
// 359.095 us; speedup vs baseline: 2.6888x; 1.0359x over previous
//
#include <hip/hip_runtime.h>
#include <math.h>

#define B_   2
#define S_   4096
#define HID_ 768
#define H_   12
#define D_   64
#define M_   64
#define CK_  33
#define BH_  (B_*H_)   // 24
#define KD_  768
#define NCH_ 32        // k3v S-chunks
#define SC_  128       // keys per chunk

typedef float  f32x4  __attribute__((ext_vector_type(4)));
typedef short  bf16x8 __attribute__((ext_vector_type(8)));
typedef unsigned short u16;

__device__ __forceinline__ u16 f2bf(float f) {
  unsigned int u = __float_as_uint(f);
  u += 0x7FFFu + ((u >> 16) & 1u);   // round-to-nearest-even
  return (u16)(u >> 16);
}
__device__ __forceinline__ float bf2f(u16 s) {
  return __uint_as_float(((unsigned int)s) << 16);
}
// two float4 -> bf16x8 (hi) + bf16x8 (lo residual)
__device__ __forceinline__ void cvt8(const float4 a, const float4 b,
                                     bf16x8* hi, bf16x8* lo) {
  const float v[8] = {a.x, a.y, a.z, a.w, b.x, b.y, b.z, b.w};
  union { u16 u[8]; bf16x8 v; } H, L;
#pragma unroll
  for (int e = 0; e < 8; ++e) {
    const u16 hh = f2bf(v[e]);
    H.u[e] = hh;
    L.u[e] = f2bf(v[e] - bf2f(hh));
  }
  *hi = H.v; *lo = L.v;
}

__device__ __forceinline__ void gld16(const void* g, void* l) {
  __builtin_amdgcn_global_load_lds(
      (const __attribute__((address_space(1))) void*)g,
      (__attribute__((address_space(3))) void*)l, 16, 0, 0);
}

// =============================================================
// split fp32 -> (hi, lo) bf16 pair. 8 elements / thread.
// =============================================================
__global__ __launch_bounds__(256) void split_pair(
    const float* __restrict__ src, u16* __restrict__ h, u16* __restrict__ l, int n8)
{
  const int i = blockIdx.x * 256 + threadIdx.x;
  if (i >= n8) return;
  const float4* s4 = (const float4*)src;
  const float4 a = s4[2 * i], b = s4[2 * i + 1];
  const float v[8] = {a.x, a.y, a.z, a.w, b.x, b.y, b.z, b.w};
  union { u16 u[8]; uint4 q; } hv, lv;
#pragma unroll
  for (int e = 0; e < 8; ++e) {
    const u16 hh = f2bf(v[e]);
    hv.u[e] = hh;
    lv.u[e] = f2bf(v[e] - bf2f(hh));
  }
  ((uint4*)h)[i] = hv.q;
  ((uint4*)l)[i] = lv.q;
}

// =============================================================
// Split-bf16 3-product MFMA GEMM: C = A @ W^T (+bias)
// 128x128 tile, BK=32, 4 waves. LDS XOR-swizzle (T2, both-sides).
// Double-buffered 2-phase pipeline. MODE 0 fuses landmark means.
// =============================================================
template<int MODE>
__global__ __launch_bounds__(256) void gemm3_mfma(
    const u16* __restrict__ Ahg, const u16* __restrict__ Alg,
    const u16* __restrict__ Bhg, const u16* __restrict__ Blg,
    const float* __restrict__ bias,
    float* __restrict__ o0, float* __restrict__ o1, float* __restrict__ o2,
    float* __restrict__ Ql, float* __restrict__ Kl)
{
  __shared__ __align__(16) u16 lds[2][4][4096];   // [buf][Ah,Al,Bh,Bl][128*32]

  constexpr int NBX = (MODE == 0) ? 18 : 6;
  constexpr int CPX = (NBX * 64) / 8;
  constexpr int NT  = KD_ / 32;

  const int tid = threadIdx.x;
  const int lin = blockIdx.y * NBX + blockIdx.x;
  const int swb = (lin & 7) * CPX + (lin >> 3);    // XCD-contiguous chunks
  const int m0 = (swb / NBX) * 128;
  const int n0 = (swb % NBX) * 128;

  const int wave = tid >> 6, lane = tid & 63;
  const int wm = wave >> 1, wn = wave & 1;
  const int lr = lane & 15, kg = lane >> 4;

  // staging: phys row = tid>>2, phys q = tid&3; source holds logical q^swz
  const int srow = tid >> 2;
  const int swz_s = (tid >> 3) & 3;                // (row>>1)&3
  const int sk = ((tid & 3) ^ swz_s) * 8;

  const u16* pAh = Ahg + (size_t)(m0 + srow) * KD_ + sk;
  const u16* pAl = Alg + (size_t)(m0 + srow) * KD_ + sk;
  const u16* pBh = Bhg + (size_t)(n0 + srow) * KD_ + sk;
  const u16* pBl = Blg + (size_t)(n0 + srow) * KD_ + sk;

  f32x4 acc[4][4];
#pragma unroll
  for (int i = 0; i < 4; ++i)
#pragma unroll
    for (int j = 0; j < 4; ++j) acc[i][j] = (f32x4){0.f, 0.f, 0.f, 0.f};

  // fragment read: logical (row, kg) lives at phys q = kg ^ ((row>>1)&3)
  const int rsw = (lr >> 1) & 3;
  const int kq = (kg ^ rsw) * 8;
  const int abase = (wm * 64 + lr) * 32 + kq;
  const int bbase = (wn * 64 + lr) * 32 + kq;

#define STAGE_(buf, kt) do {                                        \
    const size_t go_ = (size_t)(kt) * 32;                           \
    u16* L_ = &lds[buf][0][0];                                      \
    gld16(pAh + go_,            L_ + tid * 8);                      \
    gld16(pAh + go_ + 64 * KD_, L_ + 2048 + tid * 8);               \
    gld16(pAl + go_,            L_ + 4096 + tid * 8);               \
    gld16(pAl + go_ + 64 * KD_, L_ + 6144 + tid * 8);               \
    gld16(pBh + go_,            L_ + 8192 + tid * 8);               \
    gld16(pBh + go_ + 64 * KD_, L_ + 10240 + tid * 8);              \
    gld16(pBl + go_,            L_ + 12288 + tid * 8);              \
    gld16(pBl + go_ + 64 * KD_, L_ + 14336 + tid * 8);              \
  } while (0)

  STAGE_(0, 0);
  __syncthreads();                 // drains vmcnt(0): buf0 ready

  int cur = 0;
  for (int kt = 0; kt < NT; ++kt) {
    if (kt + 1 < NT) STAGE_(cur ^ 1, kt + 1);   // prefetch next tile

    const u16* LAh = &lds[cur][0][0];
    const u16* LAl = &lds[cur][1][0];
    const u16* LBh = &lds[cur][2][0];
    const u16* LBl = &lds[cur][3][0];
    bf16x8 ah[4], al[4], bh[4], bl[4];
#pragma unroll
    for (int f = 0; f < 4; ++f) {
      ah[f] = *(const bf16x8*)&LAh[abase + f * 512];
      al[f] = *(const bf16x8*)&LAl[abase + f * 512];
      bh[f] = *(const bf16x8*)&LBh[bbase + f * 512];
      bl[f] = *(const bf16x8*)&LBl[bbase + f * 512];
    }
#pragma unroll
    for (int i = 0; i < 4; ++i)
#pragma unroll
      for (int j = 0; j < 4; ++j) {
        acc[i][j] = __builtin_amdgcn_mfma_f32_16x16x32_bf16(ah[i], bh[j], acc[i][j], 0, 0, 0);
        acc[i][j] = __builtin_amdgcn_mfma_f32_16x16x32_bf16(ah[i], bl[j], acc[i][j], 0, 0, 0);
        acc[i][j] = __builtin_amdgcn_mfma_f32_16x16x32_bf16(al[i], bh[j], acc[i][j], 0, 0, 0);
      }

    __syncthreads();               // drains vmcnt(0): next buf ready
    cur ^= 1;
  }
#undef STAGE_

  // ---- epilogue: C write (+ fused landmarks for MODE 0, parts 0/1) ----
#pragma unroll
  for (int i = 0; i < 4; ++i) {
    const int mbase = m0 + wm * 64 + i * 16 + kg * 4;
#pragma unroll
    for (int j = 0; j < 4; ++j) {
      const int ncol = n0 + wn * 64 + j * 16 + lr;
      const float bv = bias[ncol];
      if (MODE == 0) {
        const int part = (ncol >= 1536) ? 2 : (ncol >= 768 ? 1 : 0);
        const int within = ncol - part * 768;
        const int h0 = within >> 6, d = within & 63;
        float* base = (part == 0) ? o0 : ((part == 1) ? o1 : o2);
#pragma unroll
        for (int r = 0; r < 4; ++r) {
          const int row = mbase + r;
          const int b = row >> 12, s = row & (S_ - 1);
          base[(((size_t)(b * H_ + h0) * S_ + s) << 6) + d] = acc[i][j][r] + bv;
        }
      } else {
#pragma unroll
        for (int r = 0; r < 4; ++r) {
          const int row = mbase + r;
          o0[(size_t)row * HID_ + ncol] = acc[i][j][r] + bv;
        }
      }
    }
  }

  if (MODE == 0) {
    // landmark means: this wave's 64 rows form one full segment of one (b,h)
    const int part = n0 / 768;
    if (part < 2) {
      const int within0 = n0 - part * 768;
      const int h = (within0 >> 6) + wn;
      const int rowseg = m0 + wm * 64;
      const int b = rowseg >> 12;
      const int seg = (rowseg & (S_ - 1)) >> 6;
      const int bh = b * H_ + h;
      float* dst = (part == 0) ? Ql : Kl;
#pragma unroll
      for (int j = 0; j < 4; ++j) {
        float sj = 0.f;
#pragma unroll
        for (int i = 0; i < 4; ++i)
#pragma unroll
          for (int r = 0; r < 4; ++r) sj += acc[i][j][r];
        sj += __shfl_xor(sj, 16);
        sj += __shfl_xor(sj, 32);
        if (kg == 0) {
          const int d = j * 16 + lr;
          const int ncol = n0 + wn * 64 + j * 16 + lr;
          dst[((size_t)bh * M_ + seg) * 64 + d] = sj * (1.f / 64.f) + bias[ncol];
        }
      }
    }
  }
}

// =============================================================
// kernel_2 softmax + per-(b,h) max col/row sums
// =============================================================
__global__ __launch_bounds__(256) void kernel2_softmax(
    const float* __restrict__ Ql, const float* __restrict__ Kl,
    float* __restrict__ K2, float* __restrict__ colmax, float* __restrict__ rowmax)
{
  __shared__ float Qs[64][68], Ks[64][68], S2[64][68];
  __shared__ float red1[64], red2[64];
  const int bh = blockIdx.x, tid = threadIdx.x;
  for (int idx = tid; idx < 4096; idx += 256) {
    const int r = idx >> 6, c = idx & 63;
    Qs[r][c] = Ql[(size_t)bh * 4096 + idx];
    Ks[r][c] = Kl[(size_t)bh * 4096 + idx];
  }
  __syncthreads();
  for (int idx = tid; idx < 4096; idx += 256) {
    const int r = idx >> 6, c = idx & 63;
    float dot = 0.f;
#pragma unroll
    for (int k = 0; k < 64; k += 4) {
      const float4 a = *(const float4*)&Qs[r][k];
      const float4 b = *(const float4*)&Ks[c][k];
      dot += a.x * b.x + a.y * b.y + a.z * b.z + a.w * b.w;
    }
    S2[r][c] = dot * 0.125f;
  }
  __syncthreads();
  if (tid < 64) {
    const int r = tid;
    float mx = -1e30f;
    for (int c = 0; c < 64; ++c) mx = fmaxf(mx, S2[r][c]);
    float sum = 0.f;
    for (int c = 0; c < 64; ++c) { const float e = expf(S2[r][c] - mx); S2[r][c] = e; sum += e; }
    const float inv = 1.f / sum;
    for (int c = 0; c < 64; ++c) S2[r][c] *= inv;
  }
  __syncthreads();
  for (int idx = tid; idx < 4096; idx += 256)
    K2[(size_t)bh * 4096 + idx] = S2[idx >> 6][idx & 63];
  if (tid < 64) {
    float cs = 0.f, rs = 0.f;
    for (int m = 0; m < 64; ++m) { cs += S2[m][tid]; rs += S2[tid][m]; }
    red1[tid] = cs; red2[tid] = rs;
  }
  __syncthreads();
  if (tid == 0) {
    float mc = 0.f, mr = 0.f;
    for (int i = 0; i < 64; ++i) { mc = fmaxf(mc, red1[i]); mr = fmaxf(mr, red2[i]); }
    colmax[bh] = mc; rowmax[bh] = mr;
  }
}

// 64x64x64 matmul in LDS (stride-68 padded)
__device__ inline void mm64(float (*C)[68], float (*A)[68], float (*B)[68], int tid)
{
  const int ry = tid >> 4, cx = tid & 15;
  const int r0 = ry * 4, c0 = cx * 4;
  float acc[4][4];
#pragma unroll
  for (int i = 0; i < 4; ++i)
#pragma unroll
    for (int j = 0; j < 4; ++j) acc[i][j] = 0.f;
  for (int k = 0; k < 64; k += 4) {
    float4 a[4], b[4];
#pragma unroll
    for (int i = 0; i < 4; ++i) a[i] = *(const float4*)&A[r0 + i][k];
#pragma unroll
    for (int j = 0; j < 4; ++j) b[j] = *(const float4*)&B[k + j][c0];
    const float bb[4][4] = {{b[0].x, b[0].y, b[0].z, b[0].w},
                            {b[1].x, b[1].y, b[1].z, b[1].w},
                            {b[2].x, b[2].y, b[2].z, b[2].w},
                            {b[3].x, b[3].y, b[3].z, b[3].w}};
    const float aa[4][4] = {{a[0].x, a[0].y, a[0].z, a[0].w},
                            {a[1].x, a[1].y, a[1].z, a[1].w},
                            {a[2].x, a[2].y, a[2].z, a[2].w},
                            {a[3].x, a[3].y, a[3].z, a[3].w}};
#pragma unroll
    for (int i = 0; i < 4; ++i)
#pragma unroll
      for (int j = 0; j < 4; ++j)
#pragma unroll
        for (int kk = 0; kk < 4; ++kk) acc[i][j] += aa[i][kk] * bb[kk][j];
  }
#pragma unroll
  for (int i = 0; i < 4; ++i)
    *(float4*)&C[r0 + i][c0] = make_float4(acc[i][0], acc[i][1], acc[i][2], acc[i][3]);
}

// =============================================================
// Newton-Schulz pseudo-inverse (6 iters, global scale)
// =============================================================
__global__ __launch_bounds__(256) void newton_inv(
    const float* __restrict__ K2, const float* __restrict__ colmax,
    const float* __restrict__ rowmax, float* __restrict__ Vinv)
{
  __shared__ float A_[64][68], V_[64][68], KV_[64][68], T_[64][68], U_[64][68];
  __shared__ float scale_s;
  const int bh = blockIdx.x, tid = threadIdx.x;
  if (tid == 0) {
    float mc = 0.f, mr = 0.f;
    for (int i = 0; i < BH_; ++i) { mc = fmaxf(mc, colmax[i]); mr = fmaxf(mr, rowmax[i]); }
    scale_s = 1.f / (mc * mr);
  }
  for (int idx = tid; idx < 4096; idx += 256)
    A_[idx >> 6][idx & 63] = K2[(size_t)bh * 4096 + idx];
  __syncthreads();
  const float scale = scale_s;
  for (int idx = tid; idx < 4096; idx += 256) {
    const int r = idx >> 6, c = idx & 63;
    V_[r][c] = scale * A_[c][r];
  }
  __syncthreads();
  for (int it = 0; it < 6; ++it) {
    mm64(KV_, A_, V_, tid); __syncthreads();
    for (int idx = tid; idx < 4096; idx += 256) {
      const int r = idx >> 6, c = idx & 63;
      T_[r][c] = (r == c ? 7.f : 0.f) - KV_[r][c];
    }
    __syncthreads();
    mm64(U_, KV_, T_, tid); __syncthreads();
    for (int idx = tid; idx < 4096; idx += 256) {
      const int r = idx >> 6, c = idx & 63;
      T_[r][c] = (r == c ? 15.f : 0.f) - U_[r][c];
    }
    __syncthreads();
    mm64(U_, KV_, T_, tid); __syncthreads();
    for (int idx = tid; idx < 4096; idx += 256) {
      const int r = idx >> 6, c = idx & 63;
      T_[r][c] = (r == c ? 13.f : 0.f) - U_[r][c];
    }
    __syncthreads();
    mm64(U_, V_, T_, tid); __syncthreads();
    for (int idx = tid; idx < 4096; idx += 256) {
      const int r = idx >> 6, c = idx & 63;
      V_[r][c] = 0.25f * U_[r][c];
    }
    __syncthreads();
  }
  for (int idx = tid; idx < 4096; idx += 256)
    Vinv[(size_t)bh * 4096 + idx] = V_[idx >> 6][idx & 63];
}

// =============================================================
// k3v pass 1: S = Ql @ K_chunk^T / 8 (MFMA), partial softmax + O_j
// =============================================================
__global__ __launch_bounds__(256) void k3v_pass1(
    const float* __restrict__ Ql, const float* __restrict__ K,
    const float* __restrict__ V, float* __restrict__ Opart,
    float* __restrict__ mpart, float* __restrict__ lpart)
{
  __shared__ float P[64][129];
  __shared__ float red1[64][4], red2[64][4];

  const int ch = blockIdx.x;     // 0..31
  const int bh = blockIdx.y;     // 0..23
  const int tid = threadIdx.x;
  const int wave = tid >> 6, lane = tid & 63;
  const int lr = lane & 15, kg = lane >> 4;

  const float* Qlb = Ql + (size_t)bh * 4096;
  const float* Kb  = K + (size_t)bh * S_ * 64;
  const float* Vb  = V + (size_t)bh * S_ * 64;

  bf16x8 ah[4][2], al[4][2];
#pragma unroll
  for (int mt = 0; mt < 4; ++mt)
#pragma unroll
    for (int kk = 0; kk < 2; ++kk) {
      const float* qr = Qlb + (size_t)(mt * 16 + lr) * 64 + kk * 32 + kg * 8;
      cvt8(*(const float4*)qr, *(const float4*)(qr + 4), &ah[mt][kk], &al[mt][kk]);
    }

#pragma unroll
  for (int t = 0; t < 2; ++t) {
    const int s0 = (wave * 2 + t) * 16;
    const int srow = ch * SC_ + s0 + lr;
    f32x4 acc[4];
#pragma unroll
    for (int mt = 0; mt < 4; ++mt) acc[mt] = (f32x4){0.f, 0.f, 0.f, 0.f};
#pragma unroll
    for (int kk = 0; kk < 2; ++kk) {
      const float* kr = Kb + (size_t)srow * 64 + kk * 32 + kg * 8;
      bf16x8 bhf, blf;
      cvt8(*(const float4*)kr, *(const float4*)(kr + 4), &bhf, &blf);
#pragma unroll
      for (int mt = 0; mt < 4; ++mt) {
        acc[mt] = __builtin_amdgcn_mfma_f32_16x16x32_bf16(ah[mt][kk], bhf, acc[mt], 0, 0, 0);
        acc[mt] = __builtin_amdgcn_mfma_f32_16x16x32_bf16(ah[mt][kk], blf, acc[mt], 0, 0, 0);
        acc[mt] = __builtin_amdgcn_mfma_f32_16x16x32_bf16(al[mt][kk], bhf, acc[mt], 0, 0, 0);
      }
    }
#pragma unroll
    for (int mt = 0; mt < 4; ++mt)
#pragma unroll
      for (int r = 0; r < 4; ++r)
        P[mt * 16 + kg * 4 + r][s0 + lr] = acc[mt][r] * 0.125f;
  }
  __syncthreads();

  const int r = tid >> 2, q = tid & 3;
  {
    float mx = -1e30f;
#pragma unroll
    for (int s = 0; s < 32; ++s) mx = fmaxf(mx, P[r][q * 32 + s]);
    red1[r][q] = mx;
  }
  __syncthreads();
  const float rowmax = fmaxf(fmaxf(red1[r][0], red1[r][1]),
                             fmaxf(red1[r][2], red1[r][3]));
  {
    float sum = 0.f;
#pragma unroll
    for (int s = 0; s < 32; ++s) {
      const float e = expf(P[r][q * 32 + s] - rowmax);
      P[r][q * 32 + s] = e;
      sum += e;
    }
    red2[r][q] = sum;
  }
  __syncthreads();
  if (q == 0) {
    const float rowsum = red2[r][0] + red2[r][1] + red2[r][2] + red2[r][3];
    mpart[((size_t)bh * NCH_ + ch) * 64 + r] = rowmax;
    lpart[((size_t)bh * NCH_ + ch) * 64 + r] = rowsum;
  }

  const int mg = tid >> 4, dq = (tid & 15) * 4;
  float4 oacc[4];
#pragma unroll
  for (int i = 0; i < 4; ++i) oacc[i] = make_float4(0.f, 0.f, 0.f, 0.f);
  for (int s = 0; s < SC_; ++s) {
    const float4 v = *(const float4*)&Vb[(size_t)(ch * SC_ + s) * 64 + dq];
#pragma unroll
    for (int i = 0; i < 4; ++i) {
      const float p = P[mg * 4 + i][s];
      oacc[i].x += p * v.x; oacc[i].y += p * v.y;
      oacc[i].z += p * v.z; oacc[i].w += p * v.w;
    }
  }
#pragma unroll
  for (int i = 0; i < 4; ++i) {
    const size_t o = (((size_t)bh * NCH_ + ch) * 64 + mg * 4 + i) * 64 + dq;
    *(float4*)&Opart[o] = oacc[i];
  }
}

// =============================================================
// k3v pass 2 + W2: combine chunks -> W1 (LDS), then W2 = Vinv @ W1
// =============================================================
__global__ __launch_bounds__(256) void k3v_combine_w2(
    const float* __restrict__ Opart, const float* __restrict__ mpart,
    const float* __restrict__ lpart, const float* __restrict__ Vinv,
    float* __restrict__ W2)
{
  __shared__ float w[64][33];
  __shared__ float W1s[64][68], Vs[64][68], C_[64][68];
  const int bh = blockIdx.x, tid = threadIdx.x;
  for (int idx = tid; idx < 4096; idx += 256)
    Vs[idx >> 6][idx & 63] = Vinv[(size_t)bh * 4096 + idx];
  if (tid < 64) {
    const int m = tid;
    float M = -1e30f;
    for (int j = 0; j < NCH_; ++j)
      M = fmaxf(M, mpart[((size_t)bh * NCH_ + j) * 64 + m]);
    float denom = 0.f;
    for (int j = 0; j < NCH_; ++j)
      denom += expf(mpart[((size_t)bh * NCH_ + j) * 64 + m] - M) *
               lpart[((size_t)bh * NCH_ + j) * 64 + m];
    const float inv = 1.f / denom;
    for (int j = 0; j < NCH_; ++j)
      w[m][j] = expf(mpart[((size_t)bh * NCH_ + j) * 64 + m] - M) * inv;
  }
  __syncthreads();
  const int mg = tid >> 4, dq = (tid & 15) * 4;
#pragma unroll
  for (int i = 0; i < 4; ++i) {
    const int m = mg * 4 + i;
    float4 acc = make_float4(0.f, 0.f, 0.f, 0.f);
    for (int j = 0; j < NCH_; ++j) {
      const float ww = w[m][j];
      const float4 o = *(const float4*)&Opart[(((size_t)bh * NCH_ + j) * 64 + m) * 64 + dq];
      acc.x += ww * o.x; acc.y += ww * o.y; acc.z += ww * o.z; acc.w += ww * o.w;
    }
    *(float4*)&W1s[m][dq] = acc;
  }
  __syncthreads();
  mm64(C_, Vs, W1s, tid);
  __syncthreads();
  for (int idx = tid; idx < 4096; idx += 256)
    W2[(size_t)bh * 4096 + idx] = C_[idx >> 6][idx & 63];
}

// =============================================================
// FUSED: X = softmax(Q @ Kl^T / 8) @ W2  +  depthwise conv(V),
// written directly as split-bf16 (input of the out-GEMM).
// One block per (bh, 256-row chunk). Phase A: thread-per-row attention
// (o kept in regs, parked in LDS overlay). Phase B: (rowgroup, d) threads,
// register sliding-window conv reading V straight from global (once).
// =============================================================
__global__ __launch_bounds__(256) void attn_conv_fused(
    const float* __restrict__ Q, const float* __restrict__ Kl,
    const float* __restrict__ W2, const float* __restrict__ V,
    const float* __restrict__ cw,
    u16* __restrict__ Xch, u16* __restrict__ Xcl)
{
  __shared__ float smem[256 * 68];       // phase A: Kls[0..4095], W2s[4096..8191]
  __shared__ float cws[33];              // phase B: o_lds[256][68] overlay
  float* Kls = smem;
  float* W2s = smem + 4096;

  const int blk = blockIdx.x;
  const int bh = blk >> 4, chunk = blk & 15;
  const int tid = threadIdx.x;
  const int b = bh / H_, h = bh % H_;
  const int s0 = chunk * 256;

  if (tid < 33) cws[tid] = cw[h * 33 + tid];
  for (int idx = tid; idx < 4096; idx += 256) {
    Kls[idx] = Kl[(size_t)bh * 4096 + idx];
    W2s[idx] = W2[(size_t)bh * 4096 + idx];
  }
  __syncthreads();

  // ---- phase A: landmark attention, one row per thread ----
  {
    const int s = s0 + tid;
    const float* qp = Q + ((size_t)bh * S_ + s) * 64;
    float4 q4[16];
#pragma unroll
    for (int k = 0; k < 16; ++k) q4[k] = *(const float4*)&qp[k * 4];
    float p[64];
#pragma unroll
    for (int m = 0; m < 64; ++m) {
      float dot = 0.f;
#pragma unroll
      for (int k = 0; k < 16; ++k) {
        const float4 kv = *(const float4*)&Kls[m * 64 + k * 4];
        dot += q4[k].x * kv.x + q4[k].y * kv.y + q4[k].z * kv.z + q4[k].w * kv.w;
      }
      p[m] = dot * 0.125f;
    }
    float mx = -1e30f;
#pragma unroll
    for (int m = 0; m < 64; ++m) mx = fmaxf(mx, p[m]);
    float sum = 0.f;
#pragma unroll
    for (int m = 0; m < 64; ++m) { p[m] = expf(p[m] - mx); sum += p[m]; }
    const float inv = 1.f / sum;
    float4 o4[16];
#pragma unroll
    for (int k = 0; k < 16; ++k) o4[k] = make_float4(0.f, 0.f, 0.f, 0.f);
#pragma unroll
    for (int m = 0; m < 64; ++m) {
      const float pm = p[m];
#pragma unroll
      for (int k = 0; k < 16; ++k) {
        const float4 wv = *(const float4*)&W2s[m * 64 + k * 4];
        o4[k].x += pm * wv.x; o4[k].y += pm * wv.y;
        o4[k].z += pm * wv.z; o4[k].w += pm * wv.w;
      }
    }
    __syncthreads();              // Kls/W2s dead -> safe to overlay
#pragma unroll
    for (int k = 0; k < 16; ++k) {
      o4[k].x *= inv; o4[k].y *= inv; o4[k].z *= inv; o4[k].w *= inv;
      *(float4*)&smem[tid * 68 + k * 4] = o4[k];
    }
  }
  __syncthreads();

  // ---- phase B: depthwise conv (sliding window) + combine + split write ----
  const int d = tid & 63, rg = tid >> 6;        // 4 groups x 64 rows
  const int rbase = s0 + rg * 64;               // absolute first row
  const float* Vd = V + (size_t)bh * S_ * 64 + d;

  float v[40];
#pragma unroll
  for (int j = 0; j < 40; ++j) {
    const int sv = rbase - 16 + j;
    v[j] = (sv >= 0 && sv < S_) ? Vd[(size_t)sv * 64] : 0.f;
  }

#pragma unroll
  for (int c = 0; c < 8; ++c) {                 // 8 chunks of 8 rows
#pragma unroll
    for (int rr = 0; rr < 8; ++rr) {
      float acc = 0.f;
#pragma unroll
      for (int t = 0; t < 33; ++t) acc += v[rr + t] * cws[t];
      const int row = rg * 64 + c * 8 + rr;     // row within chunk (0..255)
      const float o = smem[row * 68 + d] + acc;
      const size_t idx = ((size_t)(b * S_ + s0 + row)) * HID_ + h * 64 + d;
      const u16 hh = f2bf(o);
      Xch[idx] = hh;
      Xcl[idx] = f2bf(o - bf2f(hh));
    }
    if (c < 7) {
      // shift window by 8, load 8 new rows
#pragma unroll
      for (int j = 0; j < 32; ++j) v[j] = v[j + 8];
#pragma unroll
      for (int j = 0; j < 8; ++j) {
        const int sv = rbase + 24 + c * 8 + j;
        v[32 + j] = (sv >= 0 && sv < S_) ? Vd[(size_t)sv * 64] : 0.f;
      }
    }
  }
}

// =============================================================
extern "C" void kernel_launch(void* const* d_in, const int* in_sizes, int n_in,
                              void* d_out, int out_size, void* d_ws, size_t ws_size,
                              hipStream_t stream)
{
  (void)in_sizes; (void)n_in; (void)out_size; (void)ws_size;
  const float* x      = (const float*)d_in[0];
  const float* qkv_w  = (const float*)d_in[1];
  const float* qkv_b  = (const float*)d_in[2];
  const float* conv_w = (const float*)d_in[3];
  const float* out_w  = (const float*)d_in[4];
  const float* out_b  = (const float*)d_in[5];
  float* out = (float*)d_out;

  // fp32 region
  float* ws   = (float*)d_ws;
  float* Q    = ws;                       // [BH,S,D] 6291456
  float* K    = Q + 6291456;
  float* V    = K + 6291456;
  float* Ql   = V + 6291456;              // 98304 each below
  float* Kl   = Ql + 98304;
  float* K2   = Kl + 98304;
  float* Vinv = K2 + 98304;
  float* W1   = Vinv + 98304;
  float* W2   = W1 + 98304;
  float* colmax = W2 + 98304;
  float* rowmax = colmax + 32;
  // bf16 (u16) region
  u16* ub  = (u16*)(rowmax + 32);
  u16* Xh  = ub;                          // 6291456 u16
  u16* Xl  = Xh + 6291456;
  u16* Wqh = Xl + 6291456;                // 1769472
  u16* Wql = Wqh + 1769472;
  u16* Woh = Wql + 1769472;               // 589824
  u16* Wol = Woh + 589824;
  // aliases (all ordered-safe on the single stream):
  u16* Xch = Xh;                          // Xh/Xl dead after QKV GEMM
  u16* Xcl = Xl;
  float* Opart = (float*)Xh;              // consumed by combine before Xch write
  float* mpart = (float*)Xl;
  float* lpart = mpart + BH_ * NCH_ * 64;

  split_pair<<<786432 / 256, 256, 0, stream>>>(x, Xh, Xl, 786432);
  split_pair<<<221184 / 256, 256, 0, stream>>>(qkv_w, Wqh, Wql, 221184);
  split_pair<<<73728 / 256, 256, 0, stream>>>(out_w, Woh, Wol, 73728);

  gemm3_mfma<0><<<dim3(18, 64), 256, 0, stream>>>(Xh, Xl, Wqh, Wql, qkv_b,
                                                  Q, K, V, Ql, Kl);

  kernel2_softmax<<<BH_, 256, 0, stream>>>(Ql, Kl, K2, colmax, rowmax);
  newton_inv<<<BH_, 256, 0, stream>>>(K2, colmax, rowmax, Vinv);

  k3v_pass1<<<dim3(NCH_, BH_), 256, 0, stream>>>(Ql, K, V, Opart, mpart, lpart);
  k3v_combine_w2<<<BH_, 256, 0, stream>>>(Opart, mpart, lpart, Vinv, W2);

  attn_conv_fused<<<BH_ * 16, 256, 0, stream>>>(Q, Kl, W2, V, conv_w, Xch, Xcl);

  gemm3_mfma<1><<<dim3(6, 64), 256, 0, stream>>>(Xch, Xcl, Woh, Wol, out_b,
                                                 out, nullptr, nullptr, nullptr, nullptr);
}

// Round 7
// 302.466 us; speedup vs baseline: 3.1922x; 1.1872x over previous
//
#include <hip/hip_runtime.h>
#include <math.h>

#define B_   2
#define S_   4096
#define HID_ 768
#define H_   12
#define D_   64
#define M_   64
#define CK_  33
#define BH_  (B_*H_)   // 24
#define KD_  768
#define NCH_ 32        // k3v S-chunks
#define SC_  128       // keys per chunk

typedef float  f32x4  __attribute__((ext_vector_type(4)));
typedef _Float16 f16x8 __attribute__((ext_vector_type(8)));
typedef unsigned short u16;

__device__ __forceinline__ u16 f2h_bits(float f) {
  union { _Float16 h; u16 u; } c; c.h = (_Float16)f; return c.u;
}
__device__ __forceinline__ float h2f(u16 b) {
  union { _Float16 h; u16 u; } c; c.u = b; return (float)c.h;
}
// two float4 -> f16x8 hi + f16x8 lo residual (a == hi + lo to ~2^-22)
__device__ __forceinline__ void cvt8_hl(const float4 a, const float4 b,
                                        f16x8* hi, f16x8* lo) {
  const float v[8] = {a.x, a.y, a.z, a.w, b.x, b.y, b.z, b.w};
  f16x8 H, L;
#pragma unroll
  for (int e = 0; e < 8; ++e) {
    const _Float16 hh = (_Float16)v[e];
    H[e] = hh;
    L[e] = (_Float16)(v[e] - (float)hh);
  }
  *hi = H; *lo = L;
}
// two float4 -> f16x8 hi only
__device__ __forceinline__ void cvt8_h(const float4 a, const float4 b, f16x8* hi) {
  const float v[8] = {a.x, a.y, a.z, a.w, b.x, b.y, b.z, b.w};
  f16x8 H;
#pragma unroll
  for (int e = 0; e < 8; ++e) H[e] = (_Float16)v[e];
  *hi = H;
}

__device__ __forceinline__ void gld16(const void* g, void* l) {
  __builtin_amdgcn_global_load_lds(
      (const __attribute__((address_space(1))) void*)g,
      (__attribute__((address_space(3))) void*)l, 16, 0, 0);
}

// =============================================================
// Fused split: x -> (Xh, Xl) fp16 hi/lo; qkv_w -> Wqh (hi only);
// out_w -> Woh (hi only). 8 elems per thread, flat segmented index.
// =============================================================
#define N8X  786432
#define N8WQ 221184
#define N8WO 73728
__global__ __launch_bounds__(256) void split3(
    const float* __restrict__ x, const float* __restrict__ qkv_w,
    const float* __restrict__ out_w,
    u16* __restrict__ Xh, u16* __restrict__ Xl,
    u16* __restrict__ Wqh, u16* __restrict__ Woh)
{
  const int i = blockIdx.x * 256 + threadIdx.x;
  if (i < N8X) {
    const float4 a = ((const float4*)x)[2 * i], b = ((const float4*)x)[2 * i + 1];
    const float v[8] = {a.x, a.y, a.z, a.w, b.x, b.y, b.z, b.w};
    union { u16 u[8]; uint4 q; } hv, lv;
#pragma unroll
    for (int e = 0; e < 8; ++e) {
      const u16 hh = f2h_bits(v[e]);
      hv.u[e] = hh;
      lv.u[e] = f2h_bits(v[e] - h2f(hh));
    }
    ((uint4*)Xh)[i] = hv.q;
    ((uint4*)Xl)[i] = lv.q;
  } else if (i < N8X + N8WQ) {
    const int j = i - N8X;
    const float4 a = ((const float4*)qkv_w)[2 * j], b = ((const float4*)qkv_w)[2 * j + 1];
    const float v[8] = {a.x, a.y, a.z, a.w, b.x, b.y, b.z, b.w};
    union { u16 u[8]; uint4 q; } hv;
#pragma unroll
    for (int e = 0; e < 8; ++e) hv.u[e] = f2h_bits(v[e]);
    ((uint4*)Wqh)[j] = hv.q;
  } else if (i < N8X + N8WQ + N8WO) {
    const int j = i - N8X - N8WQ;
    const float4 a = ((const float4*)out_w)[2 * j], b = ((const float4*)out_w)[2 * j + 1];
    const float v[8] = {a.x, a.y, a.z, a.w, b.x, b.y, b.z, b.w};
    union { u16 u[8]; uint4 q; } hv;
#pragma unroll
    for (int e = 0; e < 8; ++e) hv.u[e] = f2h_bits(v[e]);
    ((uint4*)Woh)[j] = hv.q;
  }
}

// =============================================================
// Split-fp16 2-product MFMA GEMM: C = A @ W^T (+bias)
//   C = ah.bh + al.bh  (A exact as fp16 hi+lo; W rounded to fp16)
// 128x128 tile, BK=32, 4 waves, 3 staged tensors (Ah, Al, Bh),
// 48 KB dbuf LDS -> 3 blocks/CU. XOR-swizzle + XCD block swizzle.
// MODE 0 fuses landmark segment means into the epilogue.
// =============================================================
template<int MODE>
__global__ __launch_bounds__(256) void gemm2_mfma(
    const u16* __restrict__ Ahg, const u16* __restrict__ Alg,
    const u16* __restrict__ Bhg,
    const float* __restrict__ bias,
    float* __restrict__ o0, float* __restrict__ o1, float* __restrict__ o2,
    float* __restrict__ Ql, float* __restrict__ Kl)
{
  __shared__ __align__(16) u16 lds[2][3][4096];   // [buf][Ah,Al,Bh][128*32]

  constexpr int NBX = (MODE == 0) ? 18 : 6;
  constexpr int CPX = (NBX * 64) / 8;
  constexpr int NT  = KD_ / 32;

  const int tid = threadIdx.x;
  const int lin = blockIdx.y * NBX + blockIdx.x;
  const int swb = (lin & 7) * CPX + (lin >> 3);    // XCD-contiguous chunks
  const int m0 = (swb / NBX) * 128;
  const int n0 = (swb % NBX) * 128;

  const int wave = tid >> 6, lane = tid & 63;
  const int wm = wave >> 1, wn = wave & 1;
  const int lr = lane & 15, kg = lane >> 4;

  // staging: phys row = tid>>2, phys q = tid&3; source holds logical q^swz
  const int srow = tid >> 2;
  const int swz_s = (tid >> 3) & 3;                // (row>>1)&3
  const int sk = ((tid & 3) ^ swz_s) * 8;

  const u16* pAh = Ahg + (size_t)(m0 + srow) * KD_ + sk;
  const u16* pAl = Alg + (size_t)(m0 + srow) * KD_ + sk;
  const u16* pBh = Bhg + (size_t)(n0 + srow) * KD_ + sk;

  f32x4 acc[4][4];
#pragma unroll
  for (int i = 0; i < 4; ++i)
#pragma unroll
    for (int j = 0; j < 4; ++j) acc[i][j] = (f32x4){0.f, 0.f, 0.f, 0.f};

  // fragment read: logical (row, kg) lives at phys q = kg ^ ((row>>1)&3)
  const int rsw = (lr >> 1) & 3;
  const int kq = (kg ^ rsw) * 8;
  const int abase = (wm * 64 + lr) * 32 + kq;
  const int bbase = (wn * 64 + lr) * 32 + kq;

#define STAGE_(buf, kt) do {                                        \
    const size_t go_ = (size_t)(kt) * 32;                           \
    u16* L_ = &lds[buf][0][0];                                      \
    gld16(pAh + go_,            L_ + tid * 8);                      \
    gld16(pAh + go_ + 64 * KD_, L_ + 2048 + tid * 8);               \
    gld16(pAl + go_,            L_ + 4096 + tid * 8);               \
    gld16(pAl + go_ + 64 * KD_, L_ + 6144 + tid * 8);               \
    gld16(pBh + go_,            L_ + 8192 + tid * 8);               \
    gld16(pBh + go_ + 64 * KD_, L_ + 10240 + tid * 8);              \
  } while (0)

  STAGE_(0, 0);
  __syncthreads();                 // drains vmcnt(0): buf0 ready

  int cur = 0;
  for (int kt = 0; kt < NT; ++kt) {
    if (kt + 1 < NT) STAGE_(cur ^ 1, kt + 1);   // prefetch next tile

    const u16* LAh = &lds[cur][0][0];
    const u16* LAl = &lds[cur][1][0];
    const u16* LBh = &lds[cur][2][0];
    f16x8 ah[4], al[4], bh[4];
#pragma unroll
    for (int f = 0; f < 4; ++f) {
      ah[f] = *(const f16x8*)&LAh[abase + f * 512];
      al[f] = *(const f16x8*)&LAl[abase + f * 512];
      bh[f] = *(const f16x8*)&LBh[bbase + f * 512];
    }
#pragma unroll
    for (int i = 0; i < 4; ++i)
#pragma unroll
      for (int j = 0; j < 4; ++j) {
        acc[i][j] = __builtin_amdgcn_mfma_f32_16x16x32_f16(ah[i], bh[j], acc[i][j], 0, 0, 0);
        acc[i][j] = __builtin_amdgcn_mfma_f32_16x16x32_f16(al[i], bh[j], acc[i][j], 0, 0, 0);
      }

    __syncthreads();               // drains vmcnt(0): next buf ready
    cur ^= 1;
  }
#undef STAGE_

  // ---- epilogue: C write (+ fused landmarks for MODE 0, parts 0/1) ----
#pragma unroll
  for (int i = 0; i < 4; ++i) {
    const int mbase = m0 + wm * 64 + i * 16 + kg * 4;
#pragma unroll
    for (int j = 0; j < 4; ++j) {
      const int ncol = n0 + wn * 64 + j * 16 + lr;
      const float bv = bias[ncol];
      if (MODE == 0) {
        const int part = (ncol >= 1536) ? 2 : (ncol >= 768 ? 1 : 0);
        const int within = ncol - part * 768;
        const int h0 = within >> 6, d = within & 63;
        float* base = (part == 0) ? o0 : ((part == 1) ? o1 : o2);
#pragma unroll
        for (int r = 0; r < 4; ++r) {
          const int row = mbase + r;
          const int b = row >> 12, s = row & (S_ - 1);
          base[(((size_t)(b * H_ + h0) * S_ + s) << 6) + d] = acc[i][j][r] + bv;
        }
      } else {
#pragma unroll
        for (int r = 0; r < 4; ++r) {
          const int row = mbase + r;
          o0[(size_t)row * HID_ + ncol] = acc[i][j][r] + bv;
        }
      }
    }
  }

  if (MODE == 0) {
    // landmark means: this wave's 64 rows form one full segment of one (b,h)
    const int part = n0 / 768;
    if (part < 2) {
      const int within0 = n0 - part * 768;
      const int h = (within0 >> 6) + wn;
      const int rowseg = m0 + wm * 64;
      const int b = rowseg >> 12;
      const int seg = (rowseg & (S_ - 1)) >> 6;
      const int bh = b * H_ + h;
      float* dst = (part == 0) ? Ql : Kl;
#pragma unroll
      for (int j = 0; j < 4; ++j) {
        float sj = 0.f;
#pragma unroll
        for (int i = 0; i < 4; ++i)
#pragma unroll
          for (int r = 0; r < 4; ++r) sj += acc[i][j][r];
        sj += __shfl_xor(sj, 16);
        sj += __shfl_xor(sj, 32);
        if (kg == 0) {
          const int d = j * 16 + lr;
          const int ncol = n0 + wn * 64 + j * 16 + lr;
          dst[((size_t)bh * M_ + seg) * 64 + d] = sj * (1.f / 64.f) + bias[ncol];
        }
      }
    }
  }
}

// =============================================================
// kernel_2 softmax + per-(b,h) max col/row sums
// =============================================================
__global__ __launch_bounds__(256) void kernel2_softmax(
    const float* __restrict__ Ql, const float* __restrict__ Kl,
    float* __restrict__ K2, float* __restrict__ colmax, float* __restrict__ rowmax)
{
  __shared__ float Qs[64][68], Ks[64][68], S2[64][68];
  __shared__ float red1[64], red2[64];
  const int bh = blockIdx.x, tid = threadIdx.x;
  for (int idx = tid; idx < 4096; idx += 256) {
    const int r = idx >> 6, c = idx & 63;
    Qs[r][c] = Ql[(size_t)bh * 4096 + idx];
    Ks[r][c] = Kl[(size_t)bh * 4096 + idx];
  }
  __syncthreads();
  for (int idx = tid; idx < 4096; idx += 256) {
    const int r = idx >> 6, c = idx & 63;
    float dot = 0.f;
#pragma unroll
    for (int k = 0; k < 64; k += 4) {
      const float4 a = *(const float4*)&Qs[r][k];
      const float4 b = *(const float4*)&Ks[c][k];
      dot += a.x * b.x + a.y * b.y + a.z * b.z + a.w * b.w;
    }
    S2[r][c] = dot * 0.125f;
  }
  __syncthreads();
  if (tid < 64) {
    const int r = tid;
    float mx = -1e30f;
    for (int c = 0; c < 64; ++c) mx = fmaxf(mx, S2[r][c]);
    float sum = 0.f;
    for (int c = 0; c < 64; ++c) { const float e = expf(S2[r][c] - mx); S2[r][c] = e; sum += e; }
    const float inv = 1.f / sum;
    for (int c = 0; c < 64; ++c) S2[r][c] *= inv;
  }
  __syncthreads();
  for (int idx = tid; idx < 4096; idx += 256)
    K2[(size_t)bh * 4096 + idx] = S2[idx >> 6][idx & 63];
  if (tid < 64) {
    float cs = 0.f, rs = 0.f;
    for (int m = 0; m < 64; ++m) { cs += S2[m][tid]; rs += S2[tid][m]; }
    red1[tid] = cs; red2[tid] = rs;
  }
  __syncthreads();
  if (tid == 0) {
    float mc = 0.f, mr = 0.f;
    for (int i = 0; i < 64; ++i) { mc = fmaxf(mc, red1[i]); mr = fmaxf(mr, red2[i]); }
    colmax[bh] = mc; rowmax[bh] = mr;
  }
}

// 64x64x64 matmul in LDS, 256 threads (4x4 per thread)
__device__ inline void mm64(float (*C)[68], float (*A)[68], float (*B)[68], int tid)
{
  const int ry = tid >> 4, cx = tid & 15;
  const int r0 = ry * 4, c0 = cx * 4;
  float acc[4][4];
#pragma unroll
  for (int i = 0; i < 4; ++i)
#pragma unroll
    for (int j = 0; j < 4; ++j) acc[i][j] = 0.f;
  for (int k = 0; k < 64; k += 4) {
    float4 a[4], b[4];
#pragma unroll
    for (int i = 0; i < 4; ++i) a[i] = *(const float4*)&A[r0 + i][k];
#pragma unroll
    for (int j = 0; j < 4; ++j) b[j] = *(const float4*)&B[k + j][c0];
    const float bb[4][4] = {{b[0].x, b[0].y, b[0].z, b[0].w},
                            {b[1].x, b[1].y, b[1].z, b[1].w},
                            {b[2].x, b[2].y, b[2].z, b[2].w},
                            {b[3].x, b[3].y, b[3].z, b[3].w}};
    const float aa[4][4] = {{a[0].x, a[0].y, a[0].z, a[0].w},
                            {a[1].x, a[1].y, a[1].z, a[1].w},
                            {a[2].x, a[2].y, a[2].z, a[2].w},
                            {a[3].x, a[3].y, a[3].z, a[3].w}};
#pragma unroll
    for (int i = 0; i < 4; ++i)
#pragma unroll
      for (int j = 0; j < 4; ++j)
#pragma unroll
        for (int kk = 0; kk < 4; ++kk) acc[i][j] += aa[i][kk] * bb[kk][j];
  }
#pragma unroll
  for (int i = 0; i < 4; ++i)
    *(float4*)&C[r0 + i][c0] = make_float4(acc[i][0], acc[i][1], acc[i][2], acc[i][3]);
}

// 64x64x64 matmul in LDS, 512 threads (2x4 per thread)
__device__ inline void mm64w(float (*C)[68], float (*A)[68], float (*B)[68], int tid)
{
  const int r0 = (tid >> 4) * 2;     // 0..62
  const int c0 = (tid & 15) * 4;
  float acc[2][4];
#pragma unroll
  for (int i = 0; i < 2; ++i)
#pragma unroll
    for (int j = 0; j < 4; ++j) acc[i][j] = 0.f;
  for (int k = 0; k < 64; k += 4) {
    float4 a[2], b[4];
#pragma unroll
    for (int i = 0; i < 2; ++i) a[i] = *(const float4*)&A[r0 + i][k];
#pragma unroll
    for (int j = 0; j < 4; ++j) b[j] = *(const float4*)&B[k + j][c0];
    const float bb[4][4] = {{b[0].x, b[0].y, b[0].z, b[0].w},
                            {b[1].x, b[1].y, b[1].z, b[1].w},
                            {b[2].x, b[2].y, b[2].z, b[2].w},
                            {b[3].x, b[3].y, b[3].z, b[3].w}};
    const float aa[2][4] = {{a[0].x, a[0].y, a[0].z, a[0].w},
                            {a[1].x, a[1].y, a[1].z, a[1].w}};
#pragma unroll
    for (int i = 0; i < 2; ++i)
#pragma unroll
      for (int j = 0; j < 4; ++j)
#pragma unroll
        for (int kk = 0; kk < 4; ++kk) acc[i][j] += aa[i][kk] * bb[kk][j];
  }
#pragma unroll
  for (int i = 0; i < 2; ++i)
    *(float4*)&C[r0 + i][c0] = make_float4(acc[i][0], acc[i][1], acc[i][2], acc[i][3]);
}

// =============================================================
// Newton-Schulz pseudo-inverse (6 iters, global scale), 512 threads
// =============================================================
__global__ __launch_bounds__(512) void newton_inv(
    const float* __restrict__ K2, const float* __restrict__ colmax,
    const float* __restrict__ rowmax, float* __restrict__ Vinv)
{
  __shared__ float A_[64][68], V_[64][68], KV_[64][68], T_[64][68], U_[64][68];
  __shared__ float scale_s;
  const int bh = blockIdx.x, tid = threadIdx.x;
  if (tid == 0) {
    float mc = 0.f, mr = 0.f;
    for (int i = 0; i < BH_; ++i) { mc = fmaxf(mc, colmax[i]); mr = fmaxf(mr, rowmax[i]); }
    scale_s = 1.f / (mc * mr);
  }
  for (int idx = tid; idx < 4096; idx += 512)
    A_[idx >> 6][idx & 63] = K2[(size_t)bh * 4096 + idx];
  __syncthreads();
  const float scale = scale_s;
  for (int idx = tid; idx < 4096; idx += 512) {
    const int r = idx >> 6, c = idx & 63;
    V_[r][c] = scale * A_[c][r];
  }
  __syncthreads();
  for (int it = 0; it < 6; ++it) {
    mm64w(KV_, A_, V_, tid); __syncthreads();
    for (int idx = tid; idx < 4096; idx += 512) {
      const int r = idx >> 6, c = idx & 63;
      T_[r][c] = (r == c ? 7.f : 0.f) - KV_[r][c];
    }
    __syncthreads();
    mm64w(U_, KV_, T_, tid); __syncthreads();
    for (int idx = tid; idx < 4096; idx += 512) {
      const int r = idx >> 6, c = idx & 63;
      T_[r][c] = (r == c ? 15.f : 0.f) - U_[r][c];
    }
    __syncthreads();
    mm64w(U_, KV_, T_, tid); __syncthreads();
    for (int idx = tid; idx < 4096; idx += 512) {
      const int r = idx >> 6, c = idx & 63;
      T_[r][c] = (r == c ? 13.f : 0.f) - U_[r][c];
    }
    __syncthreads();
    mm64w(U_, V_, T_, tid); __syncthreads();
    for (int idx = tid; idx < 4096; idx += 512) {
      const int r = idx >> 6, c = idx & 63;
      V_[r][c] = 0.25f * U_[r][c];
    }
    __syncthreads();
  }
  for (int idx = tid; idx < 4096; idx += 512)
    Vinv[(size_t)bh * 4096 + idx] = V_[idx >> 6][idx & 63];
}

// =============================================================
// k3v pass 1: S = Ql @ K_chunk^T / 8 (fp16 2-product MFMA),
// partial softmax + O_j = exp(S-m_j) @ V_chunk (fp32)
// =============================================================
__global__ __launch_bounds__(256) void k3v_pass1(
    const float* __restrict__ Ql, const float* __restrict__ K,
    const float* __restrict__ V, float* __restrict__ Opart,
    float* __restrict__ mpart, float* __restrict__ lpart)
{
  __shared__ float P[64][129];
  __shared__ float red1[64][4], red2[64][4];

  const int ch = blockIdx.x;     // 0..31
  const int bh = blockIdx.y;     // 0..23
  const int tid = threadIdx.x;
  const int wave = tid >> 6, lane = tid & 63;
  const int lr = lane & 15, kg = lane >> 4;

  const float* Qlb = Ql + (size_t)bh * 4096;
  const float* Kb  = K + (size_t)bh * S_ * 64;
  const float* Vb  = V + (size_t)bh * S_ * 64;

  f16x8 ah[4][2], al[4][2];
#pragma unroll
  for (int mt = 0; mt < 4; ++mt)
#pragma unroll
    for (int kk = 0; kk < 2; ++kk) {
      const float* qr = Qlb + (size_t)(mt * 16 + lr) * 64 + kk * 32 + kg * 8;
      cvt8_hl(*(const float4*)qr, *(const float4*)(qr + 4), &ah[mt][kk], &al[mt][kk]);
    }

#pragma unroll
  for (int t = 0; t < 2; ++t) {
    const int s0 = (wave * 2 + t) * 16;
    const int srow = ch * SC_ + s0 + lr;
    f32x4 acc[4];
#pragma unroll
    for (int mt = 0; mt < 4; ++mt) acc[mt] = (f32x4){0.f, 0.f, 0.f, 0.f};
#pragma unroll
    for (int kk = 0; kk < 2; ++kk) {
      const float* kr = Kb + (size_t)srow * 64 + kk * 32 + kg * 8;
      f16x8 bhf;
      cvt8_h(*(const float4*)kr, *(const float4*)(kr + 4), &bhf);
#pragma unroll
      for (int mt = 0; mt < 4; ++mt) {
        acc[mt] = __builtin_amdgcn_mfma_f32_16x16x32_f16(ah[mt][kk], bhf, acc[mt], 0, 0, 0);
        acc[mt] = __builtin_amdgcn_mfma_f32_16x16x32_f16(al[mt][kk], bhf, acc[mt], 0, 0, 0);
      }
    }
#pragma unroll
    for (int mt = 0; mt < 4; ++mt)
#pragma unroll
      for (int r = 0; r < 4; ++r)
        P[mt * 16 + kg * 4 + r][s0 + lr] = acc[mt][r] * 0.125f;
  }
  __syncthreads();

  const int r = tid >> 2, q = tid & 3;
  {
    float mx = -1e30f;
#pragma unroll
    for (int s = 0; s < 32; ++s) mx = fmaxf(mx, P[r][q * 32 + s]);
    red1[r][q] = mx;
  }
  __syncthreads();
  const float rowmax = fmaxf(fmaxf(red1[r][0], red1[r][1]),
                             fmaxf(red1[r][2], red1[r][3]));
  {
    float sum = 0.f;
#pragma unroll
    for (int s = 0; s < 32; ++s) {
      const float e = expf(P[r][q * 32 + s] - rowmax);
      P[r][q * 32 + s] = e;
      sum += e;
    }
    red2[r][q] = sum;
  }
  __syncthreads();
  if (q == 0) {
    const float rowsum = red2[r][0] + red2[r][1] + red2[r][2] + red2[r][3];
    mpart[((size_t)bh * NCH_ + ch) * 64 + r] = rowmax;
    lpart[((size_t)bh * NCH_ + ch) * 64 + r] = rowsum;
  }

  const int mg = tid >> 4, dq = (tid & 15) * 4;
  float4 oacc[4];
#pragma unroll
  for (int i = 0; i < 4; ++i) oacc[i] = make_float4(0.f, 0.f, 0.f, 0.f);
  for (int s = 0; s < SC_; ++s) {
    const float4 v = *(const float4*)&Vb[(size_t)(ch * SC_ + s) * 64 + dq];
#pragma unroll
    for (int i = 0; i < 4; ++i) {
      const float p = P[mg * 4 + i][s];
      oacc[i].x += p * v.x; oacc[i].y += p * v.y;
      oacc[i].z += p * v.z; oacc[i].w += p * v.w;
    }
  }
#pragma unroll
  for (int i = 0; i < 4; ++i) {
    const size_t o = (((size_t)bh * NCH_ + ch) * 64 + mg * 4 + i) * 64 + dq;
    *(float4*)&Opart[o] = oacc[i];
  }
}

// =============================================================
// k3v pass 2 + W2: combine chunks -> W1 (LDS), then W2 = Vinv @ W1
// =============================================================
__global__ __launch_bounds__(256) void k3v_combine_w2(
    const float* __restrict__ Opart, const float* __restrict__ mpart,
    const float* __restrict__ lpart, const float* __restrict__ Vinv,
    float* __restrict__ W2)
{
  __shared__ float w[64][33];
  __shared__ float W1s[64][68], Vs[64][68], C_[64][68];
  const int bh = blockIdx.x, tid = threadIdx.x;
  for (int idx = tid; idx < 4096; idx += 256)
    Vs[idx >> 6][idx & 63] = Vinv[(size_t)bh * 4096 + idx];
  if (tid < 64) {
    const int m = tid;
    float M = -1e30f;
    for (int j = 0; j < NCH_; ++j)
      M = fmaxf(M, mpart[((size_t)bh * NCH_ + j) * 64 + m]);
    float denom = 0.f;
    for (int j = 0; j < NCH_; ++j)
      denom += expf(mpart[((size_t)bh * NCH_ + j) * 64 + m] - M) *
               lpart[((size_t)bh * NCH_ + j) * 64 + m];
    const float inv = 1.f / denom;
    for (int j = 0; j < NCH_; ++j)
      w[m][j] = expf(mpart[((size_t)bh * NCH_ + j) * 64 + m] - M) * inv;
  }
  __syncthreads();
  const int mg = tid >> 4, dq = (tid & 15) * 4;
#pragma unroll
  for (int i = 0; i < 4; ++i) {
    const int m = mg * 4 + i;
    float4 acc = make_float4(0.f, 0.f, 0.f, 0.f);
    for (int j = 0; j < NCH_; ++j) {
      const float ww = w[m][j];
      const float4 o = *(const float4*)&Opart[(((size_t)bh * NCH_ + j) * 64 + m) * 64 + dq];
      acc.x += ww * o.x; acc.y += ww * o.y; acc.z += ww * o.z; acc.w += ww * o.w;
    }
    *(float4*)&W1s[m][dq] = acc;
  }
  __syncthreads();
  mm64(C_, Vs, W1s, tid);
  __syncthreads();
  for (int idx = tid; idx < 4096; idx += 256)
    W2[(size_t)bh * 4096 + idx] = C_[idx >> 6][idx & 63];
}

// =============================================================
// FUSED: X = softmax(Q @ Kl^T / 8) @ W2  +  depthwise conv(V),
// written directly as split-fp16 (input of the out-GEMM).
// =============================================================
__global__ __launch_bounds__(256) void attn_conv_fused(
    const float* __restrict__ Q, const float* __restrict__ Kl,
    const float* __restrict__ W2, const float* __restrict__ V,
    const float* __restrict__ cw,
    u16* __restrict__ Xch, u16* __restrict__ Xcl)
{
  __shared__ float smem[256 * 68];       // phase A: Kls[0..4095], W2s[4096..8191]
  __shared__ float cws[33];              // phase B: o_lds[256][68] overlay
  float* Kls = smem;
  float* W2s = smem + 4096;

  const int blk = blockIdx.x;
  const int bh = blk >> 4, chunk = blk & 15;
  const int tid = threadIdx.x;
  const int b = bh / H_, h = bh % H_;
  const int s0 = chunk * 256;

  if (tid < 33) cws[tid] = cw[h * 33 + tid];
  for (int idx = tid; idx < 4096; idx += 256) {
    Kls[idx] = Kl[(size_t)bh * 4096 + idx];
    W2s[idx] = W2[(size_t)bh * 4096 + idx];
  }
  __syncthreads();

  // ---- phase A: landmark attention, one row per thread ----
  {
    const int s = s0 + tid;
    const float* qp = Q + ((size_t)bh * S_ + s) * 64;
    float4 q4[16];
#pragma unroll
    for (int k = 0; k < 16; ++k) q4[k] = *(const float4*)&qp[k * 4];
    float p[64];
#pragma unroll
    for (int m = 0; m < 64; ++m) {
      float dot = 0.f;
#pragma unroll
      for (int k = 0; k < 16; ++k) {
        const float4 kv = *(const float4*)&Kls[m * 64 + k * 4];
        dot += q4[k].x * kv.x + q4[k].y * kv.y + q4[k].z * kv.z + q4[k].w * kv.w;
      }
      p[m] = dot * 0.125f;
    }
    float mx = -1e30f;
#pragma unroll
    for (int m = 0; m < 64; ++m) mx = fmaxf(mx, p[m]);
    float sum = 0.f;
#pragma unroll
    for (int m = 0; m < 64; ++m) { p[m] = expf(p[m] - mx); sum += p[m]; }
    const float inv = 1.f / sum;
    float4 o4[16];
#pragma unroll
    for (int k = 0; k < 16; ++k) o4[k] = make_float4(0.f, 0.f, 0.f, 0.f);
#pragma unroll
    for (int m = 0; m < 64; ++m) {
      const float pm = p[m];
#pragma unroll
      for (int k = 0; k < 16; ++k) {
        const float4 wv = *(const float4*)&W2s[m * 64 + k * 4];
        o4[k].x += pm * wv.x; o4[k].y += pm * wv.y;
        o4[k].z += pm * wv.z; o4[k].w += pm * wv.w;
      }
    }
    __syncthreads();              // Kls/W2s dead -> safe to overlay
#pragma unroll
    for (int k = 0; k < 16; ++k) {
      o4[k].x *= inv; o4[k].y *= inv; o4[k].z *= inv; o4[k].w *= inv;
      *(float4*)&smem[tid * 68 + k * 4] = o4[k];
    }
  }
  __syncthreads();

  // ---- phase B: depthwise conv (sliding window) + combine + split write ----
  const int d = tid & 63, rg = tid >> 6;        // 4 groups x 64 rows
  const int rbase = s0 + rg * 64;               // absolute first row
  const float* Vd = V + (size_t)bh * S_ * 64 + d;

  float v[40];
#pragma unroll
  for (int j = 0; j < 40; ++j) {
    const int sv = rbase - 16 + j;
    v[j] = (sv >= 0 && sv < S_) ? Vd[(size_t)sv * 64] : 0.f;
  }

#pragma unroll
  for (int c = 0; c < 8; ++c) {                 // 8 chunks of 8 rows
#pragma unroll
    for (int rr = 0; rr < 8; ++rr) {
      float acc = 0.f;
#pragma unroll
      for (int t = 0; t < 33; ++t) acc += v[rr + t] * cws[t];
      const int row = rg * 64 + c * 8 + rr;     // row within chunk (0..255)
      const float o = smem[row * 68 + d] + acc;
      const size_t idx = ((size_t)(b * S_ + s0 + row)) * HID_ + h * 64 + d;
      const u16 hh = f2h_bits(o);
      Xch[idx] = hh;
      Xcl[idx] = f2h_bits(o - h2f(hh));
    }
    if (c < 7) {
#pragma unroll
      for (int j = 0; j < 32; ++j) v[j] = v[j + 8];
#pragma unroll
      for (int j = 0; j < 8; ++j) {
        const int sv = rbase + 24 + c * 8 + j;
        v[32 + j] = (sv >= 0 && sv < S_) ? Vd[(size_t)sv * 64] : 0.f;
      }
    }
  }
}

// =============================================================
extern "C" void kernel_launch(void* const* d_in, const int* in_sizes, int n_in,
                              void* d_out, int out_size, void* d_ws, size_t ws_size,
                              hipStream_t stream)
{
  (void)in_sizes; (void)n_in; (void)out_size; (void)ws_size;
  const float* x      = (const float*)d_in[0];
  const float* qkv_w  = (const float*)d_in[1];
  const float* qkv_b  = (const float*)d_in[2];
  const float* conv_w = (const float*)d_in[3];
  const float* out_w  = (const float*)d_in[4];
  const float* out_b  = (const float*)d_in[5];
  float* out = (float*)d_out;

  // fp32 region
  float* ws   = (float*)d_ws;
  float* Q    = ws;                       // [BH,S,D] 6291456
  float* K    = Q + 6291456;
  float* V    = K + 6291456;
  float* Ql   = V + 6291456;              // 98304 each below
  float* Kl   = Ql + 98304;
  float* K2   = Kl + 98304;
  float* Vinv = K2 + 98304;
  float* W1   = Vinv + 98304;
  float* W2   = W1 + 98304;
  float* colmax = W2 + 98304;
  float* rowmax = colmax + 32;
  // fp16 (u16) region
  u16* ub  = (u16*)(rowmax + 32);
  u16* Xh  = ub;                          // 6291456 u16
  u16* Xl  = Xh + 6291456;
  u16* Wqh = Xl + 6291456;                // 1769472
  u16* Woh = Wqh + 1769472;               // 589824
  // aliases (stream-ordered safe):
  u16* Xch = Xh;                          // Xh/Xl dead after QKV GEMM
  u16* Xcl = Xl;
  float* Opart = (float*)Xh;              // consumed by combine before Xch write
  float* mpart = (float*)Xl;
  float* lpart = mpart + BH_ * NCH_ * 64;

  split3<<<(N8X + N8WQ + N8WO + 255) / 256, 256, 0, stream>>>(
      x, qkv_w, out_w, Xh, Xl, Wqh, Woh);

  gemm2_mfma<0><<<dim3(18, 64), 256, 0, stream>>>(Xh, Xl, Wqh, qkv_b,
                                                  Q, K, V, Ql, Kl);

  kernel2_softmax<<<BH_, 256, 0, stream>>>(Ql, Kl, K2, colmax, rowmax);
  newton_inv<<<BH_, 512, 0, stream>>>(K2, colmax, rowmax, Vinv);

  k3v_pass1<<<dim3(NCH_, BH_), 256, 0, stream>>>(Ql, K, V, Opart, mpart, lpart);
  k3v_combine_w2<<<BH_, 256, 0, stream>>>(Opart, mpart, lpart, Vinv, W2);

  attn_conv_fused<<<BH_ * 16, 256, 0, stream>>>(Q, Kl, W2, V, conv_w, Xch, Xcl);

  gemm2_mfma<1><<<dim3(6, 64), 256, 0, stream>>>(Xch, Xcl, Woh, out_b,
                                                 out, nullptr, nullptr, nullptr, nullptr);
}

// Round 8
// 268.716 us; speedup vs baseline: 3.5931x; 1.1256x over previous
//
#include <hip/hip_runtime.h>
#include <math.h>

#define B_   2
#define S_   4096
#define HID_ 768
#define H_   12
#define D_   64
#define M_   64
#define CK_  33
#define BH_  (B_*H_)   // 24
#define KD_  768
#define NCH_ 32        // k3v S-chunks
#define SC_  128       // keys per chunk

typedef float  f32x4  __attribute__((ext_vector_type(4)));
typedef _Float16 f16x8 __attribute__((ext_vector_type(8)));
typedef unsigned short u16;

__device__ __forceinline__ u16 f2h_bits(float f) {
  union { _Float16 h; u16 u; } c; c.h = (_Float16)f; return c.u;
}
__device__ __forceinline__ float h2f(u16 b) {
  union { _Float16 h; u16 u; } c; c.u = b; return (float)c.h;
}
// two float4 -> f16x8 hi + f16x8 lo residual
__device__ __forceinline__ void cvt8_hl(const float4 a, const float4 b,
                                        f16x8* hi, f16x8* lo) {
  const float v[8] = {a.x, a.y, a.z, a.w, b.x, b.y, b.z, b.w};
  f16x8 H, L;
#pragma unroll
  for (int e = 0; e < 8; ++e) {
    const _Float16 hh = (_Float16)v[e];
    H[e] = hh;
    L[e] = (_Float16)(v[e] - (float)hh);
  }
  *hi = H; *lo = L;
}

__device__ __forceinline__ void gld16(const void* g, void* l) {
  __builtin_amdgcn_global_load_lds(
      (const __attribute__((address_space(1))) void*)g,
      (__attribute__((address_space(3))) void*)l, 16, 0, 0);
}

// =============================================================
// Downcast: x -> Xh, qkv_w -> Wqh, out_w -> Woh (fp16 hi only)
// =============================================================
#define N8X  786432
#define N8WQ 221184
#define N8WO 73728
__global__ __launch_bounds__(256) void split3(
    const float* __restrict__ x, const float* __restrict__ qkv_w,
    const float* __restrict__ out_w,
    u16* __restrict__ Xh, u16* __restrict__ Wqh, u16* __restrict__ Woh)
{
  const int i = blockIdx.x * 256 + threadIdx.x;
  const float* src; u16* dst; int j;
  if (i < N8X)                 { src = x;     dst = Xh;  j = i; }
  else if (i < N8X + N8WQ)     { src = qkv_w; dst = Wqh; j = i - N8X; }
  else if (i < N8X + N8WQ + N8WO) { src = out_w; dst = Woh; j = i - N8X - N8WQ; }
  else return;
  const float4 a = ((const float4*)src)[2 * j], b = ((const float4*)src)[2 * j + 1];
  const float v[8] = {a.x, a.y, a.z, a.w, b.x, b.y, b.z, b.w};
  union { u16 u[8]; uint4 q; } hv;
#pragma unroll
  for (int e = 0; e < 8; ++e) hv.u[e] = f2h_bits(v[e]);
  ((uint4*)dst)[j] = hv.q;
}

// =============================================================
// fp16 MFMA GEMM: C = A @ W^T (+bias)
// PROD=1: C = ah.bh (A hi only).  PROD=2: C = ah.bh + al.bh.
// 128x128 tile, BK=32, 4 waves, XOR-swizzled LDS, dbuf 2-phase,
// XCD-bijective block swizzle. MODE 0 scatters Q(f32)/K(f16)/V(f32)
// and fuses landmark segment means; MODE 1 writes row-major f32.
// =============================================================
template<int MODE, int PROD>
__global__ __launch_bounds__(256) void gemm_mfma(
    const u16* __restrict__ Ahg, const u16* __restrict__ Alg,
    const u16* __restrict__ Bhg,
    const float* __restrict__ bias,
    float* __restrict__ o0, u16* __restrict__ o1k, float* __restrict__ o2,
    float* __restrict__ Ql, float* __restrict__ Kl)
{
  __shared__ __align__(16) u16 lds[2][PROD + 1][4096];

  constexpr int NBX = (MODE == 0) ? 18 : 6;
  constexpr int CPX = (NBX * 64) / 8;
  constexpr int NT  = KD_ / 32;

  const int tid = threadIdx.x;
  const int lin = blockIdx.y * NBX + blockIdx.x;
  const int swb = (lin & 7) * CPX + (lin >> 3);    // XCD-contiguous chunks
  const int m0 = (swb / NBX) * 128;
  const int n0 = (swb % NBX) * 128;

  const int wave = tid >> 6, lane = tid & 63;
  const int wm = wave >> 1, wn = wave & 1;
  const int lr = lane & 15, kg = lane >> 4;

  // staging: phys row = tid>>2, phys q = tid&3; source holds logical q^swz
  const int srow = tid >> 2;
  const int swz_s = (tid >> 3) & 3;                // (row>>1)&3
  const int sk = ((tid & 3) ^ swz_s) * 8;

  const u16* pAh = Ahg + (size_t)(m0 + srow) * KD_ + sk;
  const u16* pAl = (PROD == 2) ? (Alg + (size_t)(m0 + srow) * KD_ + sk) : nullptr;
  const u16* pBh = Bhg + (size_t)(n0 + srow) * KD_ + sk;

  f32x4 acc[4][4];
#pragma unroll
  for (int i = 0; i < 4; ++i)
#pragma unroll
    for (int j = 0; j < 4; ++j) acc[i][j] = (f32x4){0.f, 0.f, 0.f, 0.f};

  // fragment read: logical (row, kg) lives at phys q = kg ^ ((row>>1)&3)
  const int rsw = (lr >> 1) & 3;
  const int kq = (kg ^ rsw) * 8;
  const int abase = (wm * 64 + lr) * 32 + kq;
  const int bbase = (wn * 64 + lr) * 32 + kq;

#define STAGE_(buf, kt) do {                                          \
    const size_t go_ = (size_t)(kt) * 32;                             \
    u16* L_ = &lds[buf][0][0];                                        \
    gld16(pAh + go_,            L_ + tid * 8);                        \
    gld16(pAh + go_ + 64 * KD_, L_ + 2048 + tid * 8);                 \
    if (PROD == 2) {                                                  \
      gld16(pAl + go_,            L_ + 4096 + tid * 8);               \
      gld16(pAl + go_ + 64 * KD_, L_ + 6144 + tid * 8);               \
    }                                                                 \
    gld16(pBh + go_,            L_ + PROD * 4096 + tid * 8);          \
    gld16(pBh + go_ + 64 * KD_, L_ + PROD * 4096 + 2048 + tid * 8);   \
  } while (0)

  STAGE_(0, 0);
  __syncthreads();                 // drains vmcnt(0): buf0 ready

  int cur = 0;
  for (int kt = 0; kt < NT; ++kt) {
    if (kt + 1 < NT) STAGE_(cur ^ 1, kt + 1);   // prefetch next tile

    const u16* LAh = &lds[cur][0][0];
    const u16* LAl = &lds[cur][1][0];
    const u16* LBh = &lds[cur][PROD][0];
    f16x8 ah[4], al[4], bh[4];
#pragma unroll
    for (int f = 0; f < 4; ++f) {
      ah[f] = *(const f16x8*)&LAh[abase + f * 512];
      if (PROD == 2) al[f] = *(const f16x8*)&LAl[abase + f * 512];
      bh[f] = *(const f16x8*)&LBh[bbase + f * 512];
    }
#pragma unroll
    for (int i = 0; i < 4; ++i)
#pragma unroll
      for (int j = 0; j < 4; ++j) {
        acc[i][j] = __builtin_amdgcn_mfma_f32_16x16x32_f16(ah[i], bh[j], acc[i][j], 0, 0, 0);
        if (PROD == 2)
          acc[i][j] = __builtin_amdgcn_mfma_f32_16x16x32_f16(al[i], bh[j], acc[i][j], 0, 0, 0);
      }

    __syncthreads();               // drains vmcnt(0): next buf ready
    cur ^= 1;
  }
#undef STAGE_

  // ---- epilogue ----
#pragma unroll
  for (int i = 0; i < 4; ++i) {
    const int mbase = m0 + wm * 64 + i * 16 + kg * 4;
#pragma unroll
    for (int j = 0; j < 4; ++j) {
      const int ncol = n0 + wn * 64 + j * 16 + lr;
      const float bv = bias[ncol];
      if (MODE == 0) {
        const int part = (ncol >= 1536) ? 2 : (ncol >= 768 ? 1 : 0);
        const int within = ncol - part * 768;
        const int h0 = within >> 6, d = within & 63;
#pragma unroll
        for (int r = 0; r < 4; ++r) {
          const int row = mbase + r;
          const int b = row >> 12, s = row & (S_ - 1);
          const size_t off = (((size_t)(b * H_ + h0) * S_ + s) << 6) + d;
          const float val = acc[i][j][r] + bv;
          if (part == 0)      o0[off] = val;
          else if (part == 1) o1k[off] = f2h_bits(val);   // K stored fp16
          else                o2[off] = val;
        }
      } else {
#pragma unroll
        for (int r = 0; r < 4; ++r) {
          const int row = mbase + r;
          o0[(size_t)row * HID_ + ncol] = acc[i][j][r] + bv;
        }
      }
    }
  }

  if (MODE == 0) {
    // landmark means: this wave's 64 rows form one full segment of one (b,h)
    const int part = n0 / 768;
    if (part < 2) {
      const int within0 = n0 - part * 768;
      const int h = (within0 >> 6) + wn;
      const int rowseg = m0 + wm * 64;
      const int b = rowseg >> 12;
      const int seg = (rowseg & (S_ - 1)) >> 6;
      const int bh = b * H_ + h;
      float* dst = (part == 0) ? Ql : Kl;
#pragma unroll
      for (int j = 0; j < 4; ++j) {
        float sj = 0.f;
#pragma unroll
        for (int i = 0; i < 4; ++i)
#pragma unroll
          for (int r = 0; r < 4; ++r) sj += acc[i][j][r];
        sj += __shfl_xor(sj, 16);
        sj += __shfl_xor(sj, 32);
        if (kg == 0) {
          const int d = j * 16 + lr;
          const int ncol = n0 + wn * 64 + j * 16 + lr;
          dst[((size_t)bh * M_ + seg) * 64 + d] = sj * (1.f / 64.f) + bias[ncol];
        }
      }
    }
  }
}

// =============================================================
// kernel_2 softmax + per-(b,h) max col/row sums
// =============================================================
__global__ __launch_bounds__(256) void kernel2_softmax(
    const float* __restrict__ Ql, const float* __restrict__ Kl,
    float* __restrict__ K2, float* __restrict__ colmax, float* __restrict__ rowmax)
{
  __shared__ float Qs[64][68], Ks[64][68], S2[64][68];
  __shared__ float red1[64], red2[64];
  const int bh = blockIdx.x, tid = threadIdx.x;
  for (int idx = tid; idx < 4096; idx += 256) {
    const int r = idx >> 6, c = idx & 63;
    Qs[r][c] = Ql[(size_t)bh * 4096 + idx];
    Ks[r][c] = Kl[(size_t)bh * 4096 + idx];
  }
  __syncthreads();
  for (int idx = tid; idx < 4096; idx += 256) {
    const int r = idx >> 6, c = idx & 63;
    float dot = 0.f;
#pragma unroll
    for (int k = 0; k < 64; k += 4) {
      const float4 a = *(const float4*)&Qs[r][k];
      const float4 b = *(const float4*)&Ks[c][k];
      dot += a.x * b.x + a.y * b.y + a.z * b.z + a.w * b.w;
    }
    S2[r][c] = dot * 0.125f;
  }
  __syncthreads();
  if (tid < 64) {
    const int r = tid;
    float mx = -1e30f;
    for (int c = 0; c < 64; ++c) mx = fmaxf(mx, S2[r][c]);
    float sum = 0.f;
    for (int c = 0; c < 64; ++c) { const float e = expf(S2[r][c] - mx); S2[r][c] = e; sum += e; }
    const float inv = 1.f / sum;
    for (int c = 0; c < 64; ++c) S2[r][c] *= inv;
  }
  __syncthreads();
  for (int idx = tid; idx < 4096; idx += 256)
    K2[(size_t)bh * 4096 + idx] = S2[idx >> 6][idx & 63];
  if (tid < 64) {
    float cs = 0.f, rs = 0.f;
    for (int m = 0; m < 64; ++m) { cs += S2[m][tid]; rs += S2[tid][m]; }
    red1[tid] = cs; red2[tid] = rs;
  }
  __syncthreads();
  if (tid == 0) {
    float mc = 0.f, mr = 0.f;
    for (int i = 0; i < 64; ++i) { mc = fmaxf(mc, red1[i]); mr = fmaxf(mr, red2[i]); }
    colmax[bh] = mc; rowmax[bh] = mr;
  }
}

// 64x64x64 matmul in LDS, 512 threads (2x4 per thread)
__device__ inline void mm64w(float (*C)[68], float (*A)[68], float (*B)[68], int tid)
{
  const int r0 = (tid >> 4) * 2;     // 0..62
  const int c0 = (tid & 15) * 4;
  float acc[2][4];
#pragma unroll
  for (int i = 0; i < 2; ++i)
#pragma unroll
    for (int j = 0; j < 4; ++j) acc[i][j] = 0.f;
  for (int k = 0; k < 64; k += 4) {
    float4 a[2], b[4];
#pragma unroll
    for (int i = 0; i < 2; ++i) a[i] = *(const float4*)&A[r0 + i][k];
#pragma unroll
    for (int j = 0; j < 4; ++j) b[j] = *(const float4*)&B[k + j][c0];
    const float bb[4][4] = {{b[0].x, b[0].y, b[0].z, b[0].w},
                            {b[1].x, b[1].y, b[1].z, b[1].w},
                            {b[2].x, b[2].y, b[2].z, b[2].w},
                            {b[3].x, b[3].y, b[3].z, b[3].w}};
    const float aa[2][4] = {{a[0].x, a[0].y, a[0].z, a[0].w},
                            {a[1].x, a[1].y, a[1].z, a[1].w}};
#pragma unroll
    for (int i = 0; i < 2; ++i)
#pragma unroll
      for (int j = 0; j < 4; ++j)
#pragma unroll
        for (int kk = 0; kk < 4; ++kk) acc[i][j] += aa[i][kk] * bb[kk][j];
  }
#pragma unroll
  for (int i = 0; i < 2; ++i)
    *(float4*)&C[r0 + i][c0] = make_float4(acc[i][0], acc[i][1], acc[i][2], acc[i][3]);
}

// =============================================================
// FUSED: Newton-Schulz pinv (6 iters, global scale) + k3v combine
// + W2 = Vinv @ W1.  Vinv never leaves LDS. 512 threads, 24 blocks.
// =============================================================
__global__ __launch_bounds__(512) void newton_combine(
    const float* __restrict__ K2, const float* __restrict__ colmax,
    const float* __restrict__ rowmax,
    const float* __restrict__ Opart, const float* __restrict__ mpart,
    const float* __restrict__ lpart, float* __restrict__ W2)
{
  __shared__ float A_[64][68], V_[64][68], KV_[64][68], T_[64][68], U_[64][68];
  __shared__ float scale_s;
  const int bh = blockIdx.x, tid = threadIdx.x;
  if (tid == 0) {
    float mc = 0.f, mr = 0.f;
    for (int i = 0; i < BH_; ++i) { mc = fmaxf(mc, colmax[i]); mr = fmaxf(mr, rowmax[i]); }
    scale_s = 1.f / (mc * mr);
  }
  for (int idx = tid; idx < 4096; idx += 512)
    A_[idx >> 6][idx & 63] = K2[(size_t)bh * 4096 + idx];
  __syncthreads();
  const float scale = scale_s;
  for (int idx = tid; idx < 4096; idx += 512) {
    const int r = idx >> 6, c = idx & 63;
    V_[r][c] = scale * A_[c][r];
  }
  __syncthreads();
  for (int it = 0; it < 6; ++it) {
    mm64w(KV_, A_, V_, tid); __syncthreads();
    for (int idx = tid; idx < 4096; idx += 512) {
      const int r = idx >> 6, c = idx & 63;
      T_[r][c] = (r == c ? 7.f : 0.f) - KV_[r][c];
    }
    __syncthreads();
    mm64w(U_, KV_, T_, tid); __syncthreads();
    for (int idx = tid; idx < 4096; idx += 512) {
      const int r = idx >> 6, c = idx & 63;
      T_[r][c] = (r == c ? 15.f : 0.f) - U_[r][c];
    }
    __syncthreads();
    mm64w(U_, KV_, T_, tid); __syncthreads();
    for (int idx = tid; idx < 4096; idx += 512) {
      const int r = idx >> 6, c = idx & 63;
      T_[r][c] = (r == c ? 13.f : 0.f) - U_[r][c];
    }
    __syncthreads();
    mm64w(U_, V_, T_, tid); __syncthreads();
    for (int idx = tid; idx < 4096; idx += 512) {
      const int r = idx >> 6, c = idx & 63;
      V_[r][c] = 0.25f * U_[r][c];
    }
    __syncthreads();
  }
  // Vinv in V_. Overlays: W1s on A_, C on KV_, w on T_ (all dead).
  float (*W1s)[68] = A_;
  float (*C_)[68]  = KV_;
  float (*w_)[68]  = T_;          // use [64][<=33] region
  if (tid < 64) {
    const int m = tid;
    float M = -1e30f;
    for (int j = 0; j < NCH_; ++j)
      M = fmaxf(M, mpart[((size_t)bh * NCH_ + j) * 64 + m]);
    float denom = 0.f;
    for (int j = 0; j < NCH_; ++j)
      denom += expf(mpart[((size_t)bh * NCH_ + j) * 64 + m] - M) *
               lpart[((size_t)bh * NCH_ + j) * 64 + m];
    const float inv = 1.f / denom;
    for (int j = 0; j < NCH_; ++j)
      w_[m][j] = expf(mpart[((size_t)bh * NCH_ + j) * 64 + m] - M) * inv;
  }
  __syncthreads();
  const int mgB = tid >> 4, dq = (tid & 15) * 4;   // mgB 0..31
#pragma unroll
  for (int i = 0; i < 2; ++i) {
    const int m = mgB + 32 * i;
    float4 acc = make_float4(0.f, 0.f, 0.f, 0.f);
    for (int j = 0; j < NCH_; ++j) {
      const float ww = w_[m][j];
      const float4 o = *(const float4*)&Opart[(((size_t)bh * NCH_ + j) * 64 + m) * 64 + dq];
      acc.x += ww * o.x; acc.y += ww * o.y; acc.z += ww * o.z; acc.w += ww * o.w;
    }
    *(float4*)&W1s[m][dq] = acc;
  }
  __syncthreads();
  mm64w(C_, V_, W1s, tid);
  __syncthreads();
  for (int idx = tid; idx < 4096; idx += 512)
    W2[(size_t)bh * 4096 + idx] = C_[idx >> 6][idx & 63];
}

// =============================================================
// k3v pass 1: S = Ql @ K_chunk^T / 8 (fp16 MFMA, K pre-stored fp16),
// partial softmax + O_j = exp(S-m_j) @ V_chunk (fp32)
// =============================================================
__global__ __launch_bounds__(256) void k3v_pass1(
    const float* __restrict__ Ql, const u16* __restrict__ Kh,
    const float* __restrict__ V, float* __restrict__ Opart,
    float* __restrict__ mpart, float* __restrict__ lpart)
{
  __shared__ float P[64][129];
  __shared__ float red1[64][4], red2[64][4];

  const int ch = blockIdx.x;     // 0..31
  const int bh = blockIdx.y;     // 0..23
  const int tid = threadIdx.x;
  const int wave = tid >> 6, lane = tid & 63;
  const int lr = lane & 15, kg = lane >> 4;

  const float* Qlb = Ql + (size_t)bh * 4096;
  const u16*   Kb  = Kh + (size_t)bh * S_ * 64;
  const float* Vb  = V + (size_t)bh * S_ * 64;

  f16x8 ah[4][2], al[4][2];
#pragma unroll
  for (int mt = 0; mt < 4; ++mt)
#pragma unroll
    for (int kk = 0; kk < 2; ++kk) {
      const float* qr = Qlb + (size_t)(mt * 16 + lr) * 64 + kk * 32 + kg * 8;
      cvt8_hl(*(const float4*)qr, *(const float4*)(qr + 4), &ah[mt][kk], &al[mt][kk]);
    }

#pragma unroll
  for (int t = 0; t < 2; ++t) {
    const int s0 = (wave * 2 + t) * 16;
    const int srow = ch * SC_ + s0 + lr;
    f32x4 acc[4];
#pragma unroll
    for (int mt = 0; mt < 4; ++mt) acc[mt] = (f32x4){0.f, 0.f, 0.f, 0.f};
#pragma unroll
    for (int kk = 0; kk < 2; ++kk) {
      const f16x8 bhf = *(const f16x8*)&Kb[(size_t)srow * 64 + kk * 32 + kg * 8];
#pragma unroll
      for (int mt = 0; mt < 4; ++mt) {
        acc[mt] = __builtin_amdgcn_mfma_f32_16x16x32_f16(ah[mt][kk], bhf, acc[mt], 0, 0, 0);
        acc[mt] = __builtin_amdgcn_mfma_f32_16x16x32_f16(al[mt][kk], bhf, acc[mt], 0, 0, 0);
      }
    }
#pragma unroll
    for (int mt = 0; mt < 4; ++mt)
#pragma unroll
      for (int r = 0; r < 4; ++r)
        P[mt * 16 + kg * 4 + r][s0 + lr] = acc[mt][r] * 0.125f;
  }
  __syncthreads();

  const int r = tid >> 2, q = tid & 3;
  {
    float mx = -1e30f;
#pragma unroll
    for (int s = 0; s < 32; ++s) mx = fmaxf(mx, P[r][q * 32 + s]);
    red1[r][q] = mx;
  }
  __syncthreads();
  const float rowmax = fmaxf(fmaxf(red1[r][0], red1[r][1]),
                             fmaxf(red1[r][2], red1[r][3]));
  {
    float sum = 0.f;
#pragma unroll
    for (int s = 0; s < 32; ++s) {
      const float e = expf(P[r][q * 32 + s] - rowmax);
      P[r][q * 32 + s] = e;
      sum += e;
    }
    red2[r][q] = sum;
  }
  __syncthreads();
  if (q == 0) {
    const float rowsum = red2[r][0] + red2[r][1] + red2[r][2] + red2[r][3];
    mpart[((size_t)bh * NCH_ + ch) * 64 + r] = rowmax;
    lpart[((size_t)bh * NCH_ + ch) * 64 + r] = rowsum;
  }

  const int mg = tid >> 4, dq = (tid & 15) * 4;
  float4 oacc[4];
#pragma unroll
  for (int i = 0; i < 4; ++i) oacc[i] = make_float4(0.f, 0.f, 0.f, 0.f);
  for (int s = 0; s < SC_; ++s) {
    const float4 v = *(const float4*)&Vb[(size_t)(ch * SC_ + s) * 64 + dq];
#pragma unroll
    for (int i = 0; i < 4; ++i) {
      const float p = P[mg * 4 + i][s];
      oacc[i].x += p * v.x; oacc[i].y += p * v.y;
      oacc[i].z += p * v.z; oacc[i].w += p * v.w;
    }
  }
#pragma unroll
  for (int i = 0; i < 4; ++i) {
    const size_t o = (((size_t)bh * NCH_ + ch) * 64 + mg * 4 + i) * 64 + dq;
    *(float4*)&Opart[o] = oacc[i];
  }
}

// =============================================================
// FUSED: X = softmax(Q @ Kl^T / 8) @ W2  +  depthwise conv(V),
// written directly as split-fp16 (input of the out-GEMM).
// =============================================================
__global__ __launch_bounds__(256) void attn_conv_fused(
    const float* __restrict__ Q, const float* __restrict__ Kl,
    const float* __restrict__ W2, const float* __restrict__ V,
    const float* __restrict__ cw,
    u16* __restrict__ Xch, u16* __restrict__ Xcl)
{
  __shared__ float smem[256 * 68];       // phase A: Kls[0..4095], W2s[4096..8191]
  __shared__ float cws[33];              // phase B: o_lds[256][68] overlay
  float* Kls = smem;
  float* W2s = smem + 4096;

  const int blk = blockIdx.x;
  const int bh = blk >> 4, chunk = blk & 15;
  const int tid = threadIdx.x;
  const int b = bh / H_, h = bh % H_;
  const int s0 = chunk * 256;

  if (tid < 33) cws[tid] = cw[h * 33 + tid];
  for (int idx = tid; idx < 4096; idx += 256) {
    Kls[idx] = Kl[(size_t)bh * 4096 + idx];
    W2s[idx] = W2[(size_t)bh * 4096 + idx];
  }
  __syncthreads();

  // ---- phase A: landmark attention, one row per thread ----
  {
    const int s = s0 + tid;
    const float* qp = Q + ((size_t)bh * S_ + s) * 64;
    float4 q4[16];
#pragma unroll
    for (int k = 0; k < 16; ++k) q4[k] = *(const float4*)&qp[k * 4];
    float p[64];
#pragma unroll
    for (int m = 0; m < 64; ++m) {
      float dot = 0.f;
#pragma unroll
      for (int k = 0; k < 16; ++k) {
        const float4 kv = *(const float4*)&Kls[m * 64 + k * 4];
        dot += q4[k].x * kv.x + q4[k].y * kv.y + q4[k].z * kv.z + q4[k].w * kv.w;
      }
      p[m] = dot * 0.125f;
    }
    float mx = -1e30f;
#pragma unroll
    for (int m = 0; m < 64; ++m) mx = fmaxf(mx, p[m]);
    float sum = 0.f;
#pragma unroll
    for (int m = 0; m < 64; ++m) { p[m] = expf(p[m] - mx); sum += p[m]; }
    const float inv = 1.f / sum;
    float4 o4[16];
#pragma unroll
    for (int k = 0; k < 16; ++k) o4[k] = make_float4(0.f, 0.f, 0.f, 0.f);
#pragma unroll
    for (int m = 0; m < 64; ++m) {
      const float pm = p[m];
#pragma unroll
      for (int k = 0; k < 16; ++k) {
        const float4 wv = *(const float4*)&W2s[m * 64 + k * 4];
        o4[k].x += pm * wv.x; o4[k].y += pm * wv.y;
        o4[k].z += pm * wv.z; o4[k].w += pm * wv.w;
      }
    }
    __syncthreads();              // Kls/W2s dead -> safe to overlay
#pragma unroll
    for (int k = 0; k < 16; ++k) {
      o4[k].x *= inv; o4[k].y *= inv; o4[k].z *= inv; o4[k].w *= inv;
      *(float4*)&smem[tid * 68 + k * 4] = o4[k];
    }
  }
  __syncthreads();

  // ---- phase B: depthwise conv (sliding window) + combine + split write ----
  const int d = tid & 63, rg = tid >> 6;        // 4 groups x 64 rows
  const int rbase = s0 + rg * 64;               // absolute first row
  const float* Vd = V + (size_t)bh * S_ * 64 + d;

  float v[40];
#pragma unroll
  for (int j = 0; j < 40; ++j) {
    const int sv = rbase - 16 + j;
    v[j] = (sv >= 0 && sv < S_) ? Vd[(size_t)sv * 64] : 0.f;
  }

#pragma unroll
  for (int c = 0; c < 8; ++c) {                 // 8 chunks of 8 rows
#pragma unroll
    for (int rr = 0; rr < 8; ++rr) {
      float acc = 0.f;
#pragma unroll
      for (int t = 0; t < 33; ++t) acc += v[rr + t] * cws[t];
      const int row = rg * 64 + c * 8 + rr;     // row within chunk (0..255)
      const float o = smem[row * 68 + d] + acc;
      const size_t idx = ((size_t)(b * S_ + s0 + row)) * HID_ + h * 64 + d;
      const u16 hh = f2h_bits(o);
      Xch[idx] = hh;
      Xcl[idx] = f2h_bits(o - h2f(hh));
    }
    if (c < 7) {
#pragma unroll
      for (int j = 0; j < 32; ++j) v[j] = v[j + 8];
#pragma unroll
      for (int j = 0; j < 8; ++j) {
        const int sv = rbase + 24 + c * 8 + j;
        v[32 + j] = (sv >= 0 && sv < S_) ? Vd[(size_t)sv * 64] : 0.f;
      }
    }
  }
}

// =============================================================
extern "C" void kernel_launch(void* const* d_in, const int* in_sizes, int n_in,
                              void* d_out, int out_size, void* d_ws, size_t ws_size,
                              hipStream_t stream)
{
  (void)in_sizes; (void)n_in; (void)out_size; (void)ws_size;
  const float* x      = (const float*)d_in[0];
  const float* qkv_w  = (const float*)d_in[1];
  const float* qkv_b  = (const float*)d_in[2];
  const float* conv_w = (const float*)d_in[3];
  const float* out_w  = (const float*)d_in[4];
  const float* out_b  = (const float*)d_in[5];
  float* out = (float*)d_out;

  // fp32 region
  float* ws   = (float*)d_ws;
  float* Q    = ws;                       // [BH,S,D] 6291456 f32
  u16*   Kh   = (u16*)(Q + 6291456);      // [BH,S,D] fp16 (in f32-sized slot)
  float* V    = Q + 2 * 6291456;
  float* Ql   = V + 6291456;              // 98304 each below
  float* Kl   = Ql + 98304;
  float* K2   = Kl + 98304;
  float* W2   = K2 + 98304;
  float* colmax = W2 + 98304;
  float* rowmax = colmax + 32;
  // fp16 (u16) region
  u16* ub  = (u16*)(rowmax + 32);
  u16* Xh  = ub;                          // 6291456 u16
  u16* Xl  = Xh + 6291456;
  u16* Wqh = Xl + 6291456;                // 1769472
  u16* Woh = Wqh + 1769472;               // 589824
  // aliases (stream-ordered safe):
  u16* Xch = Xh;                          // Xh dead after QKV GEMM
  u16* Xcl = Xl;
  float* Opart = (float*)Xh;              // consumed by newton_combine before Xch write
  float* mpart = (float*)Xl;
  float* lpart = mpart + BH_ * NCH_ * 64;

  split3<<<(N8X + N8WQ + N8WO + 255) / 256, 256, 0, stream>>>(
      x, qkv_w, out_w, Xh, Wqh, Woh);

  gemm_mfma<0, 1><<<dim3(18, 64), 256, 0, stream>>>(
      Xh, nullptr, Wqh, qkv_b, Q, Kh, V, Ql, Kl);

  kernel2_softmax<<<BH_, 256, 0, stream>>>(Ql, Kl, K2, colmax, rowmax);

  k3v_pass1<<<dim3(NCH_, BH_), 256, 0, stream>>>(Ql, Kh, V, Opart, mpart, lpart);

  newton_combine<<<BH_, 512, 0, stream>>>(K2, colmax, rowmax,
                                          Opart, mpart, lpart, W2);

  attn_conv_fused<<<BH_ * 16, 256, 0, stream>>>(Q, Kl, W2, V, conv_w, Xch, Xcl);

  gemm_mfma<1, 2><<<dim3(6, 64), 256, 0, stream>>>(
      Xch, Xcl, Woh, out_b, out, nullptr, nullptr, nullptr, nullptr);
}